// Round 4
// baseline (1452.557 us; speedup 1.0000x reference)
//
#include <hip/hip_runtime.h>
#include <hip/hip_bf16.h>
#include <math.h>

#define TT   256
#define FF   32
#define CCH  8
#define VV   10000
#define HH   1024
#define EE   256
#define NG   3072        // gate cols r|z|n (original order: g*1024 + j)
#define EOS_ID 2
#define NSTEPS 40
#define CHAIN_BLKS 64

typedef __attribute__((ext_vector_type(8))) short bf16x8;
typedef __attribute__((ext_vector_type(4))) float f32x4;

__device__ __forceinline__ void gload_lds16(const void* g, void* l) {
    __builtin_amdgcn_global_load_lds((const __attribute__((address_space(1))) void*)g,
                                     (__attribute__((address_space(3))) void*)l,
                                     16, 0, 0);
}

__device__ __forceinline__ float sigmf(float x) { return 1.f / (1.f + __expf(-x)); }

// ---------------------------------------------------------------------------
// prep: decoder ids c_in[t][f], entry-done flags, zero barrier counters
// ---------------------------------------------------------------------------
__global__ __launch_bounds__(256) void prep_kernel(const int* __restrict__ oc,
                                                   int* __restrict__ c_in,
                                                   unsigned char* __restrict__ done,
                                                   int* __restrict__ ctr) {
    int t = threadIdx.x;
    if (t < NSTEPS) ctr[t] = 0;
    int c0 = oc[0];
    bool d = (c0 == EOS_ID);
    for (int f = 0; f < FF; ++f) {
        c_in[t * FF + f] = (f == 0) ? c0 : oc[1 + t * FF + f - 1];
        done[t * FF + f] = d ? 1 : 0;
        d = d || (oc[1 + t * FF + f] == EOS_ID);
    }
}

// ---------------------------------------------------------------------------
// h0 (fp32) + A0 = bf16(h0)
// ---------------------------------------------------------------------------
__global__ __launch_bounds__(256) void h0_kernel(const float* __restrict__ tctx,
                                                 const int* __restrict__ sent,
                                                 float* __restrict__ h,
                                                 __hip_bfloat16* __restrict__ A0) {
    int t = blockIdx.x;
    int tid = threadIdx.x;
    __shared__ int xt[CCH];
    if (tid < CCH) xt[tid] = sent[(t * CCH + tid) * 3 + 1];
    __syncthreads();
#pragma unroll
    for (int jj = 0; jj < 4; ++jj) {
        int j = tid + jj * 256;
        float s = 0.f;
#pragma unroll
        for (int c = 0; c < CCH; ++c) s += tctx[(size_t)xt[c] * HH + j];
        float hv = s * 0.125f;
        h[(size_t)t * HH + j] = hv;
        A0[(size_t)t * HH + j] = __float2bfloat16(hv);
    }
}

// ---------------------------------------------------------------------------
// generic fp32 -> bf16
// ---------------------------------------------------------------------------
__global__ __launch_bounds__(256) void f2b_kernel(const float* __restrict__ src,
                                                  __hip_bfloat16* __restrict__ dst) {
    size_t base = ((size_t)blockIdx.x * 256 + threadIdx.x) * 4;
    float4 v = *(const float4*)(src + base);
    dst[base + 0] = __float2bfloat16(v.x);
    dst[base + 1] = __float2bfloat16(v.y);
    dst[base + 2] = __float2bfloat16(v.z);
    dst[base + 3] = __float2bfloat16(v.w);
}

// ---------------------------------------------------------------------------
// Build gate-interleaved, 128-padded Bg from Whh (3072x1024 fp32):
//   Bg[(jb*128 + g*32 + ji)][k] = bf16(Whh[g*1024 + jb*32 + ji][k]), g<3
//   rows with (g*32+ji)>=96 are zero padding.  grid 4096 (=32jb*128rows)
// ---------------------------------------------------------------------------
__global__ __launch_bounds__(256) void build_Bg(const float* __restrict__ Whh,
                                                __hip_bfloat16* __restrict__ Bg) {
    int by = blockIdx.x;           // row n' in [0,4096)
    int tid = threadIdx.x;
    int jbrow = by & 127;          // g*32+ji
    int jb = by >> 7;
    int g = jbrow >> 5, ji = jbrow & 31;
    __hip_bfloat16* drow = Bg + (size_t)by * HH;
    if (g < 3) {
        const float* srow = Whh + (size_t)(g * 1024 + jb * 32 + ji) * HH;
#pragma unroll
        for (int q = 0; q < 4; ++q) {
            int k = tid * 4 + q * 1024; // wrong stride; fix below
        }
        // 1024 k / 256 thr = 4 per thread, contiguous float4
        float4 v = *(const float4*)(srow + tid * 4);
        drow[tid * 4 + 0] = __float2bfloat16(v.x);
        drow[tid * 4 + 1] = __float2bfloat16(v.y);
        drow[tid * 4 + 2] = __float2bfloat16(v.z);
        drow[tid * 4 + 3] = __float2bfloat16(v.w);
    } else {
        __hip_bfloat16 z = __float2bfloat16(0.f);
        drow[tid * 4 + 0] = z; drow[tid * 4 + 1] = z;
        drow[tid * 4 + 2] = z; drow[tid * 4 + 3] = z;
    }
}

// ---------------------------------------------------------------------------
// Pipelined 128x128 MFMA GEMM (round-3 validated) for x-side gi tables.
// MODE 1: enc rows gathered emb_bf[sent char]; MODE 2: dec rows emb_bf[c_in]
// ---------------------------------------------------------------------------
template<int MODE>
__global__ __launch_bounds__(256) void gemm_pipe(const __hip_bfloat16* __restrict__ A, int lda,
                                                 const __hip_bfloat16* __restrict__ B, int ldb,
                                                 float* __restrict__ C,
                                                 const int* __restrict__ idsrc,
                                                 int NIT) {
    __shared__ __hip_bfloat16 As[4][128 * 32];
    __shared__ __hip_bfloat16 Bs[4][128 * 32];
    __shared__ int sids[128];

    const int tid = threadIdx.x;
    const int n0 = blockIdx.x * 128;
    const int m0 = blockIdx.y * 128;

    if (tid < 128) {
        int row = m0 + tid;
        int t = row & 255;
        int id;
        if (MODE == 1) { int c = row >> 8; id = idsrc[(t * CCH + c) * 3 + 2]; }
        else           { int f = row >> 8; id = idsrc[t * FF + f]; }
        sids[tid] = id;
    }
    __syncthreads();

    const int srow = tid >> 2, skq = tid & 3;
    const int l = tid & 63;
    const int w = tid >> 6;
    const int wr = (w >> 1) * 64, wc = (w & 1) * 64;
    const int fra = ((wr + (l & 15)) << 5) + ((l >> 4) << 3);
    const int frb = ((wc + (l & 15)) << 5) + ((l >> 4) << 3);

    f32x4 acc[4][4];
#pragma unroll
    for (int i = 0; i < 4; ++i)
#pragma unroll
        for (int j = 0; j < 4; ++j) acc[i][j] = (f32x4){0.f, 0.f, 0.f, 0.f};

    auto stage = [&](int slot, int it) {
        const int k0 = it * 32;
        const __hip_bfloat16* ga0 = A + (size_t)sids[srow] * lda + k0 + skq * 8;
        const __hip_bfloat16* ga1 = A + (size_t)sids[64 + srow] * lda + k0 + skq * 8;
        const __hip_bfloat16* gb0 = B + (size_t)(n0 + srow) * ldb + k0 + skq * 8;
        const __hip_bfloat16* gb1 = B + (size_t)(n0 + 64 + srow) * ldb + k0 + skq * 8;
        __hip_bfloat16* lA = &As[slot][tid * 8];
        __hip_bfloat16* lB = &Bs[slot][tid * 8];
        gload_lds16(ga0, lA);
        gload_lds16(ga1, lA + 2048);
        gload_lds16(gb0, lB);
        gload_lds16(gb1, lB + 2048);
    };

    stage(0, 0);
    stage(1, 1);

    for (int it = 0; it < NIT; ++it) {
        if (it + 2 < NIT) stage((it + 2) & 3, it + 2);
        int ahead = NIT - 1 - it; if (ahead > 2) ahead = 2;
        if (ahead >= 2)      asm volatile("s_waitcnt vmcnt(8)" ::: "memory");
        else if (ahead == 1) asm volatile("s_waitcnt vmcnt(4)" ::: "memory");
        else                 asm volatile("s_waitcnt vmcnt(0)" ::: "memory");
        __builtin_amdgcn_s_barrier();
        __builtin_amdgcn_sched_barrier(0);

        const __hip_bfloat16* cA = As[it & 3];
        const __hip_bfloat16* cB = Bs[it & 3];
        bf16x8 af[4], bfv[4];
#pragma unroll
        for (int fm = 0; fm < 4; ++fm) af[fm] = *(const bf16x8*)&cA[fra + fm * 512];
#pragma unroll
        for (int fn = 0; fn < 4; ++fn) bfv[fn] = *(const bf16x8*)&cB[frb + fn * 512];
#pragma unroll
        for (int fm = 0; fm < 4; ++fm)
#pragma unroll
            for (int fn = 0; fn < 4; ++fn)
                acc[fm][fn] = __builtin_amdgcn_mfma_f32_16x16x32_bf16(af[fm], bfv[fn], acc[fm][fn], 0, 0, 0);
    }

    const int colb = wc + (l & 15);
    const int rb   = wr + ((l >> 4) << 2);
#pragma unroll
    for (int fm = 0; fm < 4; ++fm)
#pragma unroll
        for (int fn = 0; fn < 4; ++fn)
#pragma unroll
            for (int q = 0; q < 4; ++q)
                C[(size_t)(m0 + rb + fm * 16 + q) * NG + n0 + colb + fn * 16] = acc[fm][fn][q];
}

// ---------------------------------------------------------------------------
// device-scope grid barrier (sense-free: unique counter per step)
// ---------------------------------------------------------------------------
__device__ __forceinline__ void grid_barrier(int* ctr, int target) {
    __syncthreads();
    if (threadIdx.x == 0) {
        __threadfence();   // release: write back to device-coherent point
        __hip_atomic_fetch_add(ctr, 1, __ATOMIC_RELEASE, __HIP_MEMORY_SCOPE_AGENT);
        int v; long guard = 0;
        do {
            v = __hip_atomic_load(ctr, __ATOMIC_ACQUIRE, __HIP_MEMORY_SCOPE_AGENT);
        } while (v < target && ++guard < (1L << 24));
        __threadfence();   // acquire: invalidate stale cache lines
    }
    __syncthreads();
}

// ---------------------------------------------------------------------------
// Persistent chain kernel: 40 GRU steps, fused GEMM+epilogue, 1 barrier/step.
// 64 blocks: block = (mt in 0..1, jb in 0..31); owns t in [mt*128, +128),
// j in [jb*32, +32). h kept in registers (16 floats/thread).
// ---------------------------------------------------------------------------
__global__ __launch_bounds__(256) void chain_kernel(
    __hip_bfloat16* Abuf0, __hip_bfloat16* Abuf1,              // NOT restrict (ping-pong)
    const __hip_bfloat16* __restrict__ Bg_e,
    const __hip_bfloat16* __restrict__ Bg_d,
    const float* __restrict__ gi_enc, const float* __restrict__ gi_dec,
    const float* __restrict__ ebih, const float* __restrict__ ebhh,
    const float* __restrict__ dbih, const float* __restrict__ dbhh,
    const float* __restrict__ hA,
    __hip_bfloat16* __restrict__ hsb,
    const unsigned char* __restrict__ dflags,
    int* ctr) {

    __shared__ __align__(16) char smem[65536];

    const int tid = threadIdx.x;
    const int b = blockIdx.x;
    const int mt = b >> 5, jb = b & 31;
    const int m0 = mt * 128;

    const int l = tid & 63, w = tid >> 6;
    const int wr = (w >> 1) * 64, wcol = (w & 1) * 48;
    const int fra = ((wr + (l & 15)) << 5) + ((l >> 4) << 3);
    const int frb = ((wcol + (l & 15)) << 5) + ((l >> 4) << 3);
    const int srow = tid >> 2, skq = tid & 3;

    // persistent h registers: pair p -> (trow = (p*256+tid)>>5, ji = (p*256+tid)&31)
    float hreg[16];
#pragma unroll
    for (int p = 0; p < 16; ++p) {
        int idx = p * 256 + tid;
        int trow = idx >> 5, ji = idx & 31;
        hreg[p] = hA[(size_t)(m0 + trow) * HH + jb * 32 + ji];
    }

    for (int s = 0; s < NSTEPS; ++s) {
        const __hip_bfloat16* Ab = (s & 1) ? Abuf1 : Abuf0;
        __hip_bfloat16* An = (s & 1) ? Abuf0 : Abuf1;
        const __hip_bfloat16* Bg = (s < CCH) ? Bg_e : Bg_d;
        const float* gib = (s < CCH) ? (gi_enc + ((size_t)s * TT + m0) * NG)
                                     : (gi_dec + ((size_t)(s - CCH) * TT + m0) * NG);
        const float* bih = (s < CCH) ? ebih : dbih;
        const float* bhh = (s < CCH) ? ebhh : dbhh;

        // ---- GEMM phase: 128x96 tile over K=1024, 4-slot ring, depth-2 ----
        f32x4 acc[4][3];
#pragma unroll
        for (int i = 0; i < 4; ++i)
#pragma unroll
            for (int j = 0; j < 3; ++j) acc[i][j] = (f32x4){0.f, 0.f, 0.f, 0.f};

        auto stage = [&](int slot, int it) {
            const int k0 = it * 32;
            const __hip_bfloat16* ga0 = Ab + (size_t)(m0 + srow) * HH + k0 + skq * 8;
            const __hip_bfloat16* ga1 = Ab + (size_t)(m0 + 64 + srow) * HH + k0 + skq * 8;
            const __hip_bfloat16* gb0 = Bg + (size_t)(jb * 128 + srow) * HH + k0 + skq * 8;
            const __hip_bfloat16* gb1 = Bg + (size_t)(jb * 128 + 64 + srow) * HH + k0 + skq * 8;
            __hip_bfloat16* lA = (__hip_bfloat16*)(smem + slot * 16384) + tid * 8;
            __hip_bfloat16* lB = (__hip_bfloat16*)(smem + slot * 16384 + 8192) + tid * 8;
            gload_lds16(ga0, lA);
            gload_lds16(ga1, lA + 2048);
            gload_lds16(gb0, lB);
            gload_lds16(gb1, lB + 2048);
        };

        stage(0, 0);
        stage(1, 1);
        for (int it = 0; it < 32; ++it) {
            if (it + 2 < 32) stage((it + 2) & 3, it + 2);
            int ahead = 31 - it; if (ahead > 2) ahead = 2;
            if (ahead >= 2)      asm volatile("s_waitcnt vmcnt(8)" ::: "memory");
            else if (ahead == 1) asm volatile("s_waitcnt vmcnt(4)" ::: "memory");
            else                 asm volatile("s_waitcnt vmcnt(0)" ::: "memory");
            __builtin_amdgcn_s_barrier();
            __builtin_amdgcn_sched_barrier(0);

            const __hip_bfloat16* cA = (const __hip_bfloat16*)(smem + (it & 3) * 16384);
            const __hip_bfloat16* cB = (const __hip_bfloat16*)(smem + (it & 3) * 16384 + 8192);
            bf16x8 af[4], bfv[3];
#pragma unroll
            for (int fm = 0; fm < 4; ++fm) af[fm] = *(const bf16x8*)&cA[fra + fm * 512];
#pragma unroll
            for (int fn = 0; fn < 3; ++fn) bfv[fn] = *(const bf16x8*)&cB[frb + fn * 512];
#pragma unroll
            for (int fm = 0; fm < 4; ++fm)
#pragma unroll
                for (int fn = 0; fn < 3; ++fn)
                    acc[fm][fn] = __builtin_amdgcn_mfma_f32_16x16x32_bf16(af[fm], bfv[fn], acc[fm][fn], 0, 0, 0);
        }

        __syncthreads();   // all frag reads done before LDS reuse

        // ---- dump acc to LDS as gp[128][100] fp32 ----
        float* gp = (float*)smem;
        {
            const int rb = wr + ((l >> 4) << 2);
#pragma unroll
            for (int fm = 0; fm < 4; ++fm)
#pragma unroll
                for (int fn = 0; fn < 3; ++fn)
#pragma unroll
                    for (int q = 0; q < 4; ++q)
                        gp[(rb + fm * 16 + q) * 100 + wcol + fn * 16 + (l & 15)] = acc[fm][fn][q];
        }
        __syncthreads();

        // ---- fused GRU epilogue ----
        const int f = s - CCH;
#pragma unroll
        for (int p = 0; p < 16; ++p) {
            int idx = p * 256 + tid;
            int trow = idx >> 5, ji = idx & 31;
            int t = m0 + trow, j = jb * 32 + ji;
            float racc = gp[trow * 100 + ji];
            float zacc = gp[trow * 100 + 32 + ji];
            float nacc = gp[trow * 100 + 64 + ji];
            const float* grow = gib + (size_t)trow * NG;
            float r = sigmf(grow[j] + bih[j] + racc + bhh[j]);
            float z = sigmf(grow[HH + j] + bih[HH + j] + zacc + bhh[HH + j]);
            float n = tanhf(grow[2 * HH + j] + bih[2 * HH + j] + r * (nacc + bhh[2 * HH + j]));
            float hold = hreg[p];
            float hv = (1.f - z) * n + z * hold;
            if (s >= CCH && dflags[t * FF + f]) hv = hold;
            hreg[p] = hv;
            __hip_bfloat16 hb = __float2bfloat16(hv);
            An[(size_t)t * HH + j] = hb;
            if (s >= CCH) hsb[((size_t)f * TT + t) * HH + j] = hb;
        }

        if (s < NSTEPS - 1) grid_barrier(ctr + s, CHAIN_BLKS);
    }
}

// ---------------------------------------------------------------------------
// scores (validated): 128x128 MFMA, single-buffer 2-barrier core
// ---------------------------------------------------------------------------
__global__ __launch_bounds__(256) void scores_mfma(const __hip_bfloat16* __restrict__ hsb,
                                                   const __hip_bfloat16* __restrict__ Wb,
                                                   const float* __restrict__ bout,
                                                   const int* __restrict__ oc,
                                                   float* __restrict__ out) {
    __shared__ __hip_bfloat16 As[128 * 32], Bs[128 * 32];
    int bid = blockIdx.x;
    int sid = (bid & 7) * 632 + (bid >> 3);      // 5056 = 8*632, bijective
    int bx = sid % 79, by = sid / 79;
    int n0 = bx * 128, m0 = by * 128;

    const int tid = threadIdx.x;
    const int l = tid & 63;
    const int w = tid >> 6;
    const int wr = (w >> 1) * 64, wc = (w & 1) * 64;
    const int srow = tid >> 2, skq = tid & 3;

    f32x4 acc[4][4];
#pragma unroll
    for (int i = 0; i < 4; ++i)
#pragma unroll
        for (int j = 0; j < 4; ++j) acc[i][j] = (f32x4){0.f, 0.f, 0.f, 0.f};

    const int ar0 = m0 + srow, ar1 = m0 + 64 + srow;
    int br0 = n0 + srow, br1 = n0 + 64 + srow;
    br0 = (br0 > VV - 1) ? VV - 1 : br0;
    br1 = (br1 > VV - 1) ? VV - 1 : br1;
    const __hip_bfloat16* gA0 = hsb + (size_t)ar0 * HH + skq * 8;
    const __hip_bfloat16* gA1 = hsb + (size_t)ar1 * HH + skq * 8;
    const __hip_bfloat16* gB0 = Wb + (size_t)br0 * HH + skq * 8;
    const __hip_bfloat16* gB1 = Wb + (size_t)br1 * HH + skq * 8;
    __hip_bfloat16* lA = As + tid * 8;
    __hip_bfloat16* lB = Bs + tid * 8;
    const int fra = ((wr + (l & 15)) << 5) + ((l >> 4) << 3);
    const int frb = ((wc + (l & 15)) << 5) + ((l >> 4) << 3);

    for (int k0 = 0; k0 < HH; k0 += 32) {
        __syncthreads();
        gload_lds16(gA0 + k0, lA);
        gload_lds16(gA1 + k0, lA + 2048);
        gload_lds16(gB0 + k0, lB);
        gload_lds16(gB1 + k0, lB + 2048);
        __syncthreads();
        bf16x8 af[4], bfv[4];
#pragma unroll
        for (int fm = 0; fm < 4; ++fm) af[fm] = *(const bf16x8*)&As[fra + fm * 512];
#pragma unroll
        for (int fn = 0; fn < 4; ++fn) bfv[fn] = *(const bf16x8*)&Bs[frb + fn * 512];
#pragma unroll
        for (int fm = 0; fm < 4; ++fm)
#pragma unroll
            for (int fn = 0; fn < 4; ++fn)
                acc[fm][fn] = __builtin_amdgcn_mfma_f32_16x16x32_bf16(af[fm], bfv[fn], acc[fm][fn], 0, 0, 0);
    }

    const bool zf = (oc[0] == EOS_ID);
    const int colb = wc + (l & 15);
    const int rb   = wr + ((l >> 4) << 2);
#pragma unroll
    for (int fn = 0; fn < 4; ++fn) {
        int v = n0 + colb + fn * 16;
        if (v < VV) {
            float bb = bout[v];
#pragma unroll
            for (int fm = 0; fm < 4; ++fm) {
#pragma unroll
                for (int q = 0; q < 4; ++q) {
                    int m = m0 + rb + fm * 16 + q;
                    int f = m >> 8, t = m & 255;
                    out[(size_t)(t * FF + f) * VV + v] = zf ? 0.f : (acc[fm][fn][q] + bb);
                }
            }
        }
    }
}

// ---------------------------------------------------------------------------
extern "C" void kernel_launch(void* const* d_in, const int* in_sizes, int n_in,
                              void* d_out, int out_size, void* d_ws, size_t ws_size,
                              hipStream_t stream) {
    (void)in_sizes; (void)n_in; (void)ws_size;

    const float* token_ctx = (const float*)d_in[0];
    const float* emb       = (const float*)d_in[1];
    const float* eWih      = (const float*)d_in[2];
    const float* eWhh      = (const float*)d_in[3];
    const float* ebih      = (const float*)d_in[4];
    const float* ebhh      = (const float*)d_in[5];
    const float* dWih      = (const float*)d_in[6];
    const float* dWhh      = (const float*)d_in[7];
    const float* dbih      = (const float*)d_in[8];
    const float* dbhh      = (const float*)d_in[9];
    const float* Wout      = (const float*)d_in[10];
    const float* bout      = (const float*)d_in[11];
    const int*   sent      = (const int*)d_in[12];
    const int*   ochars    = (const int*)d_in[13];
    float* out = (float*)d_out;

    // ---- ws layout (~40 MB) ----
    char* w = (char*)d_ws;
    float* hA = (float*)w;                      w += (size_t)TT * HH * 4;        // 1 MB
    __hip_bfloat16* Ab0 = (__hip_bfloat16*)w;   w += (size_t)TT * HH * 2;        // 0.5 MB
    __hip_bfloat16* Ab1 = (__hip_bfloat16*)w;   w += (size_t)TT * HH * 2;        // 0.5 MB
    __hip_bfloat16* hsb = (__hip_bfloat16*)w;   w += (size_t)FF * TT * HH * 2;   // 16.8 MB
    __hip_bfloat16* Woutb = (__hip_bfloat16*)w; w += (size_t)VV * HH * 2;        // 20.5 MB
    int* c_in = (int*)w;                        w += (size_t)TT * FF * 4;
    unsigned char* done = (unsigned char*)w;    w += (size_t)TT * FF;
    w = (char*)(((size_t)w + 255) & ~(size_t)255);
    int* ctr = (int*)w;                         w += NSTEPS * 4;

    // ---- d_out tail scratch (dead until scores_mfma) ----
    char* tail = (char*)d_out + (size_t)out_size * 4;
    tail -= (size_t)32 * 128 * HH * 2;    __hip_bfloat16* Bg_e = (__hip_bfloat16*)tail;   // 8.4 MB
    tail -= (size_t)32 * 128 * HH * 2;    __hip_bfloat16* Bg_d = (__hip_bfloat16*)tail;   // 8.4 MB
    tail -= (size_t)CCH * TT * NG * 4;    float* gi_enc = (float*)tail;                   // 25.2 MB
    tail -= (size_t)FF * TT * NG * 4;     float* gi_dec = (float*)tail;                   // 100.7 MB
    tail -= (size_t)VV * EE * 2;          __hip_bfloat16* emb_bf = (__hip_bfloat16*)tail; // 5.1 MB
    tail -= (size_t)NG * EE * 2;          __hip_bfloat16* Wihb_e = (__hip_bfloat16*)tail;
    tail -= (size_t)NG * EE * 2;          __hip_bfloat16* Wihb_d = (__hip_bfloat16*)tail;

    // ---- prep & conversions ----
    prep_kernel<<<1, 256, 0, stream>>>(ochars, c_in, done, ctr);
    h0_kernel<<<TT, 256, 0, stream>>>(token_ctx, sent, hA, Ab0);
    f2b_kernel<<<(VV * EE) / 4 / 256, 256, 0, stream>>>(emb, emb_bf);
    f2b_kernel<<<(NG * EE) / 4 / 256, 256, 0, stream>>>(eWih, Wihb_e);
    f2b_kernel<<<(NG * EE) / 4 / 256, 256, 0, stream>>>(dWih, Wihb_d);
    f2b_kernel<<<(VV * HH) / 4 / 256, 256, 0, stream>>>(Wout, Woutb);
    build_Bg<<<4096, 256, 0, stream>>>(eWhh, Bg_e);
    build_Bg<<<4096, 256, 0, stream>>>(dWhh, Bg_d);

    // ---- x-side tables: gi = emb_bf[ids] @ Wih^T (fp32, gate order g*1024+j) ----
    gemm_pipe<1><<<dim3(24, 16), 256, 0, stream>>>(emb_bf, EE, Wihb_e, EE, gi_enc, sent, 8);
    gemm_pipe<2><<<dim3(24, 64), 256, 0, stream>>>(emb_bf, EE, Wihb_d, EE, gi_dec, c_in, 8);

    // ---- persistent recurrent chain ----
    chain_kernel<<<CHAIN_BLKS, 256, 0, stream>>>(Ab0, Ab1, Bg_e, Bg_d,
                                                 gi_enc, gi_dec,
                                                 ebih, ebhh, dbih, dbhh,
                                                 hA, hsb, done, ctr);

    // ---- scores ----
    scores_mfma<<<5056, 256, 0, stream>>>(hsb, Woutb, bout, ochars, out);
}

// Round 5
// 934.586 us; speedup vs baseline: 1.5542x; 1.5542x over previous
//
#include <hip/hip_runtime.h>
#include <hip/hip_bf16.h>
#include <math.h>

#define TT   256
#define FF   32
#define CCH  8
#define VV   10000
#define HH   1024
#define EE   256
#define NG   3072        // gate cols r|z|n (original order: g*1024 + j)
#define EOS_ID 2
#define NSTEPS 40
#define CHAIN_BLKS 128

typedef __attribute__((ext_vector_type(8))) short bf16x8;
typedef __attribute__((ext_vector_type(4))) float f32x4;

__device__ __forceinline__ void gload_lds16(const void* g, void* l) {
    __builtin_amdgcn_global_load_lds((const __attribute__((address_space(1))) void*)g,
                                     (__attribute__((address_space(3))) void*)l,
                                     16, 0, 0);
}

__device__ __forceinline__ float sigmf(float x) { return 1.f / (1.f + __expf(-x)); }

// ---------------------------------------------------------------------------
// prep: decoder ids c_in[t][f], entry-done flags, zero barrier counters
// ---------------------------------------------------------------------------
__global__ __launch_bounds__(256) void prep_kernel(const int* __restrict__ oc,
                                                   int* __restrict__ c_in,
                                                   unsigned char* __restrict__ done,
                                                   int* __restrict__ ctr) {
    int t = threadIdx.x;
    if (t < NSTEPS) ctr[t] = 0;
    int c0 = oc[0];
    bool d = (c0 == EOS_ID);
    for (int f = 0; f < FF; ++f) {
        c_in[t * FF + f] = (f == 0) ? c0 : oc[1 + t * FF + f - 1];
        done[t * FF + f] = d ? 1 : 0;
        d = d || (oc[1 + t * FF + f] == EOS_ID);
    }
}

// ---------------------------------------------------------------------------
// h0 (fp32) + A0 = bf16(h0)
// ---------------------------------------------------------------------------
__global__ __launch_bounds__(256) void h0_kernel(const float* __restrict__ tctx,
                                                 const int* __restrict__ sent,
                                                 float* __restrict__ h,
                                                 __hip_bfloat16* __restrict__ A0) {
    int t = blockIdx.x;
    int tid = threadIdx.x;
    __shared__ int xt[CCH];
    if (tid < CCH) xt[tid] = sent[(t * CCH + tid) * 3 + 1];
    __syncthreads();
#pragma unroll
    for (int jj = 0; jj < 4; ++jj) {
        int j = tid + jj * 256;
        float s = 0.f;
#pragma unroll
        for (int c = 0; c < CCH; ++c) s += tctx[(size_t)xt[c] * HH + j];
        float hv = s * 0.125f;
        h[(size_t)t * HH + j] = hv;
        A0[(size_t)t * HH + j] = __float2bfloat16(hv);
    }
}

// ---------------------------------------------------------------------------
// generic fp32 -> bf16
// ---------------------------------------------------------------------------
__global__ __launch_bounds__(256) void f2b_kernel(const float* __restrict__ src,
                                                  __hip_bfloat16* __restrict__ dst) {
    size_t base = ((size_t)blockIdx.x * 256 + threadIdx.x) * 4;
    float4 v = *(const float4*)(src + base);
    dst[base + 0] = __float2bfloat16(v.x);
    dst[base + 1] = __float2bfloat16(v.y);
    dst[base + 2] = __float2bfloat16(v.z);
    dst[base + 3] = __float2bfloat16(v.w);
}

// ---------------------------------------------------------------------------
// Build gate-interleaved, 128-padded Bg from Whh (3072x1024 fp32):
//   Bg[(jb*128 + g*32 + ji)][k] = bf16(Whh[g*1024 + jb*32 + ji][k]), g<3
//   rows with (g*32+ji)>=96 are zero padding.  grid 4096
// ---------------------------------------------------------------------------
__global__ __launch_bounds__(256) void build_Bg(const float* __restrict__ Whh,
                                                __hip_bfloat16* __restrict__ Bg) {
    int by = blockIdx.x;           // row n' in [0,4096)
    int tid = threadIdx.x;
    int jbrow = by & 127;          // g*32+ji
    int jb = by >> 7;
    int g = jbrow >> 5, ji = jbrow & 31;
    __hip_bfloat16* drow = Bg + (size_t)by * HH;
    if (g < 3) {
        const float* srow = Whh + (size_t)(g * 1024 + jb * 32 + ji) * HH;
        float4 v = *(const float4*)(srow + tid * 4);
        drow[tid * 4 + 0] = __float2bfloat16(v.x);
        drow[tid * 4 + 1] = __float2bfloat16(v.y);
        drow[tid * 4 + 2] = __float2bfloat16(v.z);
        drow[tid * 4 + 3] = __float2bfloat16(v.w);
    } else {
        __hip_bfloat16 z = __float2bfloat16(0.f);
        drow[tid * 4 + 0] = z; drow[tid * 4 + 1] = z;
        drow[tid * 4 + 2] = z; drow[tid * 4 + 3] = z;
    }
}

// ---------------------------------------------------------------------------
// Pipelined 128x128 MFMA GEMM (round-3 validated) for x-side gi tables.
// MODE 1: enc rows gathered emb_bf[sent char]; MODE 2: dec rows emb_bf[c_in]
// ---------------------------------------------------------------------------
template<int MODE>
__global__ __launch_bounds__(256) void gemm_pipe(const __hip_bfloat16* __restrict__ A, int lda,
                                                 const __hip_bfloat16* __restrict__ B, int ldb,
                                                 float* __restrict__ C,
                                                 const int* __restrict__ idsrc,
                                                 int NIT) {
    __shared__ __hip_bfloat16 As[4][128 * 32];
    __shared__ __hip_bfloat16 Bs[4][128 * 32];
    __shared__ int sids[128];

    const int tid = threadIdx.x;
    const int n0 = blockIdx.x * 128;
    const int m0 = blockIdx.y * 128;

    if (tid < 128) {
        int row = m0 + tid;
        int t = row & 255;
        int id;
        if (MODE == 1) { int c = row >> 8; id = idsrc[(t * CCH + c) * 3 + 2]; }
        else           { int f = row >> 8; id = idsrc[t * FF + f]; }
        sids[tid] = id;
    }
    __syncthreads();

    const int srow = tid >> 2, skq = tid & 3;
    const int l = tid & 63;
    const int w = tid >> 6;
    const int wr = (w >> 1) * 64, wc = (w & 1) * 64;
    const int fra = ((wr + (l & 15)) << 5) + ((l >> 4) << 3);
    const int frb = ((wc + (l & 15)) << 5) + ((l >> 4) << 3);

    f32x4 acc[4][4];
#pragma unroll
    for (int i = 0; i < 4; ++i)
#pragma unroll
        for (int j = 0; j < 4; ++j) acc[i][j] = (f32x4){0.f, 0.f, 0.f, 0.f};

    auto stage = [&](int slot, int it) {
        const int k0 = it * 32;
        const __hip_bfloat16* ga0 = A + (size_t)sids[srow] * lda + k0 + skq * 8;
        const __hip_bfloat16* ga1 = A + (size_t)sids[64 + srow] * lda + k0 + skq * 8;
        const __hip_bfloat16* gb0 = B + (size_t)(n0 + srow) * ldb + k0 + skq * 8;
        const __hip_bfloat16* gb1 = B + (size_t)(n0 + 64 + srow) * ldb + k0 + skq * 8;
        __hip_bfloat16* lA = &As[slot][tid * 8];
        __hip_bfloat16* lB = &Bs[slot][tid * 8];
        gload_lds16(ga0, lA);
        gload_lds16(ga1, lA + 2048);
        gload_lds16(gb0, lB);
        gload_lds16(gb1, lB + 2048);
    };

    stage(0, 0);
    stage(1, 1);

    for (int it = 0; it < NIT; ++it) {
        if (it + 2 < NIT) stage((it + 2) & 3, it + 2);
        int ahead = NIT - 1 - it; if (ahead > 2) ahead = 2;
        if (ahead >= 2)      asm volatile("s_waitcnt vmcnt(8)" ::: "memory");
        else if (ahead == 1) asm volatile("s_waitcnt vmcnt(4)" ::: "memory");
        else                 asm volatile("s_waitcnt vmcnt(0)" ::: "memory");
        __builtin_amdgcn_s_barrier();
        __builtin_amdgcn_sched_barrier(0);

        const __hip_bfloat16* cA = As[it & 3];
        const __hip_bfloat16* cB = Bs[it & 3];
        bf16x8 af[4], bfv[4];
#pragma unroll
        for (int fm = 0; fm < 4; ++fm) af[fm] = *(const bf16x8*)&cA[fra + fm * 512];
#pragma unroll
        for (int fn = 0; fn < 4; ++fn) bfv[fn] = *(const bf16x8*)&cB[frb + fn * 512];
#pragma unroll
        for (int fm = 0; fm < 4; ++fm)
#pragma unroll
            for (int fn = 0; fn < 4; ++fn)
                acc[fm][fn] = __builtin_amdgcn_mfma_f32_16x16x32_bf16(af[fm], bfv[fn], acc[fm][fn], 0, 0, 0);
    }

    const int colb = wc + (l & 15);
    const int rb   = wr + ((l >> 4) << 2);
#pragma unroll
    for (int fm = 0; fm < 4; ++fm)
#pragma unroll
        for (int fn = 0; fn < 4; ++fn)
#pragma unroll
            for (int q = 0; q < 4; ++q)
                C[(size_t)(m0 + rb + fm * 16 + q) * NG + n0 + colb + fn * 16] = acc[fm][fn][q];
}

// ---------------------------------------------------------------------------
// Persistent chain kernel v2: 128 blocks = (mt 0..3 x 64 rows, jb 0..31 x 32 j).
// BK=64, 3-slot LDS ring, depth-2 counted vmcnt, XOR-swizzled LDS (T2 both-sides),
// gi prefetched to VGPRs, relaxed-poll grid barrier (acquire once on exit).
// ---------------------------------------------------------------------------
__global__ __launch_bounds__(256) void chain_kernel(
    __hip_bfloat16* Abuf0, __hip_bfloat16* Abuf1,              // NOT restrict (ping-pong)
    const __hip_bfloat16* __restrict__ Bg_e,
    const __hip_bfloat16* __restrict__ Bg_d,
    const float* __restrict__ gi_enc, const float* __restrict__ gi_dec,
    const float* __restrict__ ebih, const float* __restrict__ ebhh,
    const float* __restrict__ dbih, const float* __restrict__ dbhh,
    const float* __restrict__ hA,
    __hip_bfloat16* __restrict__ hsb,
    const unsigned char* __restrict__ dflags,
    int* ctr) {

    // 3 slots x (A 8KB + B 12KB) = 60KB; gp (64x100 f32 = 25.6KB) reuses slot 0-1
    __shared__ __align__(16) char smem[61440];

    const int tid = threadIdx.x;
    const int b = blockIdx.x;
    const int mt = b >> 5, jb = b & 31;
    const int m0 = mt * 64;

    const int l = tid & 63, w = tid >> 6;
    const int wr = (w >> 1) * 32;        // wave M offset (2x2 wave grid)
    const int wc = (w & 1) * 48;         // wave N offset
    // epilogue/persistent-h mapping: ji fixed per thread, 8 t-rows
    const int ji = tid & 31;
    const int tr0 = tid >> 5;            // 0..7
    const int j = jb * 32 + ji;

    float hreg[8];
#pragma unroll
    for (int p = 0; p < 8; ++p)
        hreg[p] = hA[(size_t)(m0 + p * 8 + tr0) * HH + j];

    for (int s = 0; s < NSTEPS; ++s) {
        const __hip_bfloat16* Ab = (s & 1) ? Abuf1 : Abuf0;
        __hip_bfloat16* An = (s & 1) ? Abuf0 : Abuf1;
        const __hip_bfloat16* Bg = (s < CCH) ? Bg_e : Bg_d;
        const float* gib = (s < CCH) ? (gi_enc + ((size_t)s * TT + m0) * NG)
                                     : (gi_dec + ((size_t)(s - CCH) * TT + m0) * NG);
        const float* bih = (s < CCH) ? ebih : dbih;
        const float* bhh = (s < CCH) ? ebhh : dbhh;

        // ---- prefetch gi into VGPRs (ordered before stages; retires in 1st wait)
        float gir[8], giz[8], gin[8];
#pragma unroll
        for (int p = 0; p < 8; ++p) {
            const float* grow = gib + (size_t)(p * 8 + tr0) * NG + j;
            gir[p] = grow[0];
            giz[p] = grow[HH];
            gin[p] = grow[2 * HH];
        }

        // ---- GEMM: 64(M) x 96(N) x 1024(K), BK=64, swizzled LDS ----
        f32x4 acc[2][3];
#pragma unroll
        for (int i = 0; i < 2; ++i)
#pragma unroll
            for (int jj = 0; jj < 3; ++jj) acc[i][jj] = (f32x4){0.f, 0.f, 0.f, 0.f};

        auto stage = [&](int slot, int it) {
            const int k0 = it * 64;
            char* sb = smem + slot * 20480;
            // A: 64 rows x 128B, 512 chunks, 2 calls; source pre-swizzled
#pragma unroll
            for (int c = 0; c < 2; ++c) {
                int chunk = c * 256 + tid;
                int row = chunk >> 3, q = chunk & 7;
                const __hip_bfloat16* src =
                    Ab + (size_t)(m0 + row) * HH + k0 + ((q ^ (row & 7)) << 3);
                gload_lds16(src, sb + chunk * 16);
            }
            // B: 96 rows x 128B, 768 chunks, 3 calls
#pragma unroll
            for (int c = 0; c < 3; ++c) {
                int chunk = c * 256 + tid;
                int row = chunk >> 3, q = chunk & 7;
                const __hip_bfloat16* src =
                    Bg + (size_t)(jb * 128 + row) * HH + k0 + ((q ^ (row & 7)) << 3);
                gload_lds16(src, sb + 8192 + chunk * 16);
            }
        };

        stage(0, 0);
        stage(1, 1);

        int cur = 0, nxt = 2;
        for (int it = 0; it < 16; ++it) {
            if (it + 2 < 16) stage(nxt, it + 2);
            int ahead = 15 - it; if (ahead > 2) ahead = 2;
            if (ahead >= 2)      asm volatile("s_waitcnt vmcnt(10)" ::: "memory");
            else if (ahead == 1) asm volatile("s_waitcnt vmcnt(5)" ::: "memory");
            else                 asm volatile("s_waitcnt vmcnt(0)" ::: "memory");
            __builtin_amdgcn_s_barrier();
            __builtin_amdgcn_sched_barrier(0);

            const char* sb = smem + cur * 20480;
            const __hip_bfloat16* cA = (const __hip_bfloat16*)sb;
            const __hip_bfloat16* cB = (const __hip_bfloat16*)(sb + 8192);
#pragma unroll
            for (int kh = 0; kh < 2; ++kh) {
                const int qg = kh * 4 + (l >> 4);
                bf16x8 af[2], bfv[3];
#pragma unroll
                for (int fm = 0; fm < 2; ++fm) {
                    int rowf = wr + fm * 16 + (l & 15);
                    af[fm] = *(const bf16x8*)&cA[rowf * 64 + ((qg ^ (rowf & 7)) << 3)];
                }
#pragma unroll
                for (int fn = 0; fn < 3; ++fn) {
                    int rowb = wc + fn * 16 + (l & 15);
                    bfv[fn] = *(const bf16x8*)&cB[rowb * 64 + ((qg ^ (rowb & 7)) << 3)];
                }
#pragma unroll
                for (int fm = 0; fm < 2; ++fm)
#pragma unroll
                    for (int fn = 0; fn < 3; ++fn)
                        acc[fm][fn] = __builtin_amdgcn_mfma_f32_16x16x32_bf16(af[fm], bfv[fn], acc[fm][fn], 0, 0, 0);
            }
            cur = (cur == 2) ? 0 : cur + 1;
            nxt = (nxt == 2) ? 0 : nxt + 1;
        }

        __syncthreads();   // all frag reads done before LDS reuse

        // ---- dump acc to LDS as gp[64][100] fp32 ----
        float* gp = (float*)smem;
        {
            const int rb = wr + ((l >> 4) << 2);
#pragma unroll
            for (int fm = 0; fm < 2; ++fm)
#pragma unroll
                for (int fn = 0; fn < 3; ++fn)
#pragma unroll
                    for (int q = 0; q < 4; ++q)
                        gp[(rb + fm * 16 + q) * 100 + wc + fn * 16 + (l & 15)] = acc[fm][fn][q];
        }
        __syncthreads();

        // ---- fused GRU epilogue ----
        const int f = s - CCH;
        const float b_r = bih[j]          + bhh[j];
        const float b_z = bih[HH + j]     + bhh[HH + j];
        const float b_i = bih[2 * HH + j];
        const float b_h = bhh[2 * HH + j];
#pragma unroll
        for (int p = 0; p < 8; ++p) {
            const int trow = p * 8 + tr0;
            const int t = m0 + trow;
            float racc = gp[trow * 100 + ji];
            float zacc = gp[trow * 100 + 32 + ji];
            float nacc = gp[trow * 100 + 64 + ji];
            float r = sigmf(gir[p] + racc + b_r);
            float z = sigmf(giz[p] + zacc + b_z);
            float n = tanhf(gin[p] + b_i + r * (nacc + b_h));
            float hold = hreg[p];
            float hv = (1.f - z) * n + z * hold;
            if (s >= CCH && dflags[t * FF + f]) hv = hold;
            hreg[p] = hv;
            __hip_bfloat16 hb = __float2bfloat16(hv);
            An[(size_t)t * HH + j] = hb;
            if (s >= CCH) hsb[((size_t)f * TT + t) * HH + j] = hb;
        }

        // ---- grid barrier: release add, RELAXED poll, one acquire on exit ----
        if (s < NSTEPS - 1) {
            __syncthreads();
            if (tid == 0) {
                int* c = ctr + s;
                __hip_atomic_fetch_add(c, 1, __ATOMIC_RELEASE, __HIP_MEMORY_SCOPE_AGENT);
                long guard = 0;
                while (__hip_atomic_load(c, __ATOMIC_RELAXED, __HIP_MEMORY_SCOPE_AGENT) < CHAIN_BLKS
                       && ++guard < (1L << 24)) {
                    __builtin_amdgcn_s_sleep(1);
                }
                (void)__hip_atomic_load(c, __ATOMIC_ACQUIRE, __HIP_MEMORY_SCOPE_AGENT);
            }
            __syncthreads();
        }
    }
}

// ---------------------------------------------------------------------------
// scores (validated): 128x128 MFMA, single-buffer 2-barrier core
// ---------------------------------------------------------------------------
__global__ __launch_bounds__(256) void scores_mfma(const __hip_bfloat16* __restrict__ hsb,
                                                   const __hip_bfloat16* __restrict__ Wb,
                                                   const float* __restrict__ bout,
                                                   const int* __restrict__ oc,
                                                   float* __restrict__ out) {
    __shared__ __hip_bfloat16 As[128 * 32], Bs[128 * 32];
    int bid = blockIdx.x;
    int sid = (bid & 7) * 632 + (bid >> 3);      // 5056 = 8*632, bijective
    int bx = sid % 79, by = sid / 79;
    int n0 = bx * 128, m0 = by * 128;

    const int tid = threadIdx.x;
    const int l = tid & 63;
    const int w = tid >> 6;
    const int wr = (w >> 1) * 64, wc = (w & 1) * 64;
    const int srow = tid >> 2, skq = tid & 3;

    f32x4 acc[4][4];
#pragma unroll
    for (int i = 0; i < 4; ++i)
#pragma unroll
        for (int j = 0; j < 4; ++j) acc[i][j] = (f32x4){0.f, 0.f, 0.f, 0.f};

    const int ar0 = m0 + srow, ar1 = m0 + 64 + srow;
    int br0 = n0 + srow, br1 = n0 + 64 + srow;
    br0 = (br0 > VV - 1) ? VV - 1 : br0;
    br1 = (br1 > VV - 1) ? VV - 1 : br1;
    const __hip_bfloat16* gA0 = hsb + (size_t)ar0 * HH + skq * 8;
    const __hip_bfloat16* gA1 = hsb + (size_t)ar1 * HH + skq * 8;
    const __hip_bfloat16* gB0 = Wb + (size_t)br0 * HH + skq * 8;
    const __hip_bfloat16* gB1 = Wb + (size_t)br1 * HH + skq * 8;
    __hip_bfloat16* lA = As + tid * 8;
    __hip_bfloat16* lB = Bs + tid * 8;
    const int fra = ((wr + (l & 15)) << 5) + ((l >> 4) << 3);
    const int frb = ((wc + (l & 15)) << 5) + ((l >> 4) << 3);

    for (int k0 = 0; k0 < HH; k0 += 32) {
        __syncthreads();
        gload_lds16(gA0 + k0, lA);
        gload_lds16(gA1 + k0, lA + 2048);
        gload_lds16(gB0 + k0, lB);
        gload_lds16(gB1 + k0, lB + 2048);
        __syncthreads();
        bf16x8 af[4], bfv[4];
#pragma unroll
        for (int fm = 0; fm < 4; ++fm) af[fm] = *(const bf16x8*)&As[fra + fm * 512];
#pragma unroll
        for (int fn = 0; fn < 4; ++fn) bfv[fn] = *(const bf16x8*)&Bs[frb + fn * 512];
#pragma unroll
        for (int fm = 0; fm < 4; ++fm)
#pragma unroll
            for (int fn = 0; fn < 4; ++fn)
                acc[fm][fn] = __builtin_amdgcn_mfma_f32_16x16x32_bf16(af[fm], bfv[fn], acc[fm][fn], 0, 0, 0);
    }

    const bool zf = (oc[0] == EOS_ID);
    const int colb = wc + (l & 15);
    const int rb   = wr + ((l >> 4) << 2);
#pragma unroll
    for (int fn = 0; fn < 4; ++fn) {
        int v = n0 + colb + fn * 16;
        if (v < VV) {
            float bb = bout[v];
#pragma unroll
            for (int fm = 0; fm < 4; ++fm) {
#pragma unroll
                for (int q = 0; q < 4; ++q) {
                    int m = m0 + rb + fm * 16 + q;
                    int f = m >> 8, t = m & 255;
                    out[(size_t)(t * FF + f) * VV + v] = zf ? 0.f : (acc[fm][fn][q] + bb);
                }
            }
        }
    }
}

// ---------------------------------------------------------------------------
extern "C" void kernel_launch(void* const* d_in, const int* in_sizes, int n_in,
                              void* d_out, int out_size, void* d_ws, size_t ws_size,
                              hipStream_t stream) {
    (void)in_sizes; (void)n_in; (void)ws_size;

    const float* token_ctx = (const float*)d_in[0];
    const float* emb       = (const float*)d_in[1];
    const float* eWih      = (const float*)d_in[2];
    const float* eWhh      = (const float*)d_in[3];
    const float* ebih      = (const float*)d_in[4];
    const float* ebhh      = (const float*)d_in[5];
    const float* dWih      = (const float*)d_in[6];
    const float* dWhh      = (const float*)d_in[7];
    const float* dbih      = (const float*)d_in[8];
    const float* dbhh      = (const float*)d_in[9];
    const float* Wout      = (const float*)d_in[10];
    const float* bout      = (const float*)d_in[11];
    const int*   sent      = (const int*)d_in[12];
    const int*   ochars    = (const int*)d_in[13];
    float* out = (float*)d_out;

    // ---- ws layout (~40 MB) ----
    char* w = (char*)d_ws;
    float* hA = (float*)w;                      w += (size_t)TT * HH * 4;        // 1 MB
    __hip_bfloat16* Ab0 = (__hip_bfloat16*)w;   w += (size_t)TT * HH * 2;        // 0.5 MB
    __hip_bfloat16* Ab1 = (__hip_bfloat16*)w;   w += (size_t)TT * HH * 2;        // 0.5 MB
    __hip_bfloat16* hsb = (__hip_bfloat16*)w;   w += (size_t)FF * TT * HH * 2;   // 16.8 MB
    __hip_bfloat16* Woutb = (__hip_bfloat16*)w; w += (size_t)VV * HH * 2;        // 20.5 MB
    int* c_in = (int*)w;                        w += (size_t)TT * FF * 4;
    unsigned char* done = (unsigned char*)w;    w += (size_t)TT * FF;
    w = (char*)(((size_t)w + 255) & ~(size_t)255);
    int* ctr = (int*)w;                         w += NSTEPS * 4;

    // ---- d_out tail scratch (dead until scores_mfma) ----
    char* tail = (char*)d_out + (size_t)out_size * 4;
    tail -= (size_t)32 * 128 * HH * 2;    __hip_bfloat16* Bg_e = (__hip_bfloat16*)tail;   // 8.4 MB
    tail -= (size_t)32 * 128 * HH * 2;    __hip_bfloat16* Bg_d = (__hip_bfloat16*)tail;   // 8.4 MB
    tail -= (size_t)CCH * TT * NG * 4;    float* gi_enc = (float*)tail;                   // 25.2 MB
    tail -= (size_t)FF * TT * NG * 4;     float* gi_dec = (float*)tail;                   // 100.7 MB
    tail -= (size_t)VV * EE * 2;          __hip_bfloat16* emb_bf = (__hip_bfloat16*)tail; // 5.1 MB
    tail -= (size_t)NG * EE * 2;          __hip_bfloat16* Wihb_e = (__hip_bfloat16*)tail;
    tail -= (size_t)NG * EE * 2;          __hip_bfloat16* Wihb_d = (__hip_bfloat16*)tail;

    // ---- prep & conversions ----
    prep_kernel<<<1, 256, 0, stream>>>(ochars, c_in, done, ctr);
    h0_kernel<<<TT, 256, 0, stream>>>(token_ctx, sent, hA, Ab0);
    f2b_kernel<<<(VV * EE) / 4 / 256, 256, 0, stream>>>(emb, emb_bf);
    f2b_kernel<<<(NG * EE) / 4 / 256, 256, 0, stream>>>(eWih, Wihb_e);
    f2b_kernel<<<(NG * EE) / 4 / 256, 256, 0, stream>>>(dWih, Wihb_d);
    f2b_kernel<<<(VV * HH) / 4 / 256, 256, 0, stream>>>(Wout, Woutb);
    build_Bg<<<4096, 256, 0, stream>>>(eWhh, Bg_e);
    build_Bg<<<4096, 256, 0, stream>>>(dWhh, Bg_d);

    // ---- x-side tables: gi = emb_bf[ids] @ Wih^T (fp32, gate order g*1024+j) ----
    gemm_pipe<1><<<dim3(24, 16), 256, 0, stream>>>(emb_bf, EE, Wihb_e, EE, gi_enc, sent, 8);
    gemm_pipe<2><<<dim3(24, 64), 256, 0, stream>>>(emb_bf, EE, Wihb_d, EE, gi_dec, c_in, 8);

    // ---- persistent recurrent chain ----
    chain_kernel<<<CHAIN_BLKS, 256, 0, stream>>>(Ab0, Ab1, Bg_e, Bg_d,
                                                 gi_enc, gi_dec,
                                                 ebih, ebhh, dbih, dbhh,
                                                 hA, hsb, done, ctr);

    // ---- scores ----
    scores_mfma<<<5056, 256, 0, stream>>>(hsb, Woutb, bout, ochars, out);
}

// Round 6
// 843.034 us; speedup vs baseline: 1.7230x; 1.1086x over previous
//
#include <hip/hip_runtime.h>
#include <hip/hip_bf16.h>
#include <math.h>

#define TT   256
#define FF   32
#define CCH  8
#define VV   10000
#define HH   1024
#define EE   256
#define NG   3072        // gate cols r|z|n (original order: g*1024 + j)
#define EOS_ID 2
#define NSTEPS 40
#define CHAIN_BLKS 256
#define NLEAF 32
#define CTR_INTS (64 + NSTEPS * NLEAF * 16)

typedef __attribute__((ext_vector_type(8))) short bf16x8;
typedef __attribute__((ext_vector_type(4))) float f32x4;

__device__ __forceinline__ void gload_lds16(const void* g, void* l) {
    __builtin_amdgcn_global_load_lds((const __attribute__((address_space(1))) void*)g,
                                     (__attribute__((address_space(3))) void*)l,
                                     16, 0, 0);
}

__device__ __forceinline__ float sigmf(float x) { return 1.f / (1.f + __expf(-x)); }

// ---------------------------------------------------------------------------
// prep: decoder ids c_in[t][f], entry-done flags, zero barrier counters
// ---------------------------------------------------------------------------
__global__ __launch_bounds__(256) void prep_kernel(const int* __restrict__ oc,
                                                   int* __restrict__ c_in,
                                                   unsigned char* __restrict__ done,
                                                   int* __restrict__ ctr) {
    int t = threadIdx.x;
    for (int i = t; i < CTR_INTS; i += 256) ctr[i] = 0;
    int c0 = oc[0];
    bool d = (c0 == EOS_ID);
    for (int f = 0; f < FF; ++f) {
        c_in[t * FF + f] = (f == 0) ? c0 : oc[1 + t * FF + f - 1];
        done[t * FF + f] = d ? 1 : 0;
        d = d || (oc[1 + t * FF + f] == EOS_ID);
    }
}

// ---------------------------------------------------------------------------
// h0 (fp32) + A0 = bf16(h0)
// ---------------------------------------------------------------------------
__global__ __launch_bounds__(256) void h0_kernel(const float* __restrict__ tctx,
                                                 const int* __restrict__ sent,
                                                 float* __restrict__ h,
                                                 __hip_bfloat16* __restrict__ A0) {
    int t = blockIdx.x;
    int tid = threadIdx.x;
    __shared__ int xt[CCH];
    if (tid < CCH) xt[tid] = sent[(t * CCH + tid) * 3 + 1];
    __syncthreads();
#pragma unroll
    for (int jj = 0; jj < 4; ++jj) {
        int j = tid + jj * 256;
        float s = 0.f;
#pragma unroll
        for (int c = 0; c < CCH; ++c) s += tctx[(size_t)xt[c] * HH + j];
        float hv = s * 0.125f;
        h[(size_t)t * HH + j] = hv;
        A0[(size_t)t * HH + j] = __float2bfloat16(hv);
    }
}

// ---------------------------------------------------------------------------
// generic fp32 -> bf16
// ---------------------------------------------------------------------------
__global__ __launch_bounds__(256) void f2b_kernel(const float* __restrict__ src,
                                                  __hip_bfloat16* __restrict__ dst) {
    size_t base = ((size_t)blockIdx.x * 256 + threadIdx.x) * 4;
    float4 v = *(const float4*)(src + base);
    dst[base + 0] = __float2bfloat16(v.x);
    dst[base + 1] = __float2bfloat16(v.y);
    dst[base + 2] = __float2bfloat16(v.z);
    dst[base + 3] = __float2bfloat16(v.w);
}

// ---------------------------------------------------------------------------
// Build gate-interleaved, 128-padded Bg from Whh (3072x1024 fp32):
//   Bg[(jb*128 + g*32 + ji)][k] = bf16(Whh[g*1024 + jb*32 + ji][k]), g<3
// ---------------------------------------------------------------------------
__global__ __launch_bounds__(256) void build_Bg(const float* __restrict__ Whh,
                                                __hip_bfloat16* __restrict__ Bg) {
    int by = blockIdx.x;           // row n' in [0,4096)
    int tid = threadIdx.x;
    int jbrow = by & 127;          // g*32+ji
    int jb = by >> 7;
    int g = jbrow >> 5, ji = jbrow & 31;
    __hip_bfloat16* drow = Bg + (size_t)by * HH;
    if (g < 3) {
        const float* srow = Whh + (size_t)(g * 1024 + jb * 32 + ji) * HH;
        float4 v = *(const float4*)(srow + tid * 4);
        drow[tid * 4 + 0] = __float2bfloat16(v.x);
        drow[tid * 4 + 1] = __float2bfloat16(v.y);
        drow[tid * 4 + 2] = __float2bfloat16(v.z);
        drow[tid * 4 + 3] = __float2bfloat16(v.w);
    } else {
        __hip_bfloat16 z = __float2bfloat16(0.f);
        drow[tid * 4 + 0] = z; drow[tid * 4 + 1] = z;
        drow[tid * 4 + 2] = z; drow[tid * 4 + 3] = z;
    }
}

// ---------------------------------------------------------------------------
// Pipelined 128x128 MFMA GEMM (validated) for x-side gi tables.
// MODE 1: enc rows gathered emb_bf[sent char]; MODE 2: dec rows emb_bf[c_in]
// ---------------------------------------------------------------------------
template<int MODE>
__global__ __launch_bounds__(256) void gemm_pipe(const __hip_bfloat16* __restrict__ A, int lda,
                                                 const __hip_bfloat16* __restrict__ B, int ldb,
                                                 float* __restrict__ C,
                                                 const int* __restrict__ idsrc,
                                                 int NIT) {
    __shared__ __hip_bfloat16 As[4][128 * 32];
    __shared__ __hip_bfloat16 Bs[4][128 * 32];
    __shared__ int sids[128];

    const int tid = threadIdx.x;
    const int n0 = blockIdx.x * 128;
    const int m0 = blockIdx.y * 128;

    if (tid < 128) {
        int row = m0 + tid;
        int t = row & 255;
        int id;
        if (MODE == 1) { int c = row >> 8; id = idsrc[(t * CCH + c) * 3 + 2]; }
        else           { int f = row >> 8; id = idsrc[t * FF + f]; }
        sids[tid] = id;
    }
    __syncthreads();

    const int srow = tid >> 2, skq = tid & 3;
    const int l = tid & 63;
    const int w = tid >> 6;
    const int wr = (w >> 1) * 64, wc = (w & 1) * 64;
    const int fra = ((wr + (l & 15)) << 5) + ((l >> 4) << 3);
    const int frb = ((wc + (l & 15)) << 5) + ((l >> 4) << 3);

    f32x4 acc[4][4];
#pragma unroll
    for (int i = 0; i < 4; ++i)
#pragma unroll
        for (int j = 0; j < 4; ++j) acc[i][j] = (f32x4){0.f, 0.f, 0.f, 0.f};

    auto stage = [&](int slot, int it) {
        const int k0 = it * 32;
        const __hip_bfloat16* ga0 = A + (size_t)sids[srow] * lda + k0 + skq * 8;
        const __hip_bfloat16* ga1 = A + (size_t)sids[64 + srow] * lda + k0 + skq * 8;
        const __hip_bfloat16* gb0 = B + (size_t)(n0 + srow) * ldb + k0 + skq * 8;
        const __hip_bfloat16* gb1 = B + (size_t)(n0 + 64 + srow) * ldb + k0 + skq * 8;
        __hip_bfloat16* lA = &As[slot][tid * 8];
        __hip_bfloat16* lB = &Bs[slot][tid * 8];
        gload_lds16(ga0, lA);
        gload_lds16(ga1, lA + 2048);
        gload_lds16(gb0, lB);
        gload_lds16(gb1, lB + 2048);
    };

    stage(0, 0);
    stage(1, 1);

    for (int it = 0; it < NIT; ++it) {
        if (it + 2 < NIT) stage((it + 2) & 3, it + 2);
        int ahead = NIT - 1 - it; if (ahead > 2) ahead = 2;
        if (ahead >= 2)      asm volatile("s_waitcnt vmcnt(8)" ::: "memory");
        else if (ahead == 1) asm volatile("s_waitcnt vmcnt(4)" ::: "memory");
        else                 asm volatile("s_waitcnt vmcnt(0)" ::: "memory");
        __builtin_amdgcn_s_barrier();
        __builtin_amdgcn_sched_barrier(0);

        const __hip_bfloat16* cA = As[it & 3];
        const __hip_bfloat16* cB = Bs[it & 3];
        bf16x8 af[4], bfv[4];
#pragma unroll
        for (int fm = 0; fm < 4; ++fm) af[fm] = *(const bf16x8*)&cA[fra + fm * 512];
#pragma unroll
        for (int fn = 0; fn < 4; ++fn) bfv[fn] = *(const bf16x8*)&cB[frb + fn * 512];
#pragma unroll
        for (int fm = 0; fm < 4; ++fm)
#pragma unroll
            for (int fn = 0; fn < 4; ++fn)
                acc[fm][fn] = __builtin_amdgcn_mfma_f32_16x16x32_bf16(af[fm], bfv[fn], acc[fm][fn], 0, 0, 0);
    }

    const int colb = wc + (l & 15);
    const int rb   = wr + ((l >> 4) << 2);
#pragma unroll
    for (int fm = 0; fm < 4; ++fm)
#pragma unroll
        for (int fn = 0; fn < 4; ++fn)
#pragma unroll
            for (int q = 0; q < 4; ++q)
                C[(size_t)(m0 + rb + fm * 16 + q) * NG + n0 + colb + fn * 16] = acc[fm][fn][q];
}

// ---------------------------------------------------------------------------
// Persistent chain v3: 256 blocks = (mt 0..7 x 32 rows, jb 0..31 x 32 j).
// No release/acquire in the loop: A ping-pong via sc0/sc1 write-through stores
// + forced-miss register loads (A never cached -> replay-safe); B via
// global_load_lds stays L2-resident. Two-level relaxed barrier; gi prefetch
// for s+1 overlaps the barrier wait.
// ---------------------------------------------------------------------------
__global__ __launch_bounds__(256) void chain_kernel(
    __hip_bfloat16* Abuf0, __hip_bfloat16* Abuf1,
    const __hip_bfloat16* __restrict__ Bg_e,
    const __hip_bfloat16* __restrict__ Bg_d,
    const float* __restrict__ gi_enc, const float* __restrict__ gi_dec,
    const float* __restrict__ ebih, const float* __restrict__ ebhh,
    const float* __restrict__ dbih, const float* __restrict__ dbhh,
    const float* __restrict__ hA,
    __hip_bfloat16* __restrict__ hsb,
    const unsigned char* __restrict__ dflags,
    int* ctr) {

    // 3 B-slots x 12288 = 36864; gp (32x100 f32 = 12800) reuses slots 0-1
    __shared__ __align__(16) char smem[50176];

    const int tid = threadIdx.x;
    const int b = blockIdx.x;
    const int mt = b >> 5, jb = b & 31;
    const int m0 = mt * 32;
    const int lb = b >> 3;               // leaf index, 8 blocks/leaf

    const int l = tid & 63, w = tid >> 6;
    const int wr = (w >> 1) * 16;        // wave M offset (2x2 wave grid)
    const int wc = (w & 1) * 48;         // wave N offset
    const int ji = tid & 31;
    const int tr0 = tid >> 5;            // 0..7
    const int j = jb * 32 + ji;

    float hreg[4];
#pragma unroll
    for (int p = 0; p < 4; ++p)
        hreg[p] = hA[(size_t)(m0 + p * 8 + tr0) * HH + j];

    // gi registers for the CURRENT step (prefetched across barriers)
    float gr[4], gz[4], gn_[4];
#pragma unroll
    for (int p = 0; p < 4; ++p) {
        const float* gb = gi_enc + (size_t)(m0 + p * 8 + tr0) * NG + j;
        gr[p] = gb[0]; gz[p] = gb[HH]; gn_[p] = gb[2 * HH];
    }

    for (int s = 0; s < NSTEPS; ++s) {
        const __hip_bfloat16* Ab = (s & 1) ? Abuf1 : Abuf0;
        __hip_bfloat16* An = (s & 1) ? Abuf0 : Abuf1;
        const __hip_bfloat16* Bg = (s < CCH) ? Bg_e : Bg_d;
        const float* bih = (s < CCH) ? ebih : dbih;
        const float* bhh = (s < CCH) ? ebhh : dbhh;

        // per-lane A fragment base: row = m0+wr+(l&15), elem off (l>>4)*8
        const __hip_bfloat16* aptr = Ab + (size_t)(m0 + wr + (l & 15)) * HH + ((l >> 4) << 3);

        bf16x8 av[3][2];                  // A frag ring (depth 3), kh halves
        f32x4 acc[3];
        acc[0] = (f32x4){0.f, 0.f, 0.f, 0.f};
        acc[1] = (f32x4){0.f, 0.f, 0.f, 0.f};
        acc[2] = (f32x4){0.f, 0.f, 0.f, 0.f};

        auto stageB = [&](int slot, int it) {
            char* sb = smem + slot * 12288;
#pragma unroll
            for (int c = 0; c < 3; ++c) {
                int chunk = c * 256 + tid;
                int row = chunk >> 3, q = chunk & 7;
                const __hip_bfloat16* src =
                    Bg + (size_t)(jb * 128 + row) * HH + it * 64 + ((q ^ (row & 7)) << 3);
                gload_lds16(src, sb + chunk * 16);
            }
        };
        auto stageA = [&](int slot, int it) {
            const __hip_bfloat16* a0 = aptr + it * 64;
            asm volatile("global_load_dwordx4 %0, %1, off sc0 sc1"
                         : "=v"(av[slot][0]) : "v"(a0));
            asm volatile("global_load_dwordx4 %0, %1, off sc0 sc1"
                         : "=v"(av[slot][1]) : "v"(a0 + 32));
        };

        stageB(0, 0); stageA(0, 0);      // 5 vmem per stage (3 B + 2 A)
        stageB(1, 1); stageA(1, 1);

#pragma unroll
        for (int it = 0; it < 16; ++it) {
            if (it + 2 < 16) { stageB((it + 2) % 3, it + 2); stageA((it + 2) % 3, it + 2); }
            const int ahead = (15 - it) > 2 ? 2 : (15 - it);
            if (ahead >= 2)      asm volatile("s_waitcnt vmcnt(10)" ::: "memory");
            else if (ahead == 1) asm volatile("s_waitcnt vmcnt(5)" ::: "memory");
            else                 asm volatile("s_waitcnt vmcnt(0)" ::: "memory");
            __builtin_amdgcn_s_barrier();
            __builtin_amdgcn_sched_barrier(0);

            const __hip_bfloat16* cB = (const __hip_bfloat16*)(smem + (it % 3) * 12288);
#pragma unroll
            for (int kh = 0; kh < 2; ++kh) {
                const int qg = kh * 4 + (l >> 4);
                bf16x8 bf0, bf1, bf2;
                { int r_ = wc + (l & 15);      bf0 = *(const bf16x8*)&cB[r_ * 64 + ((qg ^ (r_ & 7)) << 3)]; }
                { int r_ = wc + 16 + (l & 15); bf1 = *(const bf16x8*)&cB[r_ * 64 + ((qg ^ (r_ & 7)) << 3)]; }
                { int r_ = wc + 32 + (l & 15); bf2 = *(const bf16x8*)&cB[r_ * 64 + ((qg ^ (r_ & 7)) << 3)]; }
                acc[0] = __builtin_amdgcn_mfma_f32_16x16x32_bf16(av[it % 3][kh], bf0, acc[0], 0, 0, 0);
                acc[1] = __builtin_amdgcn_mfma_f32_16x16x32_bf16(av[it % 3][kh], bf1, acc[1], 0, 0, 0);
                acc[2] = __builtin_amdgcn_mfma_f32_16x16x32_bf16(av[it % 3][kh], bf2, acc[2], 0, 0, 0);
            }
        }

        __syncthreads();   // all frag reads done before LDS reuse

        // ---- dump acc to LDS as gp[32][100] fp32 ----
        float* gp = (float*)smem;
        {
            const int rb = wr + ((l >> 4) << 2);
#pragma unroll
            for (int fn = 0; fn < 3; ++fn)
#pragma unroll
                for (int q = 0; q < 4; ++q)
                    gp[(rb + q) * 100 + wc + fn * 16 + (l & 15)] = acc[fn][q];
        }
        __syncthreads();

        // ---- fused GRU epilogue ----
        const int f = s - CCH;
#pragma unroll
        for (int p = 0; p < 4; ++p) {
            const int tr = p * 8 + tr0;
            const int t = m0 + tr;
            float racc = gp[tr * 100 + ji];
            float zacc = gp[tr * 100 + 32 + ji];
            float nacc = gp[tr * 100 + 64 + ji];
            float r = sigmf(gr[p] + bih[j] + racc + bhh[j]);
            float z = sigmf(gz[p] + bih[HH + j] + zacc + bhh[HH + j]);
            float n = tanhf(gn_[p] + bih[2 * HH + j] + r * (nacc + bhh[2 * HH + j]));
            float hold = hreg[p];
            float hv = (1.f - z) * n + z * hold;
            if (s >= CCH && dflags[t * FF + f]) hv = hold;
            hreg[p] = hv;
            __hip_bfloat16 hb = __float2bfloat16(hv);
            if (s < NSTEPS - 1) {
                unsigned short us = *(unsigned short*)&hb;
                int val = us;
                const __hip_bfloat16* sa = An + (size_t)t * HH + j;
                asm volatile("global_store_short %0, %1, off sc0 sc1"
                             :: "v"(sa), "v"(val) : "memory");
            }
            if (s >= CCH) hsb[((size_t)f * TT + t) * HH + j] = hb;
        }

        // ---- relaxed 2-level grid barrier; gi(s+1) prefetch overlaps poll ----
        if (s < NSTEPS - 1) {
            asm volatile("s_waitcnt vmcnt(0)" ::: "memory");  // A write-through done
            __syncthreads();
            int* root = ctr + s;
            if (tid == 0) {
                int* leaf = ctr + 64 + (s * NLEAF + lb) * 16;
                int old = __hip_atomic_fetch_add(leaf, 1, __ATOMIC_RELAXED, __HIP_MEMORY_SCOPE_AGENT);
                if (old == (CHAIN_BLKS / NLEAF) - 1)
                    __hip_atomic_fetch_add(root, 1, __ATOMIC_RELAXED, __HIP_MEMORY_SCOPE_AGENT);
            }
            {   // prefetch next step's gi while the barrier settles
                const float* gnext = (s + 1 < CCH) ? (gi_enc + (size_t)(s + 1) * TT * NG)
                                                   : (gi_dec + (size_t)(s + 1 - CCH) * TT * NG);
#pragma unroll
                for (int p = 0; p < 4; ++p) {
                    const float* gb = gnext + (size_t)(m0 + p * 8 + tr0) * NG + j;
                    gr[p] = gb[0]; gz[p] = gb[HH]; gn_[p] = gb[2 * HH];
                }
            }
            if (tid == 0) {
                long guard = 0;
                while (__hip_atomic_load(root, __ATOMIC_RELAXED, __HIP_MEMORY_SCOPE_AGENT) < NLEAF
                       && ++guard < (1L << 24)) {
                    __builtin_amdgcn_s_sleep(2);
                }
            }
            __syncthreads();
        }
    }
}

// ---------------------------------------------------------------------------
// scores (validated): 128x128 MFMA, single-buffer 2-barrier core
// ---------------------------------------------------------------------------
__global__ __launch_bounds__(256) void scores_mfma(const __hip_bfloat16* __restrict__ hsb,
                                                   const __hip_bfloat16* __restrict__ Wb,
                                                   const float* __restrict__ bout,
                                                   const int* __restrict__ oc,
                                                   float* __restrict__ out) {
    __shared__ __hip_bfloat16 As[128 * 32], Bs[128 * 32];
    int bid = blockIdx.x;
    int sid = (bid & 7) * 632 + (bid >> 3);      // 5056 = 8*632, bijective
    int bx = sid % 79, by = sid / 79;
    int n0 = bx * 128, m0 = by * 128;

    const int tid = threadIdx.x;
    const int l = tid & 63;
    const int w = tid >> 6;
    const int wr = (w >> 1) * 64, wc = (w & 1) * 64;
    const int srow = tid >> 2, skq = tid & 3;

    f32x4 acc[4][4];
#pragma unroll
    for (int i = 0; i < 4; ++i)
#pragma unroll
        for (int j = 0; j < 4; ++j) acc[i][j] = (f32x4){0.f, 0.f, 0.f, 0.f};

    const int ar0 = m0 + srow, ar1 = m0 + 64 + srow;
    int br0 = n0 + srow, br1 = n0 + 64 + srow;
    br0 = (br0 > VV - 1) ? VV - 1 : br0;
    br1 = (br1 > VV - 1) ? VV - 1 : br1;
    const __hip_bfloat16* gA0 = hsb + (size_t)ar0 * HH + skq * 8;
    const __hip_bfloat16* gA1 = hsb + (size_t)ar1 * HH + skq * 8;
    const __hip_bfloat16* gB0 = Wb + (size_t)br0 * HH + skq * 8;
    const __hip_bfloat16* gB1 = Wb + (size_t)br1 * HH + skq * 8;
    __hip_bfloat16* lA = As + tid * 8;
    __hip_bfloat16* lB = Bs + tid * 8;
    const int fra = ((wr + (l & 15)) << 5) + ((l >> 4) << 3);
    const int frb = ((wc + (l & 15)) << 5) + ((l >> 4) << 3);

    for (int k0 = 0; k0 < HH; k0 += 32) {
        __syncthreads();
        gload_lds16(gA0 + k0, lA);
        gload_lds16(gA1 + k0, lA + 2048);
        gload_lds16(gB0 + k0, lB);
        gload_lds16(gB1 + k0, lB + 2048);
        __syncthreads();
        bf16x8 af[4], bfv[4];
#pragma unroll
        for (int fm = 0; fm < 4; ++fm) af[fm] = *(const bf16x8*)&As[fra + fm * 512];
#pragma unroll
        for (int fn = 0; fn < 4; ++fn) bfv[fn] = *(const bf16x8*)&Bs[frb + fn * 512];
#pragma unroll
        for (int fm = 0; fm < 4; ++fm)
#pragma unroll
            for (int fn = 0; fn < 4; ++fn)
                acc[fm][fn] = __builtin_amdgcn_mfma_f32_16x16x32_bf16(af[fm], bfv[fn], acc[fm][fn], 0, 0, 0);
    }

    const bool zf = (oc[0] == EOS_ID);
    const int colb = wc + (l & 15);
    const int rb   = wr + ((l >> 4) << 2);
#pragma unroll
    for (int fn = 0; fn < 4; ++fn) {
        int v = n0 + colb + fn * 16;
        if (v < VV) {
            float bb = bout[v];
#pragma unroll
            for (int fm = 0; fm < 4; ++fm) {
#pragma unroll
                for (int q = 0; q < 4; ++q) {
                    int m = m0 + rb + fm * 16 + q;
                    int f = m >> 8, t = m & 255;
                    out[(size_t)(t * FF + f) * VV + v] = zf ? 0.f : (acc[fm][fn][q] + bb);
                }
            }
        }
    }
}

// ---------------------------------------------------------------------------
extern "C" void kernel_launch(void* const* d_in, const int* in_sizes, int n_in,
                              void* d_out, int out_size, void* d_ws, size_t ws_size,
                              hipStream_t stream) {
    (void)in_sizes; (void)n_in; (void)ws_size;

    const float* token_ctx = (const float*)d_in[0];
    const float* emb       = (const float*)d_in[1];
    const float* eWih      = (const float*)d_in[2];
    const float* eWhh      = (const float*)d_in[3];
    const float* ebih      = (const float*)d_in[4];
    const float* ebhh      = (const float*)d_in[5];
    const float* dWih      = (const float*)d_in[6];
    const float* dWhh      = (const float*)d_in[7];
    const float* dbih      = (const float*)d_in[8];
    const float* dbhh      = (const float*)d_in[9];
    const float* Wout      = (const float*)d_in[10];
    const float* bout      = (const float*)d_in[11];
    const int*   sent      = (const int*)d_in[12];
    const int*   ochars    = (const int*)d_in[13];
    float* out = (float*)d_out;

    // ---- ws layout (~40 MB) ----
    char* w = (char*)d_ws;
    float* hA = (float*)w;                      w += (size_t)TT * HH * 4;        // 1 MB
    __hip_bfloat16* Ab0 = (__hip_bfloat16*)w;   w += (size_t)TT * HH * 2;        // 0.5 MB
    __hip_bfloat16* Ab1 = (__hip_bfloat16*)w;   w += (size_t)TT * HH * 2;        // 0.5 MB
    __hip_bfloat16* hsb = (__hip_bfloat16*)w;   w += (size_t)FF * TT * HH * 2;   // 16.8 MB
    __hip_bfloat16* Woutb = (__hip_bfloat16*)w; w += (size_t)VV * HH * 2;        // 20.5 MB
    int* c_in = (int*)w;                        w += (size_t)TT * FF * 4;
    unsigned char* done = (unsigned char*)w;    w += (size_t)TT * FF;
    w = (char*)(((size_t)w + 255) & ~(size_t)255);
    int* ctr = (int*)w;                         w += (size_t)CTR_INTS * 4;       // 82 KB

    // ---- d_out tail scratch (dead until scores_mfma) ----
    char* tail = (char*)d_out + (size_t)out_size * 4;
    tail -= (size_t)32 * 128 * HH * 2;    __hip_bfloat16* Bg_e = (__hip_bfloat16*)tail;   // 8.4 MB
    tail -= (size_t)32 * 128 * HH * 2;    __hip_bfloat16* Bg_d = (__hip_bfloat16*)tail;   // 8.4 MB
    tail -= (size_t)CCH * TT * NG * 4;    float* gi_enc = (float*)tail;                   // 25.2 MB
    tail -= (size_t)FF * TT * NG * 4;     float* gi_dec = (float*)tail;                   // 100.7 MB
    tail -= (size_t)VV * EE * 2;          __hip_bfloat16* emb_bf = (__hip_bfloat16*)tail; // 5.1 MB
    tail -= (size_t)NG * EE * 2;          __hip_bfloat16* Wihb_e = (__hip_bfloat16*)tail;
    tail -= (size_t)NG * EE * 2;          __hip_bfloat16* Wihb_d = (__hip_bfloat16*)tail;

    // ---- prep & conversions ----
    prep_kernel<<<1, 256, 0, stream>>>(ochars, c_in, done, ctr);
    h0_kernel<<<TT, 256, 0, stream>>>(token_ctx, sent, hA, Ab0);
    f2b_kernel<<<(VV * EE) / 4 / 256, 256, 0, stream>>>(emb, emb_bf);
    f2b_kernel<<<(NG * EE) / 4 / 256, 256, 0, stream>>>(eWih, Wihb_e);
    f2b_kernel<<<(NG * EE) / 4 / 256, 256, 0, stream>>>(dWih, Wihb_d);
    f2b_kernel<<<(VV * HH) / 4 / 256, 256, 0, stream>>>(Wout, Woutb);
    build_Bg<<<4096, 256, 0, stream>>>(eWhh, Bg_e);
    build_Bg<<<4096, 256, 0, stream>>>(dWhh, Bg_d);

    // ---- x-side tables: gi = emb_bf[ids] @ Wih^T (fp32, gate order g*1024+j) ----
    gemm_pipe<1><<<dim3(24, 16), 256, 0, stream>>>(emb_bf, EE, Wihb_e, EE, gi_enc, sent, 8);
    gemm_pipe<2><<<dim3(24, 64), 256, 0, stream>>>(emb_bf, EE, Wihb_d, EE, gi_dec, c_in, 8);

    // ---- persistent recurrent chain ----
    chain_kernel<<<CHAIN_BLKS, 256, 0, stream>>>(Ab0, Ab1, Bg_e, Bg_d,
                                                 gi_enc, gi_dec,
                                                 ebih, ebhh, dbih, dbhh,
                                                 hA, hsb, done, ctr);

    // ---- scores ----
    scores_mfma<<<5056, 256, 0, stream>>>(hsb, Woutb, bout, ochars, out);
}

// Round 7
// 836.926 us; speedup vs baseline: 1.7356x; 1.0073x over previous
//
#include <hip/hip_runtime.h>
#include <hip/hip_bf16.h>
#include <math.h>

#define TT   256
#define FF   32
#define CCH  8
#define VV   10000
#define HH   1024
#define EE   256
#define NG   3072        // gate cols r|z|n (original order: g*1024 + j)
#define EOS_ID 2
#define NSTEPS 40
#define CHAIN_BLKS 256
#define NLEAF 32
#define CTR_INTS (64 + NSTEPS * NLEAF * 16)

typedef __attribute__((ext_vector_type(8))) short bf16x8;
typedef __attribute__((ext_vector_type(4))) float f32x4;

__device__ __forceinline__ void gload_lds16(const void* g, void* l) {
    __builtin_amdgcn_global_load_lds((const __attribute__((address_space(1))) void*)g,
                                     (__attribute__((address_space(3))) void*)l,
                                     16, 0, 0);
}

__device__ __forceinline__ float sigmf(float x) { return 1.f / (1.f + __expf(-x)); }

// ---------------------------------------------------------------------------
// prep: decoder ids c_in[t][f], entry-done flags, zero barrier counters
// ---------------------------------------------------------------------------
__global__ __launch_bounds__(256) void prep_kernel(const int* __restrict__ oc,
                                                   int* __restrict__ c_in,
                                                   unsigned char* __restrict__ done,
                                                   int* __restrict__ ctr) {
    int t = threadIdx.x;
    for (int i = t; i < CTR_INTS; i += 256) ctr[i] = 0;
    int c0 = oc[0];
    bool d = (c0 == EOS_ID);
    for (int f = 0; f < FF; ++f) {
        c_in[t * FF + f] = (f == 0) ? c0 : oc[1 + t * FF + f - 1];
        done[t * FF + f] = d ? 1 : 0;
        d = d || (oc[1 + t * FF + f] == EOS_ID);
    }
}

// ---------------------------------------------------------------------------
// h0 (fp32) + A0 = bf16(h0)
// ---------------------------------------------------------------------------
__global__ __launch_bounds__(256) void h0_kernel(const float* __restrict__ tctx,
                                                 const int* __restrict__ sent,
                                                 float* __restrict__ h,
                                                 __hip_bfloat16* __restrict__ A0) {
    int t = blockIdx.x;
    int tid = threadIdx.x;
    __shared__ int xt[CCH];
    if (tid < CCH) xt[tid] = sent[(t * CCH + tid) * 3 + 1];
    __syncthreads();
#pragma unroll
    for (int jj = 0; jj < 4; ++jj) {
        int j = tid + jj * 256;
        float s = 0.f;
#pragma unroll
        for (int c = 0; c < CCH; ++c) s += tctx[(size_t)xt[c] * HH + j];
        float hv = s * 0.125f;
        h[(size_t)t * HH + j] = hv;
        A0[(size_t)t * HH + j] = __float2bfloat16(hv);
    }
}

// ---------------------------------------------------------------------------
// generic fp32 -> bf16
// ---------------------------------------------------------------------------
__global__ __launch_bounds__(256) void f2b_kernel(const float* __restrict__ src,
                                                  __hip_bfloat16* __restrict__ dst) {
    size_t base = ((size_t)blockIdx.x * 256 + threadIdx.x) * 4;
    float4 v = *(const float4*)(src + base);
    dst[base + 0] = __float2bfloat16(v.x);
    dst[base + 1] = __float2bfloat16(v.y);
    dst[base + 2] = __float2bfloat16(v.z);
    dst[base + 3] = __float2bfloat16(v.w);
}

// ---------------------------------------------------------------------------
// Build gate-interleaved, 128-padded Bg from Whh (3072x1024 fp32):
//   Bg[(jb*128 + g*32 + ji)][k] = bf16(Whh[g*1024 + jb*32 + ji][k]), g<3
// ---------------------------------------------------------------------------
__global__ __launch_bounds__(256) void build_Bg(const float* __restrict__ Whh,
                                                __hip_bfloat16* __restrict__ Bg) {
    int by = blockIdx.x;           // row n' in [0,4096)
    int tid = threadIdx.x;
    int jbrow = by & 127;          // g*32+ji
    int jb = by >> 7;
    int g = jbrow >> 5, ji = jbrow & 31;
    __hip_bfloat16* drow = Bg + (size_t)by * HH;
    if (g < 3) {
        const float* srow = Whh + (size_t)(g * 1024 + jb * 32 + ji) * HH;
        float4 v = *(const float4*)(srow + tid * 4);
        drow[tid * 4 + 0] = __float2bfloat16(v.x);
        drow[tid * 4 + 1] = __float2bfloat16(v.y);
        drow[tid * 4 + 2] = __float2bfloat16(v.z);
        drow[tid * 4 + 3] = __float2bfloat16(v.w);
    } else {
        __hip_bfloat16 z = __float2bfloat16(0.f);
        drow[tid * 4 + 0] = z; drow[tid * 4 + 1] = z;
        drow[tid * 4 + 2] = z; drow[tid * 4 + 3] = z;
    }
}

// ---------------------------------------------------------------------------
// Pipelined 128x128 MFMA GEMM (validated) for x-side gi tables.
// MODE 1: enc rows gathered emb_bf[sent char]; MODE 2: dec rows emb_bf[c_in]
// ---------------------------------------------------------------------------
template<int MODE>
__global__ __launch_bounds__(256) void gemm_pipe(const __hip_bfloat16* __restrict__ A, int lda,
                                                 const __hip_bfloat16* __restrict__ B, int ldb,
                                                 float* __restrict__ C,
                                                 const int* __restrict__ idsrc,
                                                 int NIT) {
    __shared__ __hip_bfloat16 As[4][128 * 32];
    __shared__ __hip_bfloat16 Bs[4][128 * 32];
    __shared__ int sids[128];

    const int tid = threadIdx.x;
    const int n0 = blockIdx.x * 128;
    const int m0 = blockIdx.y * 128;

    if (tid < 128) {
        int row = m0 + tid;
        int t = row & 255;
        int id;
        if (MODE == 1) { int c = row >> 8; id = idsrc[(t * CCH + c) * 3 + 2]; }
        else           { int f = row >> 8; id = idsrc[t * FF + f]; }
        sids[tid] = id;
    }
    __syncthreads();

    const int srow = tid >> 2, skq = tid & 3;
    const int l = tid & 63;
    const int w = tid >> 6;
    const int wr = (w >> 1) * 64, wc = (w & 1) * 64;
    const int fra = ((wr + (l & 15)) << 5) + ((l >> 4) << 3);
    const int frb = ((wc + (l & 15)) << 5) + ((l >> 4) << 3);

    f32x4 acc[4][4];
#pragma unroll
    for (int i = 0; i < 4; ++i)
#pragma unroll
        for (int j = 0; j < 4; ++j) acc[i][j] = (f32x4){0.f, 0.f, 0.f, 0.f};

    auto stage = [&](int slot, int it) {
        const int k0 = it * 32;
        const __hip_bfloat16* ga0 = A + (size_t)sids[srow] * lda + k0 + skq * 8;
        const __hip_bfloat16* ga1 = A + (size_t)sids[64 + srow] * lda + k0 + skq * 8;
        const __hip_bfloat16* gb0 = B + (size_t)(n0 + srow) * ldb + k0 + skq * 8;
        const __hip_bfloat16* gb1 = B + (size_t)(n0 + 64 + srow) * ldb + k0 + skq * 8;
        __hip_bfloat16* lA = &As[slot][tid * 8];
        __hip_bfloat16* lB = &Bs[slot][tid * 8];
        gload_lds16(ga0, lA);
        gload_lds16(ga1, lA + 2048);
        gload_lds16(gb0, lB);
        gload_lds16(gb1, lB + 2048);
    };

    stage(0, 0);
    stage(1, 1);

    for (int it = 0; it < NIT; ++it) {
        if (it + 2 < NIT) stage((it + 2) & 3, it + 2);
        int ahead = NIT - 1 - it; if (ahead > 2) ahead = 2;
        if (ahead >= 2)      asm volatile("s_waitcnt vmcnt(8)" ::: "memory");
        else if (ahead == 1) asm volatile("s_waitcnt vmcnt(4)" ::: "memory");
        else                 asm volatile("s_waitcnt vmcnt(0)" ::: "memory");
        __builtin_amdgcn_s_barrier();
        __builtin_amdgcn_sched_barrier(0);

        const __hip_bfloat16* cA = As[it & 3];
        const __hip_bfloat16* cB = Bs[it & 3];
        bf16x8 af[4], bfv[4];
#pragma unroll
        for (int fm = 0; fm < 4; ++fm) af[fm] = *(const bf16x8*)&cA[fra + fm * 512];
#pragma unroll
        for (int fn = 0; fn < 4; ++fn) bfv[fn] = *(const bf16x8*)&cB[frb + fn * 512];
#pragma unroll
        for (int fm = 0; fm < 4; ++fm)
#pragma unroll
            for (int fn = 0; fn < 4; ++fn)
                acc[fm][fn] = __builtin_amdgcn_mfma_f32_16x16x32_bf16(af[fm], bfv[fn], acc[fm][fn], 0, 0, 0);
    }

    const int colb = wc + (l & 15);
    const int rb   = wr + ((l >> 4) << 2);
#pragma unroll
    for (int fm = 0; fm < 4; ++fm)
#pragma unroll
        for (int fn = 0; fn < 4; ++fn)
#pragma unroll
            for (int q = 0; q < 4; ++q)
                C[(size_t)(m0 + rb + fm * 16 + q) * NG + n0 + colb + fn * 16] = acc[fm][fn][q];
}

// ---------------------------------------------------------------------------
// Persistent chain v4: 256 blocks = (mt 0..7 x 32 t-rows, jb 0..31 x 32 j).
// A: full-step register burst (32x dwordx4 sc0 sc1). B: 3-slot LDS ring,
// L2-resident (no invalidates anywhere). Coalesced An/hsb stores via LDS
// repack. All counted-region loads are ordered inline asm. Relaxed 2-level
// barrier; gi/dflag nt-prefetch overlaps the poll.
// ---------------------------------------------------------------------------
__global__ __launch_bounds__(256, 1) void chain_kernel(
    __hip_bfloat16* Abuf0, __hip_bfloat16* Abuf1,
    const __hip_bfloat16* __restrict__ Bg_e,
    const __hip_bfloat16* __restrict__ Bg_d,
    const float* __restrict__ gi_enc, const float* __restrict__ gi_dec,
    const float* __restrict__ ebih, const float* __restrict__ ebhh,
    const float* __restrict__ dbih, const float* __restrict__ dbhh,
    const float* __restrict__ hA,
    __hip_bfloat16* __restrict__ hsb,
    const unsigned char* __restrict__ dflags,
    int* ctr) {

    // ring 3x12288=36864 | gp 32x100x4=12800 | st 2048
    __shared__ __align__(16) char smem[52224];

    const int tid = threadIdx.x;
    const int b = blockIdx.x;
    const int mt = b >> 5, jb = b & 31;
    const int m0 = mt * 32;
    const int lb = b >> 3;               // leaf index, 8 blocks/leaf

    const int l = tid & 63, w = tid >> 6;
    const int wr = (w >> 1) * 16;        // wave M offset
    const int wc = (w & 1) * 48;         // wave N offset
    const int ji = tid & 31;
    const int tr0 = tid >> 5;            // 0..7
    const int j = jb * 32 + ji;

    float* gp = (float*)(smem + 36864);
    __hip_bfloat16* stb = (__hip_bfloat16*)(smem + 36864 + 12800);

    // persistent h (4 t-rows per thread)
    float hreg[4];
#pragma unroll
    for (int p = 0; p < 4; ++p)
        hreg[p] = hA[(size_t)(m0 + p * 8 + tr0) * HH + j];

    // biases hoisted for both phases (no loads in counted region)
    const float e_br = ebih[j] + ebhh[j];
    const float e_bz = ebih[HH + j] + ebhh[HH + j];
    const float e_bi = ebih[2 * HH + j];
    const float e_bh = ebhh[2 * HH + j];
    const float d_br = dbih[j] + dbhh[j];
    const float d_bz = dbih[HH + j] + dbhh[HH + j];
    const float d_bi = dbih[2 * HH + j];
    const float d_bh = dbhh[2 * HH + j];

    auto stageB = [&](const __hip_bfloat16* Bp, int slot, int it) {
        char* sb = smem + slot * 12288;
#pragma unroll
        for (int c = 0; c < 3; ++c) {
            int chunk = c * 256 + tid;
            int row = chunk >> 3, q = chunk & 7;
            const __hip_bfloat16* src =
                Bp + (size_t)(jb * 128 + row) * HH + it * 64 + ((q ^ (row & 7)) << 3);
            gload_lds16(src, sb + chunk * 16);
        }
    };

    // prestage B slots 0,1 for s=0, then gi for s=0 (asm-ordered, nt)
    stageB(Bg_e, 0, 0);
    stageB(Bg_e, 1, 1);

    float gr[4], gz[4], gn_[4];
    int dfl[4] = {0, 0, 0, 0};
#pragma unroll
    for (int p = 0; p < 4; ++p) {
        const float* gb = gi_enc + (size_t)(m0 + p * 8 + tr0) * NG + j;
        asm volatile("global_load_dword %0, %1, off nt" : "=v"(gr[p])  : "v"(gb));
        asm volatile("global_load_dword %0, %1, off nt" : "=v"(gz[p])  : "v"(gb + HH));
        asm volatile("global_load_dword %0, %1, off nt" : "=v"(gn_[p]) : "v"(gb + 2 * HH));
    }

    for (int s = 0; s < NSTEPS; ++s) {
        const __hip_bfloat16* Ab = (s & 1) ? Abuf1 : Abuf0;
        __hip_bfloat16* An = (s & 1) ? Abuf0 : Abuf1;
        const __hip_bfloat16* Bg = (s < CCH) ? Bg_e : Bg_d;

        // ---- A burst: full step, 32 x dwordx4 sc0 sc1 (ordered) ----
        const __hip_bfloat16* aptr = Ab + (size_t)(m0 + wr + (l & 15)) * HH + ((l >> 4) << 3);
        bf16x8 av[16][2];
#pragma unroll
        for (int it = 0; it < 16; ++it) {
            asm volatile("global_load_dwordx4 %0, %1, off sc0 sc1"
                         : "=v"(av[it][0]) : "v"(aptr + it * 64));
            asm volatile("global_load_dwordx4 %0, %1, off sc0 sc1"
                         : "=v"(av[it][1]) : "v"(aptr + it * 64 + 32));
        }

        f32x4 acc[3];
        acc[0] = (f32x4){0.f, 0.f, 0.f, 0.f};
        acc[1] = (f32x4){0.f, 0.f, 0.f, 0.f};
        acc[2] = (f32x4){0.f, 0.f, 0.f, 0.f};

#pragma unroll
        for (int it = 0; it < 16; ++it) {
            if (it + 2 < 16) stageB(Bg, (it + 2) % 3, it + 2);
            if (it == 0)       asm volatile("s_waitcnt vmcnt(33)" ::: "memory");
            else if (it == 1)  asm volatile("s_waitcnt vmcnt(34)" ::: "memory");
            else if (it <= 13) asm volatile("s_waitcnt vmcnt(6)"  ::: "memory");
            else if (it == 14) asm volatile("s_waitcnt vmcnt(3)"  ::: "memory");
            else               asm volatile("s_waitcnt vmcnt(0)"  ::: "memory");
            __builtin_amdgcn_s_barrier();
            __builtin_amdgcn_sched_barrier(0);

            const __hip_bfloat16* cB = (const __hip_bfloat16*)(smem + (it % 3) * 12288);
#pragma unroll
            for (int kh = 0; kh < 2; ++kh) {
                const int qg = kh * 4 + (l >> 4);
                bf16x8 bf0, bf1, bf2;
                { int r_ = wc + (l & 15);      bf0 = *(const bf16x8*)&cB[r_ * 64 + ((qg ^ (r_ & 7)) << 3)]; }
                { int r_ = wc + 16 + (l & 15); bf1 = *(const bf16x8*)&cB[r_ * 64 + ((qg ^ (r_ & 7)) << 3)]; }
                { int r_ = wc + 32 + (l & 15); bf2 = *(const bf16x8*)&cB[r_ * 64 + ((qg ^ (r_ & 7)) << 3)]; }
                acc[0] = __builtin_amdgcn_mfma_f32_16x16x32_bf16(av[it][kh], bf0, acc[0], 0, 0, 0);
                acc[1] = __builtin_amdgcn_mfma_f32_16x16x32_bf16(av[it][kh], bf1, acc[1], 0, 0, 0);
                acc[2] = __builtin_amdgcn_mfma_f32_16x16x32_bf16(av[it][kh], bf2, acc[2], 0, 0, 0);
            }
        }

        // ---- dump acc to LDS as gp[32][100] fp32 (gp disjoint from ring) ----
        {
            const int rb = wr + ((l >> 4) << 2);
#pragma unroll
            for (int fn = 0; fn < 3; ++fn)
#pragma unroll
                for (int q = 0; q < 4; ++q)
                    gp[(rb + q) * 100 + wc + fn * 16 + (l & 15)] = acc[fn][q];
        }
        __syncthreads();

        // ---- fused GRU epilogue ----
        const int f = s - CCH;
        const float br_ = (s < CCH) ? e_br : d_br;
        const float bz_ = (s < CCH) ? e_bz : d_bz;
        const float bi_ = (s < CCH) ? e_bi : d_bi;
        const float bh_ = (s < CCH) ? e_bh : d_bh;
#pragma unroll
        for (int p = 0; p < 4; ++p) {
            const int tr = p * 8 + tr0;
            float racc = gp[tr * 100 + ji];
            float zacc = gp[tr * 100 + 32 + ji];
            float nacc = gp[tr * 100 + 64 + ji];
            float r = sigmf(gr[p] + br_ + racc);
            float z = sigmf(gz[p] + bz_ + zacc);
            float n = tanhf(gn_[p] + bi_ + r * (nacc + bh_));
            float hold = hreg[p];
            float hv = (1.f - z) * n + z * hold;
            if (s >= CCH && dfl[p]) hv = hold;
            hreg[p] = hv;
            stb[tr * 32 + ji] = __float2bfloat16(hv);
        }
        __syncthreads();

        // ---- coalesced chunk stores (tid<128: one 16B chunk each) ----
        if (tid < 128) {
            const int row = tid >> 2, part = tid & 3;
            bf16x8 v = *(const bf16x8*)&stb[row * 32 + part * 8];
            if (s < NSTEPS - 1) {
                const __hip_bfloat16* ap = An + (size_t)(m0 + row) * HH + jb * 32 + part * 8;
                asm volatile("global_store_dwordx4 %0, %1, off sc0 sc1"
                             :: "v"(ap), "v"(v) : "memory");
            }
            if (s >= CCH) {
                bf16x8* hp = (bf16x8*)(hsb + ((size_t)f * TT + m0 + row) * HH + jb * 32 + part * 8);
                __builtin_nontemporal_store(v, hp);
            }
        }

        // ---- tail: prestage next B, drain, barrier w/ overlapped prefetch ----
        if (s < NSTEPS - 1) {
            const __hip_bfloat16* BgN = (s + 1 < CCH) ? Bg_e : Bg_d;
            stageB(BgN, 0, 0);
            stageB(BgN, 1, 1);
            asm volatile("s_waitcnt vmcnt(6)" ::: "memory");   // stores drained
            __syncthreads();
            int* root = ctr + s;
            if (tid == 0) {
                int* leaf = ctr + 64 + (s * NLEAF + lb) * 16;
                int old = __hip_atomic_fetch_add(leaf, 1, __ATOMIC_RELAXED, __HIP_MEMORY_SCOPE_AGENT);
                if (old == (CHAIN_BLKS / NLEAF) - 1)
                    __hip_atomic_fetch_add(root, 1, __ATOMIC_RELAXED, __HIP_MEMORY_SCOPE_AGENT);
            }
            {   // prefetch next step's gi (+dflags) while the barrier settles
                const float* gnext = (s + 1 < CCH) ? (gi_enc + (size_t)(s + 1) * TT * NG)
                                                   : (gi_dec + (size_t)(s + 1 - CCH) * TT * NG);
#pragma unroll
                for (int p = 0; p < 4; ++p) {
                    const float* gb = gnext + (size_t)(m0 + p * 8 + tr0) * NG + j;
                    asm volatile("global_load_dword %0, %1, off nt" : "=v"(gr[p])  : "v"(gb));
                    asm volatile("global_load_dword %0, %1, off nt" : "=v"(gz[p])  : "v"(gb + HH));
                    asm volatile("global_load_dword %0, %1, off nt" : "=v"(gn_[p]) : "v"(gb + 2 * HH));
                }
                if (s + 1 >= CCH) {
                    const int fnx = s + 1 - CCH;
#pragma unroll
                    for (int p = 0; p < 4; ++p) {
                        const unsigned char* dp = dflags + (size_t)(m0 + p * 8 + tr0) * FF + fnx;
                        asm volatile("global_load_ubyte %0, %1, off" : "=v"(dfl[p]) : "v"(dp));
                    }
                }
            }
            if (tid == 0) {
                long guard = 0;
                while (__hip_atomic_load(root, __ATOMIC_RELAXED, __HIP_MEMORY_SCOPE_AGENT) < NLEAF
                       && ++guard < (1L << 24)) {
                    __builtin_amdgcn_s_sleep(2);
                }
            }
            __syncthreads();
        }
    }
}

// ---------------------------------------------------------------------------
// scores (validated core): 128x128 MFMA + NON-TEMPORAL C-stores (preserve L3)
// ---------------------------------------------------------------------------
__global__ __launch_bounds__(256) void scores_mfma(const __hip_bfloat16* __restrict__ hsb,
                                                   const __hip_bfloat16* __restrict__ Wb,
                                                   const float* __restrict__ bout,
                                                   const int* __restrict__ oc,
                                                   float* __restrict__ out) {
    __shared__ __hip_bfloat16 As[128 * 32], Bs[128 * 32];
    int bid = blockIdx.x;
    int sid = (bid & 7) * 632 + (bid >> 3);      // 5056 = 8*632, bijective
    int bx = sid % 79, by = sid / 79;
    int n0 = bx * 128, m0 = by * 128;

    const int tid = threadIdx.x;
    const int l = tid & 63;
    const int w = tid >> 6;
    const int wr = (w >> 1) * 64, wc = (w & 1) * 64;
    const int srow = tid >> 2, skq = tid & 3;

    f32x4 acc[4][4];
#pragma unroll
    for (int i = 0; i < 4; ++i)
#pragma unroll
        for (int j = 0; j < 4; ++j) acc[i][j] = (f32x4){0.f, 0.f, 0.f, 0.f};

    const int ar0 = m0 + srow, ar1 = m0 + 64 + srow;
    int br0 = n0 + srow, br1 = n0 + 64 + srow;
    br0 = (br0 > VV - 1) ? VV - 1 : br0;
    br1 = (br1 > VV - 1) ? VV - 1 : br1;
    const __hip_bfloat16* gA0 = hsb + (size_t)ar0 * HH + skq * 8;
    const __hip_bfloat16* gA1 = hsb + (size_t)ar1 * HH + skq * 8;
    const __hip_bfloat16* gB0 = Wb + (size_t)br0 * HH + skq * 8;
    const __hip_bfloat16* gB1 = Wb + (size_t)br1 * HH + skq * 8;
    __hip_bfloat16* lA = As + tid * 8;
    __hip_bfloat16* lB = Bs + tid * 8;
    const int fra = ((wr + (l & 15)) << 5) + ((l >> 4) << 3);
    const int frb = ((wc + (l & 15)) << 5) + ((l >> 4) << 3);

    for (int k0 = 0; k0 < HH; k0 += 32) {
        __syncthreads();
        gload_lds16(gA0 + k0, lA);
        gload_lds16(gA1 + k0, lA + 2048);
        gload_lds16(gB0 + k0, lB);
        gload_lds16(gB1 + k0, lB + 2048);
        __syncthreads();
        bf16x8 af[4], bfv[4];
#pragma unroll
        for (int fm = 0; fm < 4; ++fm) af[fm] = *(const bf16x8*)&As[fra + fm * 512];
#pragma unroll
        for (int fn = 0; fn < 4; ++fn) bfv[fn] = *(const bf16x8*)&Bs[frb + fn * 512];
#pragma unroll
        for (int fm = 0; fm < 4; ++fm)
#pragma unroll
            for (int fn = 0; fn < 4; ++fn)
                acc[fm][fn] = __builtin_amdgcn_mfma_f32_16x16x32_bf16(af[fm], bfv[fn], acc[fm][fn], 0, 0, 0);
    }

    const bool zf = (oc[0] == EOS_ID);
    const int colb = wc + (l & 15);
    const int rb   = wr + ((l >> 4) << 2);
#pragma unroll
    for (int fn = 0; fn < 4; ++fn) {
        int v = n0 + colb + fn * 16;
        if (v < VV) {
            float bb = bout[v];
#pragma unroll
            for (int fm = 0; fm < 4; ++fm) {
#pragma unroll
                for (int q = 0; q < 4; ++q) {
                    int m = m0 + rb + fm * 16 + q;
                    int fo = m >> 8, t = m & 255;
                    float val = zf ? 0.f : (acc[fm][fn][q] + bb);
                    __builtin_nontemporal_store(val, &out[(size_t)(t * FF + fo) * VV + v]);
                }
            }
        }
    }
}

// ---------------------------------------------------------------------------
extern "C" void kernel_launch(void* const* d_in, const int* in_sizes, int n_in,
                              void* d_out, int out_size, void* d_ws, size_t ws_size,
                              hipStream_t stream) {
    (void)in_sizes; (void)n_in; (void)ws_size;

    const float* token_ctx = (const float*)d_in[0];
    const float* emb       = (const float*)d_in[1];
    const float* eWih      = (const float*)d_in[2];
    const float* eWhh      = (const float*)d_in[3];
    const float* ebih      = (const float*)d_in[4];
    const float* ebhh      = (const float*)d_in[5];
    const float* dWih      = (const float*)d_in[6];
    const float* dWhh      = (const float*)d_in[7];
    const float* dbih      = (const float*)d_in[8];
    const float* dbhh      = (const float*)d_in[9];
    const float* Wout      = (const float*)d_in[10];
    const float* bout      = (const float*)d_in[11];
    const int*   sent      = (const int*)d_in[12];
    const int*   ochars    = (const int*)d_in[13];
    float* out = (float*)d_out;

    // ---- ws layout (~40 MB) ----
    char* w = (char*)d_ws;
    float* hA = (float*)w;                      w += (size_t)TT * HH * 4;        // 1 MB
    __hip_bfloat16* Ab0 = (__hip_bfloat16*)w;   w += (size_t)TT * HH * 2;        // 0.5 MB
    __hip_bfloat16* Ab1 = (__hip_bfloat16*)w;   w += (size_t)TT * HH * 2;        // 0.5 MB
    __hip_bfloat16* hsb = (__hip_bfloat16*)w;   w += (size_t)FF * TT * HH * 2;   // 16.8 MB
    __hip_bfloat16* Woutb = (__hip_bfloat16*)w; w += (size_t)VV * HH * 2;        // 20.5 MB
    int* c_in = (int*)w;                        w += (size_t)TT * FF * 4;
    unsigned char* done = (unsigned char*)w;    w += (size_t)TT * FF;
    w = (char*)(((size_t)w + 255) & ~(size_t)255);
    int* ctr = (int*)w;                         w += (size_t)CTR_INTS * 4;       // 82 KB

    // ---- d_out tail scratch (dead until scores_mfma) ----
    char* tail = (char*)d_out + (size_t)out_size * 4;
    tail -= (size_t)32 * 128 * HH * 2;    __hip_bfloat16* Bg_e = (__hip_bfloat16*)tail;   // 8.4 MB
    tail -= (size_t)32 * 128 * HH * 2;    __hip_bfloat16* Bg_d = (__hip_bfloat16*)tail;   // 8.4 MB
    tail -= (size_t)CCH * TT * NG * 4;    float* gi_enc = (float*)tail;                   // 25.2 MB
    tail -= (size_t)FF * TT * NG * 4;     float* gi_dec = (float*)tail;                   // 100.7 MB
    tail -= (size_t)VV * EE * 2;          __hip_bfloat16* emb_bf = (__hip_bfloat16*)tail; // 5.1 MB
    tail -= (size_t)NG * EE * 2;          __hip_bfloat16* Wihb_e = (__hip_bfloat16*)tail;
    tail -= (size_t)NG * EE * 2;          __hip_bfloat16* Wihb_d = (__hip_bfloat16*)tail;

    // ---- prep & conversions ----
    prep_kernel<<<1, 256, 0, stream>>>(ochars, c_in, done, ctr);
    h0_kernel<<<TT, 256, 0, stream>>>(token_ctx, sent, hA, Ab0);
    f2b_kernel<<<(VV * EE) / 4 / 256, 256, 0, stream>>>(emb, emb_bf);
    f2b_kernel<<<(NG * EE) / 4 / 256, 256, 0, stream>>>(eWih, Wihb_e);
    f2b_kernel<<<(NG * EE) / 4 / 256, 256, 0, stream>>>(dWih, Wihb_d);
    f2b_kernel<<<(VV * HH) / 4 / 256, 256, 0, stream>>>(Wout, Woutb);
    build_Bg<<<4096, 256, 0, stream>>>(eWhh, Bg_e);
    build_Bg<<<4096, 256, 0, stream>>>(dWhh, Bg_d);

    // ---- x-side tables: gi = emb_bf[ids] @ Wih^T (fp32, gate order g*1024+j) ----
    gemm_pipe<1><<<dim3(24, 16), 256, 0, stream>>>(emb_bf, EE, Wihb_e, EE, gi_enc, sent, 8);
    gemm_pipe<2><<<dim3(24, 64), 256, 0, stream>>>(emb_bf, EE, Wihb_d, EE, gi_dec, c_in, 8);

    // ---- persistent recurrent chain ----
    chain_kernel<<<CHAIN_BLKS, 256, 0, stream>>>(Ab0, Ab1, Bg_e, Bg_d,
                                                 gi_enc, gi_dec,
                                                 ebih, ebhh, dbih, dbhh,
                                                 hA, hsb, done, ctr);

    // ---- scores ----
    scores_mfma<<<5056, 256, 0, stream>>>(hsb, Woutb, bout, ochars, out);
}

// Round 8
// 734.928 us; speedup vs baseline: 1.9765x; 1.1388x over previous
//
#include <hip/hip_runtime.h>
#include <hip/hip_bf16.h>
#include <math.h>

#define TT   256
#define FF   32
#define CCH  8
#define VV   10000
#define HH   1024
#define EE   256
#define NG   3072        // gate cols r|z|n (original order: g*1024 + j)
#define EOS_ID 2
#define NSTEPS 40
#define CHAIN_BLKS 256
#define CTR_INTS 512

typedef __attribute__((ext_vector_type(8))) short bf16x8;
typedef __attribute__((ext_vector_type(4))) float f32x4;

__device__ __forceinline__ void gload_lds16(const void* g, void* l) {
    __builtin_amdgcn_global_load_lds((const __attribute__((address_space(1))) void*)g,
                                     (__attribute__((address_space(3))) void*)l,
                                     16, 0, 0);
}

__device__ __forceinline__ float sigmf(float x) { return 1.f / (1.f + __expf(-x)); }

// ---------------------------------------------------------------------------
// prep: decoder ids c_in[t][f], entry-done flags, zero barrier flags
// ---------------------------------------------------------------------------
__global__ __launch_bounds__(256) void prep_kernel(const int* __restrict__ oc,
                                                   int* __restrict__ c_in,
                                                   unsigned char* __restrict__ done,
                                                   int* __restrict__ ctr) {
    int t = threadIdx.x;
    for (int i = t; i < CTR_INTS; i += 256) ctr[i] = 0;
    int c0 = oc[0];
    bool d = (c0 == EOS_ID);
    for (int f = 0; f < FF; ++f) {
        c_in[t * FF + f] = (f == 0) ? c0 : oc[1 + t * FF + f - 1];
        done[t * FF + f] = d ? 1 : 0;
        d = d || (oc[1 + t * FF + f] == EOS_ID);
    }
}

// ---------------------------------------------------------------------------
// h0 (fp32) + A0 = bf16(h0)
// ---------------------------------------------------------------------------
__global__ __launch_bounds__(256) void h0_kernel(const float* __restrict__ tctx,
                                                 const int* __restrict__ sent,
                                                 float* __restrict__ h,
                                                 __hip_bfloat16* __restrict__ A0) {
    int t = blockIdx.x;
    int tid = threadIdx.x;
    __shared__ int xt[CCH];
    if (tid < CCH) xt[tid] = sent[(t * CCH + tid) * 3 + 1];
    __syncthreads();
#pragma unroll
    for (int jj = 0; jj < 4; ++jj) {
        int j = tid + jj * 256;
        float s = 0.f;
#pragma unroll
        for (int c = 0; c < CCH; ++c) s += tctx[(size_t)xt[c] * HH + j];
        float hv = s * 0.125f;
        h[(size_t)t * HH + j] = hv;
        A0[(size_t)t * HH + j] = __float2bfloat16(hv);
    }
}

// ---------------------------------------------------------------------------
// generic fp32 -> bf16
// ---------------------------------------------------------------------------
__global__ __launch_bounds__(256) void f2b_kernel(const float* __restrict__ src,
                                                  __hip_bfloat16* __restrict__ dst) {
    size_t base = ((size_t)blockIdx.x * 256 + threadIdx.x) * 4;
    float4 v = *(const float4*)(src + base);
    dst[base + 0] = __float2bfloat16(v.x);
    dst[base + 1] = __float2bfloat16(v.y);
    dst[base + 2] = __float2bfloat16(v.z);
    dst[base + 3] = __float2bfloat16(v.w);
}

// ---------------------------------------------------------------------------
// Build gate-interleaved, 128-padded Bg from Whh (3072x1024 fp32):
//   Bg[(jb*128 + g*32 + ji)][k] = bf16(Whh[g*1024 + jb*32 + ji][k]), g<3
// ---------------------------------------------------------------------------
__global__ __launch_bounds__(256) void build_Bg(const float* __restrict__ Whh,
                                                __hip_bfloat16* __restrict__ Bg) {
    int by = blockIdx.x;           // row n' in [0,4096)
    int tid = threadIdx.x;
    int jbrow = by & 127;          // g*32+ji
    int jb = by >> 7;
    int g = jbrow >> 5, ji = jbrow & 31;
    __hip_bfloat16* drow = Bg + (size_t)by * HH;
    if (g < 3) {
        const float* srow = Whh + (size_t)(g * 1024 + jb * 32 + ji) * HH;
        float4 v = *(const float4*)(srow + tid * 4);
        drow[tid * 4 + 0] = __float2bfloat16(v.x);
        drow[tid * 4 + 1] = __float2bfloat16(v.y);
        drow[tid * 4 + 2] = __float2bfloat16(v.z);
        drow[tid * 4 + 3] = __float2bfloat16(v.w);
    } else {
        __hip_bfloat16 z = __float2bfloat16(0.f);
        drow[tid * 4 + 0] = z; drow[tid * 4 + 1] = z;
        drow[tid * 4 + 2] = z; drow[tid * 4 + 3] = z;
    }
}

// ---------------------------------------------------------------------------
// Pipelined 128x128 MFMA GEMM (validated) for x-side gi tables.
// MODE 1: enc rows gathered emb_bf[sent char]; MODE 2: dec rows emb_bf[c_in]
// ---------------------------------------------------------------------------
template<int MODE>
__global__ __launch_bounds__(256) void gemm_pipe(const __hip_bfloat16* __restrict__ A, int lda,
                                                 const __hip_bfloat16* __restrict__ B, int ldb,
                                                 float* __restrict__ C,
                                                 const int* __restrict__ idsrc,
                                                 int NIT) {
    __shared__ __hip_bfloat16 As[4][128 * 32];
    __shared__ __hip_bfloat16 Bs[4][128 * 32];
    __shared__ int sids[128];

    const int tid = threadIdx.x;
    const int n0 = blockIdx.x * 128;
    const int m0 = blockIdx.y * 128;

    if (tid < 128) {
        int row = m0 + tid;
        int t = row & 255;
        int id;
        if (MODE == 1) { int c = row >> 8; id = idsrc[(t * CCH + c) * 3 + 2]; }
        else           { int f = row >> 8; id = idsrc[t * FF + f]; }
        sids[tid] = id;
    }
    __syncthreads();

    const int srow = tid >> 2, skq = tid & 3;
    const int l = tid & 63;
    const int w = tid >> 6;
    const int wr = (w >> 1) * 64, wc = (w & 1) * 64;
    const int fra = ((wr + (l & 15)) << 5) + ((l >> 4) << 3);
    const int frb = ((wc + (l & 15)) << 5) + ((l >> 4) << 3);

    f32x4 acc[4][4];
#pragma unroll
    for (int i = 0; i < 4; ++i)
#pragma unroll
        for (int j = 0; j < 4; ++j) acc[i][j] = (f32x4){0.f, 0.f, 0.f, 0.f};

    auto stage = [&](int slot, int it) {
        const int k0 = it * 32;
        const __hip_bfloat16* ga0 = A + (size_t)sids[srow] * lda + k0 + skq * 8;
        const __hip_bfloat16* ga1 = A + (size_t)sids[64 + srow] * lda + k0 + skq * 8;
        const __hip_bfloat16* gb0 = B + (size_t)(n0 + srow) * ldb + k0 + skq * 8;
        const __hip_bfloat16* gb1 = B + (size_t)(n0 + 64 + srow) * ldb + k0 + skq * 8;
        __hip_bfloat16* lA = &As[slot][tid * 8];
        __hip_bfloat16* lB = &Bs[slot][tid * 8];
        gload_lds16(ga0, lA);
        gload_lds16(ga1, lA + 2048);
        gload_lds16(gb0, lB);
        gload_lds16(gb1, lB + 2048);
    };

    stage(0, 0);
    stage(1, 1);

    for (int it = 0; it < NIT; ++it) {
        if (it + 2 < NIT) stage((it + 2) & 3, it + 2);
        int ahead = NIT - 1 - it; if (ahead > 2) ahead = 2;
        if (ahead >= 2)      asm volatile("s_waitcnt vmcnt(8)" ::: "memory");
        else if (ahead == 1) asm volatile("s_waitcnt vmcnt(4)" ::: "memory");
        else                 asm volatile("s_waitcnt vmcnt(0)" ::: "memory");
        __builtin_amdgcn_s_barrier();
        __builtin_amdgcn_sched_barrier(0);

        const __hip_bfloat16* cA = As[it & 3];
        const __hip_bfloat16* cB = Bs[it & 3];
        bf16x8 af[4], bfv[4];
#pragma unroll
        for (int fm = 0; fm < 4; ++fm) af[fm] = *(const bf16x8*)&cA[fra + fm * 512];
#pragma unroll
        for (int fn = 0; fn < 4; ++fn) bfv[fn] = *(const bf16x8*)&cB[frb + fn * 512];
#pragma unroll
        for (int fm = 0; fm < 4; ++fm)
#pragma unroll
            for (int fn = 0; fn < 4; ++fn)
                acc[fm][fn] = __builtin_amdgcn_mfma_f32_16x16x32_bf16(af[fm], bfv[fn], acc[fm][fn], 0, 0, 0);
    }

    const int colb = wc + (l & 15);
    const int rb   = wr + ((l >> 4) << 2);
#pragma unroll
    for (int fm = 0; fm < 4; ++fm)
#pragma unroll
        for (int fn = 0; fn < 4; ++fn)
#pragma unroll
            for (int q = 0; q < 4; ++q)
                C[(size_t)(m0 + rb + fm * 16 + q) * NG + n0 + colb + fn * 16] = acc[fm][fn][q];
}

// ---------------------------------------------------------------------------
// Persistent chain v5: 256 blocks = (mt 0..7 x 32 t-rows, jb 0..31 x 32 j).
// mt-groups are fully independent -> per-group 32-block barrier, atomic-free:
// arrival = plain sc0/sc1 store of monotonic step value to own flag; poll =
// wave-0 lanes 0..31 parallel-read the group's 32 flags. Max skew 1 step is
// safe with the A double-buffer.
// ---------------------------------------------------------------------------
__global__ __launch_bounds__(256, 1) void chain_kernel(
    __hip_bfloat16* Abuf0, __hip_bfloat16* Abuf1,
    const __hip_bfloat16* __restrict__ Bg_e,
    const __hip_bfloat16* __restrict__ Bg_d,
    const float* __restrict__ gi_enc, const float* __restrict__ gi_dec,
    const float* __restrict__ ebih, const float* __restrict__ ebhh,
    const float* __restrict__ dbih, const float* __restrict__ dbhh,
    const float* __restrict__ hA,
    __hip_bfloat16* __restrict__ hsb,
    const unsigned char* __restrict__ dflags,
    int* flags) {

    // ring 3x12288=36864 | gp 32x100x4=12800 | st 2048
    __shared__ __align__(16) char smem[52224];

    const int tid = threadIdx.x;
    const int b = blockIdx.x;
    const int mt = b >> 5, jb = b & 31;
    const int m0 = mt * 32;

    const int l = tid & 63, w = tid >> 6;
    const int wr = (w >> 1) * 16;        // wave M offset
    const int wc = (w & 1) * 48;         // wave N offset
    const int ji = tid & 31;
    const int tr0 = tid >> 5;            // 0..7
    const int j = jb * 32 + ji;

    float* gp = (float*)(smem + 36864);
    __hip_bfloat16* stb = (__hip_bfloat16*)(smem + 36864 + 12800);

    // persistent h (4 t-rows per thread)
    float hreg[4];
#pragma unroll
    for (int p = 0; p < 4; ++p)
        hreg[p] = hA[(size_t)(m0 + p * 8 + tr0) * HH + j];

    // biases hoisted for both phases (no loads in counted region)
    const float e_br = ebih[j] + ebhh[j];
    const float e_bz = ebih[HH + j] + ebhh[HH + j];
    const float e_bi = ebih[2 * HH + j];
    const float e_bh = ebhh[2 * HH + j];
    const float d_br = dbih[j] + dbhh[j];
    const float d_bz = dbih[HH + j] + dbhh[HH + j];
    const float d_bi = dbih[2 * HH + j];
    const float d_bh = dbhh[2 * HH + j];

    auto stageB = [&](const __hip_bfloat16* Bp, int slot, int it) {
        char* sb = smem + slot * 12288;
#pragma unroll
        for (int c = 0; c < 3; ++c) {
            int chunk = c * 256 + tid;
            int row = chunk >> 3, q = chunk & 7;
            const __hip_bfloat16* src =
                Bp + (size_t)(jb * 128 + row) * HH + it * 64 + ((q ^ (row & 7)) << 3);
            gload_lds16(src, sb + chunk * 16);
        }
    };

    // prestage B slots 0,1 for s=0, then gi for s=0 (asm-ordered, nt)
    stageB(Bg_e, 0, 0);
    stageB(Bg_e, 1, 1);

    float gr[4], gz[4], gn_[4];
    int dfl[4] = {0, 0, 0, 0};
#pragma unroll
    for (int p = 0; p < 4; ++p) {
        const float* gb = gi_enc + (size_t)(m0 + p * 8 + tr0) * NG + j;
        asm volatile("global_load_dword %0, %1, off nt" : "=v"(gr[p])  : "v"(gb));
        asm volatile("global_load_dword %0, %1, off nt" : "=v"(gz[p])  : "v"(gb + HH));
        asm volatile("global_load_dword %0, %1, off nt" : "=v"(gn_[p]) : "v"(gb + 2 * HH));
    }

    for (int s = 0; s < NSTEPS; ++s) {
        const __hip_bfloat16* Ab = (s & 1) ? Abuf1 : Abuf0;
        __hip_bfloat16* An = (s & 1) ? Abuf0 : Abuf1;
        const __hip_bfloat16* Bg = (s < CCH) ? Bg_e : Bg_d;

        // ---- A burst: full step, 32 x dwordx4 sc0 sc1 (ordered) ----
        const __hip_bfloat16* aptr = Ab + (size_t)(m0 + wr + (l & 15)) * HH + ((l >> 4) << 3);
        bf16x8 av[16][2];
#pragma unroll
        for (int it = 0; it < 16; ++it) {
            asm volatile("global_load_dwordx4 %0, %1, off sc0 sc1"
                         : "=v"(av[it][0]) : "v"(aptr + it * 64));
            asm volatile("global_load_dwordx4 %0, %1, off sc0 sc1"
                         : "=v"(av[it][1]) : "v"(aptr + it * 64 + 32));
        }

        f32x4 acc[3];
        acc[0] = (f32x4){0.f, 0.f, 0.f, 0.f};
        acc[1] = (f32x4){0.f, 0.f, 0.f, 0.f};
        acc[2] = (f32x4){0.f, 0.f, 0.f, 0.f};

#pragma unroll
        for (int it = 0; it < 16; ++it) {
            if (it + 2 < 16) stageB(Bg, (it + 2) % 3, it + 2);
            if (it == 0)       asm volatile("s_waitcnt vmcnt(33)" ::: "memory");
            else if (it == 1)  asm volatile("s_waitcnt vmcnt(34)" ::: "memory");
            else if (it <= 13) asm volatile("s_waitcnt vmcnt(6)"  ::: "memory");
            else if (it == 14) asm volatile("s_waitcnt vmcnt(3)"  ::: "memory");
            else               asm volatile("s_waitcnt vmcnt(0)"  ::: "memory");
            __builtin_amdgcn_s_barrier();
            __builtin_amdgcn_sched_barrier(0);

            const __hip_bfloat16* cB = (const __hip_bfloat16*)(smem + (it % 3) * 12288);
#pragma unroll
            for (int kh = 0; kh < 2; ++kh) {
                const int qg = kh * 4 + (l >> 4);
                bf16x8 bf0, bf1, bf2;
                { int r_ = wc + (l & 15);      bf0 = *(const bf16x8*)&cB[r_ * 64 + ((qg ^ (r_ & 7)) << 3)]; }
                { int r_ = wc + 16 + (l & 15); bf1 = *(const bf16x8*)&cB[r_ * 64 + ((qg ^ (r_ & 7)) << 3)]; }
                { int r_ = wc + 32 + (l & 15); bf2 = *(const bf16x8*)&cB[r_ * 64 + ((qg ^ (r_ & 7)) << 3)]; }
                acc[0] = __builtin_amdgcn_mfma_f32_16x16x32_bf16(av[it][kh], bf0, acc[0], 0, 0, 0);
                acc[1] = __builtin_amdgcn_mfma_f32_16x16x32_bf16(av[it][kh], bf1, acc[1], 0, 0, 0);
                acc[2] = __builtin_amdgcn_mfma_f32_16x16x32_bf16(av[it][kh], bf2, acc[2], 0, 0, 0);
            }
        }

        // ---- dump acc to LDS as gp[32][100] fp32 (gp disjoint from ring) ----
        {
            const int rb = wr + ((l >> 4) << 2);
#pragma unroll
            for (int fn = 0; fn < 3; ++fn)
#pragma unroll
                for (int q = 0; q < 4; ++q)
                    gp[(rb + q) * 100 + wc + fn * 16 + (l & 15)] = acc[fn][q];
        }
        __syncthreads();

        // ---- fused GRU epilogue ----
        const int f = s - CCH;
        const float br_ = (s < CCH) ? e_br : d_br;
        const float bz_ = (s < CCH) ? e_bz : d_bz;
        const float bi_ = (s < CCH) ? e_bi : d_bi;
        const float bh_ = (s < CCH) ? e_bh : d_bh;
#pragma unroll
        for (int p = 0; p < 4; ++p) {
            const int tr = p * 8 + tr0;
            float racc = gp[tr * 100 + ji];
            float zacc = gp[tr * 100 + 32 + ji];
            float nacc = gp[tr * 100 + 64 + ji];
            float r = sigmf(gr[p] + br_ + racc);
            float z = sigmf(gz[p] + bz_ + zacc);
            float n = tanhf(gn_[p] + bi_ + r * (nacc + bh_));
            float hold = hreg[p];
            float hv = (1.f - z) * n + z * hold;
            if (s >= CCH && dfl[p]) hv = hold;
            hreg[p] = hv;
            stb[tr * 32 + ji] = __float2bfloat16(hv);
        }
        __syncthreads();

        // ---- coalesced chunk stores (tid<128: one 16B chunk each) ----
        if (tid < 128) {
            const int row = tid >> 2, part = tid & 3;
            bf16x8 v = *(const bf16x8*)&stb[row * 32 + part * 8];
            if (s < NSTEPS - 1) {
                const __hip_bfloat16* ap = An + (size_t)(m0 + row) * HH + jb * 32 + part * 8;
                asm volatile("global_store_dwordx4 %0, %1, off sc0 sc1"
                             :: "v"(ap), "v"(v) : "memory");
            }
            if (s >= CCH) {
                bf16x8* hp = (bf16x8*)(hsb + ((size_t)f * TT + m0 + row) * HH + jb * 32 + part * 8);
                __builtin_nontemporal_store(v, hp);
            }
        }

        // ---- tail: prestage next B, drain, per-mt flag barrier ----
        if (s < NSTEPS - 1) {
            const __hip_bfloat16* BgN = (s + 1 < CCH) ? Bg_e : Bg_d;
            stageB(BgN, 0, 0);
            stageB(BgN, 1, 1);
            asm volatile("s_waitcnt vmcnt(6)" ::: "memory");   // An/hsb stores drained
            __syncthreads();

            // arrival: one plain write-through store per block (monotonic value)
            if (tid == 0) {
                int v = s + 1;
                int* fp = flags + (mt << 5) + jb;
                asm volatile("global_store_dword %0, %1, off sc0 sc1"
                             :: "v"(fp), "v"(v) : "memory");
            }

            // overlap: prefetch next step's gi (+dflags) while group settles
            {
                const float* gnext = (s + 1 < CCH) ? (gi_enc + (size_t)(s + 1) * TT * NG)
                                                   : (gi_dec + (size_t)(s + 1 - CCH) * TT * NG);
#pragma unroll
                for (int p = 0; p < 4; ++p) {
                    const float* gb = gnext + (size_t)(m0 + p * 8 + tr0) * NG + j;
                    asm volatile("global_load_dword %0, %1, off nt" : "=v"(gr[p])  : "v"(gb));
                    asm volatile("global_load_dword %0, %1, off nt" : "=v"(gz[p])  : "v"(gb + HH));
                    asm volatile("global_load_dword %0, %1, off nt" : "=v"(gn_[p]) : "v"(gb + 2 * HH));
                }
                if (s + 1 >= CCH) {
                    const int fnx = s + 1 - CCH;
#pragma unroll
                    for (int p = 0; p < 4; ++p) {
                        const unsigned char* dp = dflags + (size_t)(m0 + p * 8 + tr0) * FF + fnx;
                        asm volatile("global_load_ubyte %0, %1, off" : "=v"(dfl[p]) : "v"(dp));
                    }
                }
            }

            // poll: wave 0 lanes 0..31 read the group's 32 flags in parallel
            if (tid < 64) {
                const int* fp = flags + (mt << 5) + (tid & 31);
                const int target = s + 1;
                long guard = 0;
                for (;;) {
                    int v = target;
                    if (tid < 32) {
                        asm volatile("global_load_dword %0, %1, off sc0 sc1"
                                     : "=v"(v) : "v"(fp));
                        asm volatile("s_waitcnt vmcnt(0)" ::: "memory");
                    }
                    if (__all(v >= target)) break;
                    if (++guard > (1L << 22)) break;
                    __builtin_amdgcn_s_sleep(4);
                }
            }
            __syncthreads();
        }
    }
}

// ---------------------------------------------------------------------------
// scores v2: pipelined 4-slot ring, depth-2 counted vmcnt (gemm_pipe core),
// nontemporal C-stores. grid 5056 XCD-swizzled.
// ---------------------------------------------------------------------------
__global__ __launch_bounds__(256) void scores_pipe(const __hip_bfloat16* __restrict__ hsb,
                                                   const __hip_bfloat16* __restrict__ Wb,
                                                   const float* __restrict__ bout,
                                                   const int* __restrict__ oc,
                                                   float* __restrict__ out) {
    __shared__ __hip_bfloat16 As[4][128 * 32];
    __shared__ __hip_bfloat16 Bs[4][128 * 32];
    int bid = blockIdx.x;
    int sid = (bid & 7) * 632 + (bid >> 3);      // 5056 = 8*632, bijective
    int bx = sid % 79, by = sid / 79;
    int n0 = bx * 128, m0 = by * 128;

    const int tid = threadIdx.x;
    const int l = tid & 63;
    const int w = tid >> 6;
    const int wr = (w >> 1) * 64, wc = (w & 1) * 64;
    const int srow = tid >> 2, skq = tid & 3;

    f32x4 acc[4][4];
#pragma unroll
    for (int i = 0; i < 4; ++i)
#pragma unroll
        for (int j = 0; j < 4; ++j) acc[i][j] = (f32x4){0.f, 0.f, 0.f, 0.f};

    int br0 = n0 + srow, br1 = n0 + 64 + srow;
    br0 = (br0 > VV - 1) ? VV - 1 : br0;
    br1 = (br1 > VV - 1) ? VV - 1 : br1;
    const __hip_bfloat16* gA0 = hsb + (size_t)(m0 + srow) * HH + skq * 8;
    const __hip_bfloat16* gA1 = hsb + (size_t)(m0 + 64 + srow) * HH + skq * 8;
    const __hip_bfloat16* gB0 = Wb + (size_t)br0 * HH + skq * 8;
    const __hip_bfloat16* gB1 = Wb + (size_t)br1 * HH + skq * 8;
    const int fra = ((wr + (l & 15)) << 5) + ((l >> 4) << 3);
    const int frb = ((wc + (l & 15)) << 5) + ((l >> 4) << 3);

    auto stage = [&](int slot, int it) {
        const int k0 = it * 32;
        __hip_bfloat16* lA = &As[slot][tid * 8];
        __hip_bfloat16* lB = &Bs[slot][tid * 8];
        gload_lds16(gA0 + k0, lA);
        gload_lds16(gA1 + k0, lA + 2048);
        gload_lds16(gB0 + k0, lB);
        gload_lds16(gB1 + k0, lB + 2048);
    };

    stage(0, 0);
    stage(1, 1);

    for (int it = 0; it < 32; ++it) {
        if (it + 2 < 32) stage((it + 2) & 3, it + 2);
        int ahead = 31 - it; if (ahead > 2) ahead = 2;
        if (ahead >= 2)      asm volatile("s_waitcnt vmcnt(8)" ::: "memory");
        else if (ahead == 1) asm volatile("s_waitcnt vmcnt(4)" ::: "memory");
        else                 asm volatile("s_waitcnt vmcnt(0)" ::: "memory");
        __builtin_amdgcn_s_barrier();
        __builtin_amdgcn_sched_barrier(0);

        const __hip_bfloat16* cA = As[it & 3];
        const __hip_bfloat16* cB = Bs[it & 3];
        bf16x8 af[4], bfv[4];
#pragma unroll
        for (int fm = 0; fm < 4; ++fm) af[fm] = *(const bf16x8*)&cA[fra + fm * 512];
#pragma unroll
        for (int fn = 0; fn < 4; ++fn) bfv[fn] = *(const bf16x8*)&cB[frb + fn * 512];
#pragma unroll
        for (int fm = 0; fm < 4; ++fm)
#pragma unroll
            for (int fn = 0; fn < 4; ++fn)
                acc[fm][fn] = __builtin_amdgcn_mfma_f32_16x16x32_bf16(af[fm], bfv[fn], acc[fm][fn], 0, 0, 0);
    }

    const bool zf = (oc[0] == EOS_ID);
    const int colb = wc + (l & 15);
    const int rb   = wr + ((l >> 4) << 2);
#pragma unroll
    for (int fn = 0; fn < 4; ++fn) {
        int v = n0 + colb + fn * 16;
        if (v < VV) {
            float bb = bout[v];
#pragma unroll
            for (int fm = 0; fm < 4; ++fm) {
#pragma unroll
                for (int q = 0; q < 4; ++q) {
                    int m = m0 + rb + fm * 16 + q;
                    int fo = m >> 8, t = m & 255;
                    float val = zf ? 0.f : (acc[fm][fn][q] + bb);
                    __builtin_nontemporal_store(val, &out[(size_t)(t * FF + fo) * VV + v]);
                }
            }
        }
    }
}

// ---------------------------------------------------------------------------
extern "C" void kernel_launch(void* const* d_in, const int* in_sizes, int n_in,
                              void* d_out, int out_size, void* d_ws, size_t ws_size,
                              hipStream_t stream) {
    (void)in_sizes; (void)n_in; (void)ws_size;

    const float* token_ctx = (const float*)d_in[0];
    const float* emb       = (const float*)d_in[1];
    const float* eWih      = (const float*)d_in[2];
    const float* eWhh      = (const float*)d_in[3];
    const float* ebih      = (const float*)d_in[4];
    const float* ebhh      = (const float*)d_in[5];
    const float* dWih      = (const float*)d_in[6];
    const float* dWhh      = (const float*)d_in[7];
    const float* dbih      = (const float*)d_in[8];
    const float* dbhh      = (const float*)d_in[9];
    const float* Wout      = (const float*)d_in[10];
    const float* bout      = (const float*)d_in[11];
    const int*   sent      = (const int*)d_in[12];
    const int*   ochars    = (const int*)d_in[13];
    float* out = (float*)d_out;

    // ---- ws layout (~40 MB) ----
    char* w = (char*)d_ws;
    float* hA = (float*)w;                      w += (size_t)TT * HH * 4;        // 1 MB
    __hip_bfloat16* Ab0 = (__hip_bfloat16*)w;   w += (size_t)TT * HH * 2;        // 0.5 MB
    __hip_bfloat16* Ab1 = (__hip_bfloat16*)w;   w += (size_t)TT * HH * 2;        // 0.5 MB
    __hip_bfloat16* hsb = (__hip_bfloat16*)w;   w += (size_t)FF * TT * HH * 2;   // 16.8 MB
    __hip_bfloat16* Woutb = (__hip_bfloat16*)w; w += (size_t)VV * HH * 2;        // 20.5 MB
    int* c_in = (int*)w;                        w += (size_t)TT * FF * 4;
    unsigned char* done = (unsigned char*)w;    w += (size_t)TT * FF;
    w = (char*)(((size_t)w + 255) & ~(size_t)255);
    int* ctr = (int*)w;                         w += (size_t)CTR_INTS * 4;

    // ---- d_out tail scratch (dead until scores_pipe) ----
    char* tail = (char*)d_out + (size_t)out_size * 4;
    tail -= (size_t)32 * 128 * HH * 2;    __hip_bfloat16* Bg_e = (__hip_bfloat16*)tail;   // 8.4 MB
    tail -= (size_t)32 * 128 * HH * 2;    __hip_bfloat16* Bg_d = (__hip_bfloat16*)tail;   // 8.4 MB
    tail -= (size_t)CCH * TT * NG * 4;    float* gi_enc = (float*)tail;                   // 25.2 MB
    tail -= (size_t)FF * TT * NG * 4;     float* gi_dec = (float*)tail;                   // 100.7 MB
    tail -= (size_t)VV * EE * 2;          __hip_bfloat16* emb_bf = (__hip_bfloat16*)tail; // 5.1 MB
    tail -= (size_t)NG * EE * 2;          __hip_bfloat16* Wihb_e = (__hip_bfloat16*)tail;
    tail -= (size_t)NG * EE * 2;          __hip_bfloat16* Wihb_d = (__hip_bfloat16*)tail;

    // ---- prep & conversions ----
    prep_kernel<<<1, 256, 0, stream>>>(ochars, c_in, done, ctr);
    h0_kernel<<<TT, 256, 0, stream>>>(token_ctx, sent, hA, Ab0);
    f2b_kernel<<<(VV * EE) / 4 / 256, 256, 0, stream>>>(emb, emb_bf);
    f2b_kernel<<<(NG * EE) / 4 / 256, 256, 0, stream>>>(eWih, Wihb_e);
    f2b_kernel<<<(NG * EE) / 4 / 256, 256, 0, stream>>>(dWih, Wihb_d);
    f2b_kernel<<<(VV * HH) / 4 / 256, 256, 0, stream>>>(Wout, Woutb);
    build_Bg<<<4096, 256, 0, stream>>>(eWhh, Bg_e);
    build_Bg<<<4096, 256, 0, stream>>>(dWhh, Bg_d);

    // ---- x-side tables: gi = emb_bf[ids] @ Wih^T (fp32, gate order g*1024+j) ----
    gemm_pipe<1><<<dim3(24, 16), 256, 0, stream>>>(emb_bf, EE, Wihb_e, EE, gi_enc, sent, 8);
    gemm_pipe<2><<<dim3(24, 64), 256, 0, stream>>>(emb_bf, EE, Wihb_d, EE, gi_dec, c_in, 8);

    // ---- persistent recurrent chain ----
    chain_kernel<<<CHAIN_BLKS, 256, 0, stream>>>(Ab0, Ab1, Bg_e, Bg_d,
                                                 gi_enc, gi_dec,
                                                 ebih, ebhh, dbih, dbhh,
                                                 hA, hsb, done, ctr);

    // ---- scores ----
    scores_pipe<<<5056, 256, 0, stream>>>(hsb, Woutb, bout, ochars, out);
}

// Round 9
// 697.871 us; speedup vs baseline: 2.0814x; 1.0531x over previous
//
#include <hip/hip_runtime.h>
#include <hip/hip_bf16.h>
#include <math.h>

#define TT   256
#define FF   32
#define CCH  8
#define VV   10000
#define HH   1024
#define EE   256
#define NG   3072        // gate cols r|z|n (original order: g*1024 + j)
#define EOS_ID 2
#define NSTEPS 40
#define CHAIN_BLKS 256   // mt 4 x jb 64
#define CTR_INTS 512

// chain LDS layout (dynamic): B 48*2048 | gp 64*52*4 | stb 64*16*2
#define LDS_B_BYTES   98304
#define LDS_GP_OFF    98304
#define LDS_STB_OFF   (98304 + 13312)
#define LDS_TOTAL     (98304 + 13312 + 2048)

typedef __attribute__((ext_vector_type(8))) short bf16x8;
typedef __attribute__((ext_vector_type(4))) float f32x4;

__device__ __forceinline__ void gload_lds16(const void* g, void* l) {
    __builtin_amdgcn_global_load_lds((const __attribute__((address_space(1))) void*)g,
                                     (__attribute__((address_space(3))) void*)l,
                                     16, 0, 0);
}

__device__ __forceinline__ float sigmf(float x) { return 1.f / (1.f + __expf(-x)); }

// ---------------------------------------------------------------------------
// prep: decoder ids c_in[t][f], entry-done flags, zero barrier flags
// ---------------------------------------------------------------------------
__global__ __launch_bounds__(256) void prep_kernel(const int* __restrict__ oc,
                                                   int* __restrict__ c_in,
                                                   unsigned char* __restrict__ done,
                                                   int* __restrict__ ctr) {
    int t = threadIdx.x;
    for (int i = t; i < CTR_INTS; i += 256) ctr[i] = 0;
    int c0 = oc[0];
    bool d = (c0 == EOS_ID);
    for (int f = 0; f < FF; ++f) {
        c_in[t * FF + f] = (f == 0) ? c0 : oc[1 + t * FF + f - 1];
        done[t * FF + f] = d ? 1 : 0;
        d = d || (oc[1 + t * FF + f] == EOS_ID);
    }
}

// ---------------------------------------------------------------------------
// h0 (fp32) + A0 = bf16(h0)
// ---------------------------------------------------------------------------
__global__ __launch_bounds__(256) void h0_kernel(const float* __restrict__ tctx,
                                                 const int* __restrict__ sent,
                                                 float* __restrict__ h,
                                                 __hip_bfloat16* __restrict__ A0) {
    int t = blockIdx.x;
    int tid = threadIdx.x;
    __shared__ int xt[CCH];
    if (tid < CCH) xt[tid] = sent[(t * CCH + tid) * 3 + 1];
    __syncthreads();
#pragma unroll
    for (int jj = 0; jj < 4; ++jj) {
        int j = tid + jj * 256;
        float s = 0.f;
#pragma unroll
        for (int c = 0; c < CCH; ++c) s += tctx[(size_t)xt[c] * HH + j];
        float hv = s * 0.125f;
        h[(size_t)t * HH + j] = hv;
        A0[(size_t)t * HH + j] = __float2bfloat16(hv);
    }
}

// ---------------------------------------------------------------------------
// generic fp32 -> bf16
// ---------------------------------------------------------------------------
__global__ __launch_bounds__(256) void f2b_kernel(const float* __restrict__ src,
                                                  __hip_bfloat16* __restrict__ dst) {
    size_t base = ((size_t)blockIdx.x * 256 + threadIdx.x) * 4;
    float4 v = *(const float4*)(src + base);
    dst[base + 0] = __float2bfloat16(v.x);
    dst[base + 1] = __float2bfloat16(v.y);
    dst[base + 2] = __float2bfloat16(v.z);
    dst[base + 3] = __float2bfloat16(v.w);
}

// ---------------------------------------------------------------------------
// Build Bg2 (3072 x 1024 bf16): row n' = jb*48 + g*16 + ji  <-  Whh row
// g*1024 + jb*16 + ji.  jb 0..63, g 0..2, ji 0..15.  grid 3072.
// ---------------------------------------------------------------------------
__global__ __launch_bounds__(256) void build_Bg2(const float* __restrict__ Whh,
                                                 __hip_bfloat16* __restrict__ Bg) {
    int by = blockIdx.x;
    int tid = threadIdx.x;
    int jb = by / 48, rr = by % 48;
    int g = rr >> 4, jj = rr & 15;
    const float* srow = Whh + (size_t)(g * 1024 + jb * 16 + jj) * HH;
    __hip_bfloat16* drow = Bg + (size_t)by * HH;
    float4 v = *(const float4*)(srow + tid * 4);
    drow[tid * 4 + 0] = __float2bfloat16(v.x);
    drow[tid * 4 + 1] = __float2bfloat16(v.y);
    drow[tid * 4 + 2] = __float2bfloat16(v.z);
    drow[tid * 4 + 3] = __float2bfloat16(v.w);
}

// ---------------------------------------------------------------------------
// Pipelined 128x128 MFMA GEMM (validated) for x-side gi tables.
// MODE 1: enc rows gathered emb_bf[sent char]; MODE 2: dec rows emb_bf[c_in]
// ---------------------------------------------------------------------------
template<int MODE>
__global__ __launch_bounds__(256) void gemm_pipe(const __hip_bfloat16* __restrict__ A, int lda,
                                                 const __hip_bfloat16* __restrict__ B, int ldb,
                                                 float* __restrict__ C,
                                                 const int* __restrict__ idsrc,
                                                 int NIT) {
    __shared__ __hip_bfloat16 As[4][128 * 32];
    __shared__ __hip_bfloat16 Bs[4][128 * 32];
    __shared__ int sids[128];

    const int tid = threadIdx.x;
    const int n0 = blockIdx.x * 128;
    const int m0 = blockIdx.y * 128;

    if (tid < 128) {
        int row = m0 + tid;
        int t = row & 255;
        int id;
        if (MODE == 1) { int c = row >> 8; id = idsrc[(t * CCH + c) * 3 + 2]; }
        else           { int f = row >> 8; id = idsrc[t * FF + f]; }
        sids[tid] = id;
    }
    __syncthreads();

    const int srow = tid >> 2, skq = tid & 3;
    const int l = tid & 63;
    const int w = tid >> 6;
    const int wr = (w >> 1) * 64, wc = (w & 1) * 64;
    const int fra = ((wr + (l & 15)) << 5) + ((l >> 4) << 3);
    const int frb = ((wc + (l & 15)) << 5) + ((l >> 4) << 3);

    f32x4 acc[4][4];
#pragma unroll
    for (int i = 0; i < 4; ++i)
#pragma unroll
        for (int j = 0; j < 4; ++j) acc[i][j] = (f32x4){0.f, 0.f, 0.f, 0.f};

    auto stage = [&](int slot, int it) {
        const int k0 = it * 32;
        const __hip_bfloat16* ga0 = A + (size_t)sids[srow] * lda + k0 + skq * 8;
        const __hip_bfloat16* ga1 = A + (size_t)sids[64 + srow] * lda + k0 + skq * 8;
        const __hip_bfloat16* gb0 = B + (size_t)(n0 + srow) * ldb + k0 + skq * 8;
        const __hip_bfloat16* gb1 = B + (size_t)(n0 + 64 + srow) * ldb + k0 + skq * 8;
        __hip_bfloat16* lA = &As[slot][tid * 8];
        __hip_bfloat16* lB = &Bs[slot][tid * 8];
        gload_lds16(ga0, lA);
        gload_lds16(ga1, lA + 2048);
        gload_lds16(gb0, lB);
        gload_lds16(gb1, lB + 2048);
    };

    stage(0, 0);
    stage(1, 1);

    for (int it = 0; it < NIT; ++it) {
        if (it + 2 < NIT) stage((it + 2) & 3, it + 2);
        int ahead = NIT - 1 - it; if (ahead > 2) ahead = 2;
        if (ahead >= 2)      asm volatile("s_waitcnt vmcnt(8)" ::: "memory");
        else if (ahead == 1) asm volatile("s_waitcnt vmcnt(4)" ::: "memory");
        else                 asm volatile("s_waitcnt vmcnt(0)" ::: "memory");
        __builtin_amdgcn_s_barrier();
        __builtin_amdgcn_sched_barrier(0);

        const __hip_bfloat16* cA = As[it & 3];
        const __hip_bfloat16* cB = Bs[it & 3];
        bf16x8 af[4], bfv[4];
#pragma unroll
        for (int fm = 0; fm < 4; ++fm) af[fm] = *(const bf16x8*)&cA[fra + fm * 512];
#pragma unroll
        for (int fn = 0; fn < 4; ++fn) bfv[fn] = *(const bf16x8*)&cB[frb + fn * 512];
#pragma unroll
        for (int fm = 0; fm < 4; ++fm)
#pragma unroll
            for (int fn = 0; fn < 4; ++fn)
                acc[fm][fn] = __builtin_amdgcn_mfma_f32_16x16x32_bf16(af[fm], bfv[fn], acc[fm][fn], 0, 0, 0);
    }

    const int colb = wc + (l & 15);
    const int rb   = wr + ((l >> 4) << 2);
#pragma unroll
    for (int fm = 0; fm < 4; ++fm)
#pragma unroll
        for (int fn = 0; fn < 4; ++fn)
#pragma unroll
            for (int q = 0; q < 4; ++q)
                C[(size_t)(m0 + rb + fm * 16 + q) * NG + n0 + colb + fn * 16] = acc[fm][fn][q];
}

// ---------------------------------------------------------------------------
// Persistent chain v6: 256 blocks = (mt 0..3 x 64 t-rows, jb 0..63 x 16 j).
// B (48 gate-cols x 1024 K, 98 KB bf16) LDS-PERSISTENT (loaded at s=0, s=8)
// -> zero per-step B traffic, NO barriers in the GEMM loop. A = 32x dwordx4
// sc0/sc1 burst, consumed with vmcnt(31-ks). Exchange = round-8 flag scheme.
// ---------------------------------------------------------------------------
__global__ __launch_bounds__(256, 1) void chain_kernel(
    __hip_bfloat16* Abuf0, __hip_bfloat16* Abuf1,
    const __hip_bfloat16* __restrict__ Bg_e,
    const __hip_bfloat16* __restrict__ Bg_d,
    const float* __restrict__ gi_enc, const float* __restrict__ gi_dec,
    const float* __restrict__ ebih, const float* __restrict__ ebhh,
    const float* __restrict__ dbih, const float* __restrict__ dbhh,
    const float* __restrict__ hA,
    __hip_bfloat16* __restrict__ hsb,
    const unsigned char* __restrict__ dflags,
    int* flags) {

    extern __shared__ __align__(16) char smem[];
    char* Bs = smem;
    float* gp = (float*)(smem + LDS_GP_OFF);
    __hip_bfloat16* stb = (__hip_bfloat16*)(smem + LDS_STB_OFF);

    const int tid = threadIdx.x;
    const int b = blockIdx.x;
    const int mt = b >> 6, jb = b & 63;
    const int m0 = mt * 64;
    const int jbase = jb * 16;

    const int l = tid & 63, w = tid >> 6;
    const int ji = tid & 15;
    const int rg = tid >> 4;             // 0..15 (epilogue row group)
    const int j = jbase + ji;

    // persistent h (4 t-rows per thread: t = m0 + p*16 + rg)
    float hreg[4];
#pragma unroll
    for (int p = 0; p < 4; ++p)
        hreg[p] = hA[(size_t)(m0 + p * 16 + rg) * HH + j];

    // hoisted biases
    const float e_br = ebih[j] + ebhh[j];
    const float e_bz = ebih[HH + j] + ebhh[HH + j];
    const float e_bi = ebih[2 * HH + j];
    const float e_bh = ebhh[2 * HH + j];
    const float d_br = dbih[j] + dbhh[j];
    const float d_bz = dbih[HH + j] + dbhh[HH + j];
    const float d_bi = dbih[2 * HH + j];
    const float d_bh = dbhh[2 * HH + j];

    // full-B LDS stage: 48 rows x 2048B = 6144 chunks of 16B, 24/thread.
    // source pre-swizzled (granule q ^= row&7), LDS linear (rule #21).
    auto stageBfull = [&](const __hip_bfloat16* Bp) {
#pragma unroll
        for (int c = 0; c < 24; ++c) {
            int chunk = c * 256 + tid;
            int row = chunk >> 7, q = chunk & 127;
            const char* src = (const char*)(Bp + (size_t)row * HH) + ((q ^ (row & 7)) << 4);
            gload_lds16(src, Bs + chunk * 16);
        }
    };

    // B fragment read from LDS (swizzled)
    auto ldB = [&](int nt, int ks) -> bf16x8 {
        int r = nt * 16 + (l & 15);
        int g = ks * 4 + (l >> 4);
        return *(const bf16x8*)(Bs + r * 2048 + ((g ^ (r & 7)) << 4));
    };

    // gi prefetch for s=0
    float gr[4], gz[4], gn_[4];
    int dfl[4] = {0, 0, 0, 0};
#pragma unroll
    for (int p = 0; p < 4; ++p) {
        const float* gb = gi_enc + (size_t)(m0 + p * 16 + rg) * NG + j;
        asm volatile("global_load_dword %0, %1, off nt" : "=v"(gr[p])  : "v"(gb));
        asm volatile("global_load_dword %0, %1, off nt" : "=v"(gz[p])  : "v"(gb + HH));
        asm volatile("global_load_dword %0, %1, off nt" : "=v"(gn_[p]) : "v"(gb + 2 * HH));
    }

    for (int s = 0; s < NSTEPS; ++s) {
        // ---- entry barrier: wait group flags >= s ----
        if (s > 0) {
            if (tid < 64) {
                const int* fp = flags + (mt << 6) + l;
                long guard = 0;
                for (;;) {
                    int v;
                    asm volatile("global_load_dword %0, %1, off sc0 sc1" : "=v"(v) : "v"(fp));
                    asm volatile("s_waitcnt vmcnt(0)" ::: "memory");
                    if (__all(v >= s)) break;
                    if (++guard > (1L << 22)) break;
                    __builtin_amdgcn_s_sleep(2);
                }
            }
            __syncthreads();
        }

        // ---- B phase (re)load: once for enc, once for dec ----
        if (s == 0 || s == CCH) {
            stageBfull(((s == 0) ? Bg_e : Bg_d) + (size_t)jb * 48 * HH);
            asm volatile("s_waitcnt vmcnt(0)" ::: "memory");
            __syncthreads();
        }

        const __hip_bfloat16* Ab = (s & 1) ? Abuf1 : Abuf0;
        __hip_bfloat16* An = (s & 1) ? Abuf0 : Abuf1;

        // ---- drain leftover loads, then A burst (32 x dwordx4 sc0 sc1) ----
        asm volatile("s_waitcnt vmcnt(0)" ::: "memory");
        const __hip_bfloat16* aptr = Ab + (size_t)(m0 + w * 16 + (l & 15)) * HH + ((l >> 4) << 3);
        bf16x8 av[32];
#pragma unroll
        for (int ks = 0; ks < 32; ++ks)
            asm volatile("global_load_dwordx4 %0, %1, off sc0 sc1"
                         : "=v"(av[ks]) : "v"(aptr + ks * 32));

        // ---- barrier-free GEMM: 32 K-steps, B from LDS (depth-2 reg prefetch)
        f32x4 acc[3];
        acc[0] = (f32x4){0.f, 0.f, 0.f, 0.f};
        acc[1] = (f32x4){0.f, 0.f, 0.f, 0.f};
        acc[2] = (f32x4){0.f, 0.f, 0.f, 0.f};

        bf16x8 bb[3][3];
#pragma unroll
        for (int nt = 0; nt < 3; ++nt) { bb[0][nt] = ldB(nt, 0); bb[1][nt] = ldB(nt, 1); }

#pragma unroll
        for (int ks = 0; ks < 32; ++ks) {
            if (ks + 2 < 32) {
#pragma unroll
                for (int nt = 0; nt < 3; ++nt) bb[(ks + 2) % 3][nt] = ldB(nt, ks + 2);
            }
            asm volatile("s_waitcnt vmcnt(%0)" :: "i"(31 - ks) : "memory");
            __builtin_amdgcn_sched_barrier(0);
            acc[0] = __builtin_amdgcn_mfma_f32_16x16x32_bf16(av[ks], bb[ks % 3][0], acc[0], 0, 0, 0);
            acc[1] = __builtin_amdgcn_mfma_f32_16x16x32_bf16(av[ks], bb[ks % 3][1], acc[1], 0, 0, 0);
            acc[2] = __builtin_amdgcn_mfma_f32_16x16x32_bf16(av[ks], bb[ks % 3][2], acc[2], 0, 0, 0);
        }

        // ---- dump acc to gp[64][52] ----
        {
            const int rb = w * 16 + ((l >> 4) << 2);
#pragma unroll
            for (int nt = 0; nt < 3; ++nt)
#pragma unroll
                for (int q = 0; q < 4; ++q)
                    gp[(rb + q) * 52 + nt * 16 + (l & 15)] = acc[nt][q];
        }
        __syncthreads();

        // ---- fused GRU epilogue ----
        const int f = s - CCH;
        const float br_ = (s < CCH) ? e_br : d_br;
        const float bz_ = (s < CCH) ? e_bz : d_bz;
        const float bi_ = (s < CCH) ? e_bi : d_bi;
        const float bh_ = (s < CCH) ? e_bh : d_bh;
#pragma unroll
        for (int p = 0; p < 4; ++p) {
            const int tr = p * 16 + rg;
            float racc = gp[tr * 52 + ji];
            float zacc = gp[tr * 52 + 16 + ji];
            float nacc = gp[tr * 52 + 32 + ji];
            float r = sigmf(gr[p] + br_ + racc);
            float z = sigmf(gz[p] + bz_ + zacc);
            float n = tanhf(gn_[p] + bi_ + r * (nacc + bh_));
            float hold = hreg[p];
            float hv = (1.f - z) * n + z * hold;
            if (s >= CCH && dfl[p]) hv = hold;
            hreg[p] = hv;
            stb[tr * 16 + ji] = __float2bfloat16(hv);
        }
        __syncthreads();

        // ---- coalesced stores (tid<128: one 16B chunk each) ----
        if (tid < 128) {
            const int row = tid >> 1, part = tid & 1;
            bf16x8 v = *(const bf16x8*)&stb[row * 16 + part * 8];
            if (s < NSTEPS - 1) {
                const __hip_bfloat16* ap = An + (size_t)(m0 + row) * HH + jbase + part * 8;
                asm volatile("global_store_dwordx4 %0, %1, off sc0 sc1"
                             :: "v"(ap), "v"(v) : "memory");
            }
            if (s >= CCH) {
                bf16x8* hp = (bf16x8*)(hsb + ((size_t)f * TT + m0 + row) * HH + jbase + part * 8);
                __builtin_nontemporal_store(v, hp);
            }
        }

        // ---- tail: drain stores, flag, prefetch next gi/dflags ----
        if (s < NSTEPS - 1) {
            asm volatile("s_waitcnt vmcnt(0)" ::: "memory");
            __syncthreads();
            if (tid == 0) {
                int v = s + 1;
                int* fp = flags + (mt << 6) + jb;
                asm volatile("global_store_dword %0, %1, off sc0 sc1"
                             :: "v"(fp), "v"(v) : "memory");
            }
            {
                const float* gnext = (s + 1 < CCH) ? (gi_enc + (size_t)(s + 1) * TT * NG)
                                                   : (gi_dec + (size_t)(s + 1 - CCH) * TT * NG);
#pragma unroll
                for (int p = 0; p < 4; ++p) {
                    const float* gb = gnext + (size_t)(m0 + p * 16 + rg) * NG + j;
                    asm volatile("global_load_dword %0, %1, off nt" : "=v"(gr[p])  : "v"(gb));
                    asm volatile("global_load_dword %0, %1, off nt" : "=v"(gz[p])  : "v"(gb + HH));
                    asm volatile("global_load_dword %0, %1, off nt" : "=v"(gn_[p]) : "v"(gb + 2 * HH));
                }
                if (s + 1 >= CCH) {
                    const int fnx = s + 1 - CCH;
#pragma unroll
                    for (int p = 0; p < 4; ++p) {
                        const unsigned char* dp = dflags + (size_t)(m0 + p * 16 + rg) * FF + fnx;
                        asm volatile("global_load_ubyte %0, %1, off" : "=v"(dfl[p]) : "v"(dp));
                    }
                }
            }
        }
    }
}

// ---------------------------------------------------------------------------
// scores (validated round 8): pipelined 4-slot ring, counted vmcnt, nt stores
// ---------------------------------------------------------------------------
__global__ __launch_bounds__(256) void scores_pipe(const __hip_bfloat16* __restrict__ hsb,
                                                   const __hip_bfloat16* __restrict__ Wb,
                                                   const float* __restrict__ bout,
                                                   const int* __restrict__ oc,
                                                   float* __restrict__ out) {
    __shared__ __hip_bfloat16 As[4][128 * 32];
    __shared__ __hip_bfloat16 Bs[4][128 * 32];
    int bid = blockIdx.x;
    int sid = (bid & 7) * 632 + (bid >> 3);      // 5056 = 8*632, bijective
    int bx = sid % 79, by = sid / 79;
    int n0 = bx * 128, m0 = by * 128;

    const int tid = threadIdx.x;
    const int l = tid & 63;
    const int w = tid >> 6;
    const int wr = (w >> 1) * 64, wc = (w & 1) * 64;
    const int srow = tid >> 2, skq = tid & 3;

    f32x4 acc[4][4];
#pragma unroll
    for (int i = 0; i < 4; ++i)
#pragma unroll
        for (int j = 0; j < 4; ++j) acc[i][j] = (f32x4){0.f, 0.f, 0.f, 0.f};

    int br0 = n0 + srow, br1 = n0 + 64 + srow;
    br0 = (br0 > VV - 1) ? VV - 1 : br0;
    br1 = (br1 > VV - 1) ? VV - 1 : br1;
    const __hip_bfloat16* gA0 = hsb + (size_t)(m0 + srow) * HH + skq * 8;
    const __hip_bfloat16* gA1 = hsb + (size_t)(m0 + 64 + srow) * HH + skq * 8;
    const __hip_bfloat16* gB0 = Wb + (size_t)br0 * HH + skq * 8;
    const __hip_bfloat16* gB1 = Wb + (size_t)br1 * HH + skq * 8;
    const int fra = ((wr + (l & 15)) << 5) + ((l >> 4) << 3);
    const int frb = ((wc + (l & 15)) << 5) + ((l >> 4) << 3);

    auto stage = [&](int slot, int it) {
        const int k0 = it * 32;
        __hip_bfloat16* lA = &As[slot][tid * 8];
        __hip_bfloat16* lB = &Bs[slot][tid * 8];
        gload_lds16(gA0 + k0, lA);
        gload_lds16(gA1 + k0, lA + 2048);
        gload_lds16(gB0 + k0, lB);
        gload_lds16(gB1 + k0, lB + 2048);
    };

    stage(0, 0);
    stage(1, 1);

    for (int it = 0; it < 32; ++it) {
        if (it + 2 < 32) stage((it + 2) & 3, it + 2);
        int ahead = 31 - it; if (ahead > 2) ahead = 2;
        if (ahead >= 2)      asm volatile("s_waitcnt vmcnt(8)" ::: "memory");
        else if (ahead == 1) asm volatile("s_waitcnt vmcnt(4)" ::: "memory");
        else                 asm volatile("s_waitcnt vmcnt(0)" ::: "memory");
        __builtin_amdgcn_s_barrier();
        __builtin_amdgcn_sched_barrier(0);

        const __hip_bfloat16* cA = As[it & 3];
        const __hip_bfloat16* cB = Bs[it & 3];
        bf16x8 af[4], bfv[4];
#pragma unroll
        for (int fm = 0; fm < 4; ++fm) af[fm] = *(const bf16x8*)&cA[fra + fm * 512];
#pragma unroll
        for (int fn = 0; fn < 4; ++fn) bfv[fn] = *(const bf16x8*)&cB[frb + fn * 512];
#pragma unroll
        for (int fm = 0; fm < 4; ++fm)
#pragma unroll
            for (int fn = 0; fn < 4; ++fn)
                acc[fm][fn] = __builtin_amdgcn_mfma_f32_16x16x32_bf16(af[fm], bfv[fn], acc[fm][fn], 0, 0, 0);
    }

    const bool zf = (oc[0] == EOS_ID);
    const int colb = wc + (l & 15);
    const int rb   = wr + ((l >> 4) << 2);
#pragma unroll
    for (int fn = 0; fn < 4; ++fn) {
        int v = n0 + colb + fn * 16;
        if (v < VV) {
            float bb = bout[v];
#pragma unroll
            for (int fm = 0; fm < 4; ++fm) {
#pragma unroll
                for (int q = 0; q < 4; ++q) {
                    int m = m0 + rb + fm * 16 + q;
                    int fo = m >> 8, t = m & 255;
                    float val = zf ? 0.f : (acc[fm][fn][q] + bb);
                    __builtin_nontemporal_store(val, &out[(size_t)(t * FF + fo) * VV + v]);
                }
            }
        }
    }
}

// ---------------------------------------------------------------------------
extern "C" void kernel_launch(void* const* d_in, const int* in_sizes, int n_in,
                              void* d_out, int out_size, void* d_ws, size_t ws_size,
                              hipStream_t stream) {
    (void)in_sizes; (void)n_in; (void)ws_size;

    const float* token_ctx = (const float*)d_in[0];
    const float* emb       = (const float*)d_in[1];
    const float* eWih      = (const float*)d_in[2];
    const float* eWhh      = (const float*)d_in[3];
    const float* ebih      = (const float*)d_in[4];
    const float* ebhh      = (const float*)d_in[5];
    const float* dWih      = (const float*)d_in[6];
    const float* dWhh      = (const float*)d_in[7];
    const float* dbih      = (const float*)d_in[8];
    const float* dbhh      = (const float*)d_in[9];
    const float* Wout      = (const float*)d_in[10];
    const float* bout      = (const float*)d_in[11];
    const int*   sent      = (const int*)d_in[12];
    const int*   ochars    = (const int*)d_in[13];
    float* out = (float*)d_out;

    // ---- ws layout (~40 MB) ----
    char* w = (char*)d_ws;
    float* hA = (float*)w;                      w += (size_t)TT * HH * 4;        // 1 MB
    __hip_bfloat16* Ab0 = (__hip_bfloat16*)w;   w += (size_t)TT * HH * 2;        // 0.5 MB
    __hip_bfloat16* Ab1 = (__hip_bfloat16*)w;   w += (size_t)TT * HH * 2;        // 0.5 MB
    __hip_bfloat16* hsb = (__hip_bfloat16*)w;   w += (size_t)FF * TT * HH * 2;   // 16.8 MB
    __hip_bfloat16* Woutb = (__hip_bfloat16*)w; w += (size_t)VV * HH * 2;        // 20.5 MB
    int* c_in = (int*)w;                        w += (size_t)TT * FF * 4;
    unsigned char* done = (unsigned char*)w;    w += (size_t)TT * FF;
    w = (char*)(((size_t)w + 255) & ~(size_t)255);
    int* ctr = (int*)w;                         w += (size_t)CTR_INTS * 4;

    // ---- d_out tail scratch (dead until scores_pipe) ----
    char* tail = (char*)d_out + (size_t)out_size * 4;
    tail -= (size_t)NG * HH * 2;          __hip_bfloat16* Bg_e = (__hip_bfloat16*)tail;   // 6.3 MB
    tail -= (size_t)NG * HH * 2;          __hip_bfloat16* Bg_d = (__hip_bfloat16*)tail;   // 6.3 MB
    tail -= (size_t)CCH * TT * NG * 4;    float* gi_enc = (float*)tail;                   // 25.2 MB
    tail -= (size_t)FF * TT * NG * 4;     float* gi_dec = (float*)tail;                   // 100.7 MB
    tail -= (size_t)VV * EE * 2;          __hip_bfloat16* emb_bf = (__hip_bfloat16*)tail; // 5.1 MB
    tail -= (size_t)NG * EE * 2;          __hip_bfloat16* Wihb_e = (__hip_bfloat16*)tail;
    tail -= (size_t)NG * EE * 2;          __hip_bfloat16* Wihb_d = (__hip_bfloat16*)tail;

    // allow >64KB dynamic LDS for the chain kernel (idempotent)
    hipFuncSetAttribute((const void*)chain_kernel,
                        hipFuncAttributeMaxDynamicSharedMemorySize, LDS_TOTAL);

    // ---- prep & conversions ----
    prep_kernel<<<1, 256, 0, stream>>>(ochars, c_in, done, ctr);
    h0_kernel<<<TT, 256, 0, stream>>>(token_ctx, sent, hA, Ab0);
    f2b_kernel<<<(VV * EE) / 4 / 256, 256, 0, stream>>>(emb, emb_bf);
    f2b_kernel<<<(NG * EE) / 4 / 256, 256, 0, stream>>>(eWih, Wihb_e);
    f2b_kernel<<<(NG * EE) / 4 / 256, 256, 0, stream>>>(dWih, Wihb_d);
    f2b_kernel<<<(VV * HH) / 4 / 256, 256, 0, stream>>>(Wout, Woutb);
    build_Bg2<<<NG, 256, 0, stream>>>(eWhh, Bg_e);
    build_Bg2<<<NG, 256, 0, stream>>>(dWhh, Bg_d);

    // ---- x-side tables: gi = emb_bf[ids] @ Wih^T (fp32, gate order g*1024+j) ----
    gemm_pipe<1><<<dim3(24, 16), 256, 0, stream>>>(emb_bf, EE, Wihb_e, EE, gi_enc, sent, 8);
    gemm_pipe<2><<<dim3(24, 64), 256, 0, stream>>>(emb_bf, EE, Wihb_d, EE, gi_dec, c_in, 8);

    // ---- persistent recurrent chain ----
    chain_kernel<<<CHAIN_BLKS, 256, LDS_TOTAL, stream>>>(Ab0, Ab1, Bg_e, Bg_d,
                                                         gi_enc, gi_dec,
                                                         ebih, ebhh, dbih, dbhh,
                                                         hA, hsb, done, ctr);

    // ---- scores ----
    scores_pipe<<<5056, 256, 0, stream>>>(hsb, Woutb, bout, ochars, out);
}

// Round 11
// 693.505 us; speedup vs baseline: 2.0945x; 1.0063x over previous
//
#include <hip/hip_runtime.h>
#include <hip/hip_bf16.h>
#include <math.h>

#define TT   256
#define FF   32
#define CCH  8
#define VV   10000
#define HH   1024
#define EE   256
#define NG   3072        // gate cols r|z|n (original order: g*1024 + j)
#define EOS_ID 2
#define NSTEPS 40
#define CHAIN_BLKS 256   // mt 4 x jb 64
#define CTR_INTS 512

// chain dynamic LDS: B 48*2048 | gp 4*64*52*4 | stb 64*16*2
#define LDS_GP_OFF    98304
#define LDS_STB_OFF   (98304 + 53248)
#define LDS_TOTAL     (98304 + 53248 + 2048)

typedef __attribute__((ext_vector_type(8))) short bf16x8;
typedef __attribute__((ext_vector_type(4))) float f32x4;

__device__ __forceinline__ void gload_lds16(const void* g, void* l) {
    __builtin_amdgcn_global_load_lds((const __attribute__((address_space(1))) void*)g,
                                     (__attribute__((address_space(3))) void*)l,
                                     16, 0, 0);
}

__device__ __forceinline__ float sigmf(float x) { return 1.f / (1.f + __expf(-x)); }

// ---------------------------------------------------------------------------
// prep: decoder ids c_in[t][f], entry-done flags, zero barrier flags
// ---------------------------------------------------------------------------
__global__ __launch_bounds__(256) void prep_kernel(const int* __restrict__ oc,
                                                   int* __restrict__ c_in,
                                                   unsigned char* __restrict__ done,
                                                   int* __restrict__ ctr) {
    int t = threadIdx.x;
    for (int i = t; i < CTR_INTS; i += 256) ctr[i] = 0;
    int c0 = oc[0];
    bool d = (c0 == EOS_ID);
    for (int f = 0; f < FF; ++f) {
        c_in[t * FF + f] = (f == 0) ? c0 : oc[1 + t * FF + f - 1];
        done[t * FF + f] = d ? 1 : 0;
        d = d || (oc[1 + t * FF + f] == EOS_ID);
    }
}

// ---------------------------------------------------------------------------
// h0 (fp32) + A0 = bf16(h0)
// ---------------------------------------------------------------------------
__global__ __launch_bounds__(256) void h0_kernel(const float* __restrict__ tctx,
                                                 const int* __restrict__ sent,
                                                 float* __restrict__ h,
                                                 __hip_bfloat16* __restrict__ A0) {
    int t = blockIdx.x;
    int tid = threadIdx.x;
    __shared__ int xt[CCH];
    if (tid < CCH) xt[tid] = sent[(t * CCH + tid) * 3 + 1];
    __syncthreads();
#pragma unroll
    for (int jj = 0; jj < 4; ++jj) {
        int j = tid + jj * 256;
        float s = 0.f;
#pragma unroll
        for (int c = 0; c < CCH; ++c) s += tctx[(size_t)xt[c] * HH + j];
        float hv = s * 0.125f;
        h[(size_t)t * HH + j] = hv;
        A0[(size_t)t * HH + j] = __float2bfloat16(hv);
    }
}

// ---------------------------------------------------------------------------
// generic fp32 -> bf16
// ---------------------------------------------------------------------------
__global__ __launch_bounds__(256) void f2b_kernel(const float* __restrict__ src,
                                                  __hip_bfloat16* __restrict__ dst) {
    size_t base = ((size_t)blockIdx.x * 256 + threadIdx.x) * 4;
    float4 v = *(const float4*)(src + base);
    dst[base + 0] = __float2bfloat16(v.x);
    dst[base + 1] = __float2bfloat16(v.y);
    dst[base + 2] = __float2bfloat16(v.z);
    dst[base + 3] = __float2bfloat16(v.w);
}

// ---------------------------------------------------------------------------
// Build Bg2 (3072 x 1024 bf16): row n' = jb*48 + g*16 + ji  <-  Whh row
// g*1024 + jb*16 + ji.  jb 0..63, g 0..2, ji 0..15.  grid 3072.
// ---------------------------------------------------------------------------
__global__ __launch_bounds__(256) void build_Bg2(const float* __restrict__ Whh,
                                                 __hip_bfloat16* __restrict__ Bg) {
    int by = blockIdx.x;
    int tid = threadIdx.x;
    int jb = by / 48, rr = by % 48;
    int g = rr >> 4, jj = rr & 15;
    const float* srow = Whh + (size_t)(g * 1024 + jb * 16 + jj) * HH;
    __hip_bfloat16* drow = Bg + (size_t)by * HH;
    float4 v = *(const float4*)(srow + tid * 4);
    drow[tid * 4 + 0] = __float2bfloat16(v.x);
    drow[tid * 4 + 1] = __float2bfloat16(v.y);
    drow[tid * 4 + 2] = __float2bfloat16(v.z);
    drow[tid * 4 + 3] = __float2bfloat16(v.w);
}

// ---------------------------------------------------------------------------
// Pipelined 128x128 MFMA GEMM for x-side gi tables — BF16 OUTPUT.
// MODE 1: enc rows gathered emb_bf[sent char]; MODE 2: dec rows emb_bf[c_in]
// ---------------------------------------------------------------------------
template<int MODE>
__global__ __launch_bounds__(256) void gemm_pipe(const __hip_bfloat16* __restrict__ A, int lda,
                                                 const __hip_bfloat16* __restrict__ B, int ldb,
                                                 __hip_bfloat16* __restrict__ Cb,
                                                 const int* __restrict__ idsrc,
                                                 int NIT) {
    __shared__ __hip_bfloat16 As[4][128 * 32];
    __shared__ __hip_bfloat16 Bs[4][128 * 32];
    __shared__ int sids[128];

    const int tid = threadIdx.x;
    const int n0 = blockIdx.x * 128;
    const int m0 = blockIdx.y * 128;

    if (tid < 128) {
        int row = m0 + tid;
        int t = row & 255;
        int id;
        if (MODE == 1) { int c = row >> 8; id = idsrc[(t * CCH + c) * 3 + 2]; }
        else           { int f = row >> 8; id = idsrc[t * FF + f]; }
        sids[tid] = id;
    }
    __syncthreads();

    const int srow = tid >> 2, skq = tid & 3;
    const int l = tid & 63;
    const int w = tid >> 6;
    const int wr = (w >> 1) * 64, wc = (w & 1) * 64;
    const int fra = ((wr + (l & 15)) << 5) + ((l >> 4) << 3);
    const int frb = ((wc + (l & 15)) << 5) + ((l >> 4) << 3);

    f32x4 acc[4][4];
#pragma unroll
    for (int i = 0; i < 4; ++i)
#pragma unroll
        for (int j = 0; j < 4; ++j) acc[i][j] = (f32x4){0.f, 0.f, 0.f, 0.f};

    auto stage = [&](int slot, int it) {
        const int k0 = it * 32;
        const __hip_bfloat16* ga0 = A + (size_t)sids[srow] * lda + k0 + skq * 8;
        const __hip_bfloat16* ga1 = A + (size_t)sids[64 + srow] * lda + k0 + skq * 8;
        const __hip_bfloat16* gb0 = B + (size_t)(n0 + srow) * ldb + k0 + skq * 8;
        const __hip_bfloat16* gb1 = B + (size_t)(n0 + 64 + srow) * ldb + k0 + skq * 8;
        __hip_bfloat16* lA = &As[slot][tid * 8];
        __hip_bfloat16* lB = &Bs[slot][tid * 8];
        gload_lds16(ga0, lA);
        gload_lds16(ga1, lA + 2048);
        gload_lds16(gb0, lB);
        gload_lds16(gb1, lB + 2048);
    };

    stage(0, 0);
    stage(1, 1);

    for (int it = 0; it < NIT; ++it) {
        if (it + 2 < NIT) stage((it + 2) & 3, it + 2);
        int ahead = NIT - 1 - it; if (ahead > 2) ahead = 2;
        if (ahead >= 2)      asm volatile("s_waitcnt vmcnt(8)" ::: "memory");
        else if (ahead == 1) asm volatile("s_waitcnt vmcnt(4)" ::: "memory");
        else                 asm volatile("s_waitcnt vmcnt(0)" ::: "memory");
        __builtin_amdgcn_s_barrier();
        __builtin_amdgcn_sched_barrier(0);

        const __hip_bfloat16* cA = As[it & 3];
        const __hip_bfloat16* cB = Bs[it & 3];
        bf16x8 af[4], bfv[4];
#pragma unroll
        for (int fm = 0; fm < 4; ++fm) af[fm] = *(const bf16x8*)&cA[fra + fm * 512];
#pragma unroll
        for (int fn = 0; fn < 4; ++fn) bfv[fn] = *(const bf16x8*)&cB[frb + fn * 512];
#pragma unroll
        for (int fm = 0; fm < 4; ++fm)
#pragma unroll
            for (int fn = 0; fn < 4; ++fn)
                acc[fm][fn] = __builtin_amdgcn_mfma_f32_16x16x32_bf16(af[fm], bfv[fn], acc[fm][fn], 0, 0, 0);
    }

    const int colb = wc + (l & 15);
    const int rb   = wr + ((l >> 4) << 2);
#pragma unroll
    for (int fm = 0; fm < 4; ++fm)
#pragma unroll
        for (int fn = 0; fn < 4; ++fn)
#pragma unroll
            for (int q = 0; q < 4; ++q)
                Cb[(size_t)(m0 + rb + fm * 16 + q) * NG + n0 + colb + fn * 16] =
                    __float2bfloat16(acc[fm][fn][q]);
}

// ---------------------------------------------------------------------------
// Persistent chain v8 (r9 structure + K-split): 256 blocks =
// (mt 0..3 x 64 t-rows, jb 0..63 x 16 j). B (48x1024, 96KB) LDS-persistent.
// Waves split K: wave w owns k in [w*256, w*256+256) -> 24 ds_reads/wave/step
// (was 96), 32 A-frag asm loads (proven shape), acc[4][3] K-partials summed
// via gp LDS. gi tables are bf16. Exchange = per-mt flag store + 64-lane
// parallel poll (validated r8/r9).
// ---------------------------------------------------------------------------
__global__ __launch_bounds__(256, 1) void chain_kernel(
    __hip_bfloat16* Abuf0, __hip_bfloat16* Abuf1,
    const __hip_bfloat16* __restrict__ Bg_e,
    const __hip_bfloat16* __restrict__ Bg_d,
    const __hip_bfloat16* __restrict__ gi_enc, const __hip_bfloat16* __restrict__ gi_dec,
    const float* __restrict__ ebih, const float* __restrict__ ebhh,
    const float* __restrict__ dbih, const float* __restrict__ dbhh,
    const float* __restrict__ hA,
    __hip_bfloat16* __restrict__ hsb,
    const unsigned char* __restrict__ dflags,
    int* flags) {

    extern __shared__ __align__(16) char smem[];
    char* Bs = smem;
    float* gp = (float*)(smem + LDS_GP_OFF);
    __hip_bfloat16* stb = (__hip_bfloat16*)(smem + LDS_STB_OFF);

    const int tid = threadIdx.x;
    const int b = blockIdx.x;
    const int mt = b >> 6, jb = b & 63;
    const int m0 = mt * 64;
    const int jbase = jb * 16;

    const int l = tid & 63, w = tid >> 6;
    const int ji = tid & 15;
    const int rg = tid >> 4;             // 0..15 (epilogue row group)
    const int j = jbase + ji;
    const int lrow = l & 15;             // fragment row lane
    const int lk8  = (l >> 4) << 3;      // fragment k sub-offset (elems)

    // persistent h (4 t-rows per thread: t = m0 + p*16 + rg)
    float hreg[4];
#pragma unroll
    for (int p = 0; p < 4; ++p)
        hreg[p] = hA[(size_t)(m0 + p * 16 + rg) * HH + j];

    // hoisted biases
    const float e_br = ebih[j] + ebhh[j];
    const float e_bz = ebih[HH + j] + ebhh[HH + j];
    const float e_bi = ebih[2 * HH + j];
    const float e_bh = ebhh[2 * HH + j];
    const float d_br = dbih[j] + dbhh[j];
    const float d_bz = dbih[HH + j] + dbhh[HH + j];
    const float d_bi = dbih[2 * HH + j];
    const float d_bh = dbhh[2 * HH + j];

    // full-B LDS stage: 48 rows x 2048B = 6144 chunks of 16B, 24/thread.
    // source pre-swizzled (granule q ^= row&7), LDS linear (rule #21).
    auto stageBfull = [&](const __hip_bfloat16* Bp) {
#pragma unroll
        for (int c = 0; c < 24; ++c) {
            int chunk = c * 256 + tid;
            int row = chunk >> 7, q = chunk & 127;
            const char* src = (const char*)(Bp + (size_t)row * HH) + ((q ^ (row & 7)) << 4);
            gload_lds16(src, Bs + chunk * 16);
        }
    };

    // B fragment read from LDS (swizzled), global k-chunk index ks
    auto ldB = [&](int nt, int ks) -> bf16x8 {
        int r = nt * 16 + lrow;
        int g = ks * 4 + (l >> 4);
        return *(const bf16x8*)(Bs + r * 2048 + ((g ^ (r & 7)) << 4));
    };

    // gi prefetch for s=0 (bf16 -> u16 loads)
    unsigned int gru[4], gzu[4], gnu[4];
    int dfl[4] = {0, 0, 0, 0};
#pragma unroll
    for (int p = 0; p < 4; ++p) {
        const __hip_bfloat16* gb = gi_enc + (size_t)(m0 + p * 16 + rg) * NG + j;
        asm volatile("global_load_ushort %0, %1, off nt" : "=v"(gru[p]) : "v"(gb));
        asm volatile("global_load_ushort %0, %1, off nt" : "=v"(gzu[p]) : "v"(gb + HH));
        asm volatile("global_load_ushort %0, %1, off nt" : "=v"(gnu[p]) : "v"(gb + 2 * HH));
    }

    for (int s = 0; s < NSTEPS; ++s) {
        // ---- entry barrier: wave 0 polls the group's 64 flags ----
        if (s > 0) {
            if (tid < 64) {
                const int* fp = flags + (mt << 6) + l;
                long guard = 0;
                for (;;) {
                    int v;
                    asm volatile("global_load_dword %0, %1, off sc0 sc1" : "=v"(v) : "v"(fp));
                    asm volatile("s_waitcnt vmcnt(0)" ::: "memory");
                    if (__all(v >= s)) break;
                    if (++guard > (1L << 22)) break;
                    __builtin_amdgcn_s_sleep(2);
                }
            }
            __syncthreads();
        }

        // ---- B phase (re)load: once for enc, once for dec ----
        if (s == 0 || s == CCH) {
            stageBfull(((s == 0) ? Bg_e : Bg_d) + (size_t)jb * 48 * HH);
            asm volatile("s_waitcnt vmcnt(0)" ::: "memory");
            __syncthreads();
        }

        const __hip_bfloat16* Ab = (s & 1) ? Abuf1 : Abuf0;
        __hip_bfloat16* An = (s & 1) ? Abuf0 : Abuf1;

        // ---- drain outstanding loads (gi/dfl), then A burst ----
        asm volatile("s_waitcnt vmcnt(0)" ::: "memory");
        const __hip_bfloat16* ap0 = Ab + (size_t)(m0 + 0 * 16 + lrow) * HH + w * 256 + lk8;
        const __hip_bfloat16* ap1 = Ab + (size_t)(m0 + 1 * 16 + lrow) * HH + w * 256 + lk8;
        const __hip_bfloat16* ap2 = Ab + (size_t)(m0 + 2 * 16 + lrow) * HH + w * 256 + lk8;
        const __hip_bfloat16* ap3 = Ab + (size_t)(m0 + 3 * 16 + lrow) * HH + w * 256 + lk8;

        bf16x8 av[8][4];
#pragma unroll
        for (int ksl = 0; ksl < 8; ++ksl) {
            asm volatile("global_load_dwordx4 %0, %1, off sc0 sc1" : "=v"(av[ksl][0]) : "v"(ap0 + ksl * 32));
            asm volatile("global_load_dwordx4 %0, %1, off sc0 sc1" : "=v"(av[ksl][1]) : "v"(ap1 + ksl * 32));
            asm volatile("global_load_dwordx4 %0, %1, off sc0 sc1" : "=v"(av[ksl][2]) : "v"(ap2 + ksl * 32));
            asm volatile("global_load_dwordx4 %0, %1, off sc0 sc1" : "=v"(av[ksl][3]) : "v"(ap3 + ksl * 32));
        }

        // ---- barrier-free GEMM: 8 K-chunks x 12 MFMA, B via depth-2 reg ring
        f32x4 acc[4][3];
#pragma unroll
        for (int m = 0; m < 4; ++m)
#pragma unroll
            for (int nt = 0; nt < 3; ++nt) acc[m][nt] = (f32x4){0.f, 0.f, 0.f, 0.f};

        const int kbase = w * 8;
        bf16x8 bb[3][3];
#pragma unroll
        for (int nt = 0; nt < 3; ++nt) { bb[0][nt] = ldB(nt, kbase); bb[1][nt] = ldB(nt, kbase + 1); }

#pragma unroll
        for (int ksl = 0; ksl < 8; ++ksl) {
            if (ksl + 2 < 8) {
#pragma unroll
                for (int nt = 0; nt < 3; ++nt) bb[(ksl + 2) % 3][nt] = ldB(nt, kbase + ksl + 2);
            }
            asm volatile("s_waitcnt vmcnt(%0)" :: "i"(28 - 4 * ksl) : "memory");
            __builtin_amdgcn_sched_barrier(0);
#pragma unroll
            for (int m = 0; m < 4; ++m)
#pragma unroll
                for (int nt = 0; nt < 3; ++nt)
                    acc[m][nt] = __builtin_amdgcn_mfma_f32_16x16x32_bf16(av[ksl][m], bb[ksl % 3][nt], acc[m][nt], 0, 0, 0);
        }

        // ---- dump wave K-partials to gp[w][64][52] ----
        {
            float* gpw = gp + w * (64 * 52);
            const int rbase = (l >> 4) << 2;
#pragma unroll
            for (int m = 0; m < 4; ++m)
#pragma unroll
                for (int nt = 0; nt < 3; ++nt)
#pragma unroll
                    for (int q = 0; q < 4; ++q)
                        gpw[(m * 16 + rbase + q) * 52 + nt * 16 + lrow] = acc[m][nt][q];
        }
        __syncthreads();

        // ---- fused GRU epilogue (sum 4 K-partials) ----
        const int f = s - CCH;
        const float br_ = (s < CCH) ? e_br : d_br;
        const float bz_ = (s < CCH) ? e_bz : d_bz;
        const float bi_ = (s < CCH) ? e_bi : d_bi;
        const float bh_ = (s < CCH) ? e_bh : d_bh;
#pragma unroll
        for (int p = 0; p < 4; ++p) {
            const int tr = p * 16 + rg;
            float racc = 0.f, zacc = 0.f, nacc = 0.f;
#pragma unroll
            for (int ww = 0; ww < 4; ++ww) {
                const float* g = gp + ww * (64 * 52) + tr * 52;
                racc += g[ji];
                zacc += g[16 + ji];
                nacc += g[32 + ji];
            }
            float grf = __uint_as_float(gru[p] << 16);
            float gzf = __uint_as_float(gzu[p] << 16);
            float gnf = __uint_as_float(gnu[p] << 16);
            float r = sigmf(grf + br_ + racc);
            float z = sigmf(gzf + bz_ + zacc);
            float n = tanhf(gnf + bi_ + r * (nacc + bh_));
            float hold = hreg[p];
            float hv = (1.f - z) * n + z * hold;
            if (s >= CCH && dfl[p]) hv = hold;
            hreg[p] = hv;
            stb[tr * 16 + ji] = __float2bfloat16(hv);
        }
        __syncthreads();

        // ---- An stores (coalesced), drain, flag ----
        if (s < NSTEPS - 1) {
            if (tid < 128) {
                const int row = tid >> 1, part = tid & 1;
                bf16x8 v = *(const bf16x8*)&stb[row * 16 + part * 8];
                const __hip_bfloat16* ap = An + (size_t)(m0 + row) * HH + jbase + part * 8;
                asm volatile("global_store_dwordx4 %0, %1, off sc0 sc1"
                             :: "v"(ap), "v"(v) : "memory");
            }
            asm volatile("s_waitcnt vmcnt(0)" ::: "memory");   // An visible
            __syncthreads();
            if (tid == 0) {
                int v = s + 1;
                int* fp = flags + (mt << 6) + jb;
                asm volatile("global_store_dword %0, %1, off sc0 sc1"
                             :: "v"(fp), "v"(v) : "memory");
            }
        }
        // hsb store (not needed until scores kernel -> after flag)
        if (s >= CCH && tid < 128) {
            const int row = tid >> 1, part = tid & 1;
            bf16x8 v = *(const bf16x8*)&stb[row * 16 + part * 8];
            bf16x8* hp = (bf16x8*)(hsb + ((size_t)f * TT + m0 + row) * HH + jbase + part * 8);
            __builtin_nontemporal_store(v, hp);
        }
        // prefetch next step's gi/dflags (overlaps other blocks' arrival)
        if (s < NSTEPS - 1) {
            const __hip_bfloat16* gnext = (s + 1 < CCH) ? (gi_enc + (size_t)(s + 1) * TT * NG)
                                                        : (gi_dec + (size_t)(s + 1 - CCH) * TT * NG);
#pragma unroll
            for (int p = 0; p < 4; ++p) {
                const __hip_bfloat16* gb = gnext + (size_t)(m0 + p * 16 + rg) * NG + j;
                asm volatile("global_load_ushort %0, %1, off nt" : "=v"(gru[p]) : "v"(gb));
                asm volatile("global_load_ushort %0, %1, off nt" : "=v"(gzu[p]) : "v"(gb + HH));
                asm volatile("global_load_ushort %0, %1, off nt" : "=v"(gnu[p]) : "v"(gb + 2 * HH));
            }
            if (s + 1 >= CCH) {
                const int fnx = s + 1 - CCH;
#pragma unroll
                for (int p = 0; p < 4; ++p) {
                    const unsigned char* dp = dflags + (size_t)(m0 + p * 16 + rg) * FF + fnx;
                    asm volatile("global_load_ubyte %0, %1, off" : "=v"(dfl[p]) : "v"(dp));
                }
            }
        }
    }
}

// ---------------------------------------------------------------------------
// scores (validated round 8/9): pipelined 4-slot ring, counted vmcnt, nt stores
// ---------------------------------------------------------------------------
__global__ __launch_bounds__(256) void scores_pipe(const __hip_bfloat16* __restrict__ hsb,
                                                   const __hip_bfloat16* __restrict__ Wb,
                                                   const float* __restrict__ bout,
                                                   const int* __restrict__ oc,
                                                   float* __restrict__ out) {
    __shared__ __hip_bfloat16 As[4][128 * 32];
    __shared__ __hip_bfloat16 Bs[4][128 * 32];
    int bid = blockIdx.x;
    int sid = (bid & 7) * 632 + (bid >> 3);      // 5056 = 8*632, bijective
    int bx = sid % 79, by = sid / 79;
    int n0 = bx * 128, m0 = by * 128;

    const int tid = threadIdx.x;
    const int l = tid & 63;
    const int w = tid >> 6;
    const int wr = (w >> 1) * 64, wc = (w & 1) * 64;
    const int srow = tid >> 2, skq = tid & 3;

    f32x4 acc[4][4];
#pragma unroll
    for (int i = 0; i < 4; ++i)
#pragma unroll
        for (int j = 0; j < 4; ++j) acc[i][j] = (f32x4){0.f, 0.f, 0.f, 0.f};

    int br0 = n0 + srow, br1 = n0 + 64 + srow;
    br0 = (br0 > VV - 1) ? VV - 1 : br0;
    br1 = (br1 > VV - 1) ? VV - 1 : br1;
    const __hip_bfloat16* gA0 = hsb + (size_t)(m0 + srow) * HH + skq * 8;
    const __hip_bfloat16* gA1 = hsb + (size_t)(m0 + 64 + srow) * HH + skq * 8;
    const __hip_bfloat16* gB0 = Wb + (size_t)br0 * HH + skq * 8;
    const __hip_bfloat16* gB1 = Wb + (size_t)br1 * HH + skq * 8;
    const int fra = ((wr + (l & 15)) << 5) + ((l >> 4) << 3);
    const int frb = ((wc + (l & 15)) << 5) + ((l >> 4) << 3);

    auto stage = [&](int slot, int it) {
        const int k0 = it * 32;
        __hip_bfloat16* lA = &As[slot][tid * 8];
        __hip_bfloat16* lB = &Bs[slot][tid * 8];
        gload_lds16(gA0 + k0, lA);
        gload_lds16(gA1 + k0, lA + 2048);
        gload_lds16(gB0 + k0, lB);
        gload_lds16(gB1 + k0, lB + 2048);
    };

    stage(0, 0);
    stage(1, 1);

    for (int it = 0; it < 32; ++it) {
        if (it + 2 < 32) stage((it + 2) & 3, it + 2);
        int ahead = 31 - it; if (ahead > 2) ahead = 2;
        if (ahead >= 2)      asm volatile("s_waitcnt vmcnt(8)" ::: "memory");
        else if (ahead == 1) asm volatile("s_waitcnt vmcnt(4)" ::: "memory");
        else                 asm volatile("s_waitcnt vmcnt(0)" ::: "memory");
        __builtin_amdgcn_s_barrier();
        __builtin_amdgcn_sched_barrier(0);

        const __hip_bfloat16* cA = As[it & 3];
        const __hip_bfloat16* cB = Bs[it & 3];
        bf16x8 af[4], bfv[4];
#pragma unroll
        for (int fm = 0; fm < 4; ++fm) af[fm] = *(const bf16x8*)&cA[fra + fm * 512];
#pragma unroll
        for (int fn = 0; fn < 4; ++fn) bfv[fn] = *(const bf16x8*)&cB[frb + fn * 512];
#pragma unroll
        for (int fm = 0; fm < 4; ++fm)
#pragma unroll
            for (int fn = 0; fn < 4; ++fn)
                acc[fm][fn] = __builtin_amdgcn_mfma_f32_16x16x32_bf16(af[fm], bfv[fn], acc[fm][fn], 0, 0, 0);
    }

    const bool zf = (oc[0] == EOS_ID);
    const int colb = wc + (l & 15);
    const int rb   = wr + ((l >> 4) << 2);
#pragma unroll
    for (int fn = 0; fn < 4; ++fn) {
        int v = n0 + colb + fn * 16;
        if (v < VV) {
            float bb = bout[v];
#pragma unroll
            for (int fm = 0; fm < 4; ++fm) {
#pragma unroll
                for (int q = 0; q < 4; ++q) {
                    int m = m0 + rb + fm * 16 + q;
                    int fo = m >> 8, t = m & 255;
                    float val = zf ? 0.f : (acc[fm][fn][q] + bb);
                    __builtin_nontemporal_store(val, &out[(size_t)(t * FF + fo) * VV + v]);
                }
            }
        }
    }
}

// ---------------------------------------------------------------------------
extern "C" void kernel_launch(void* const* d_in, const int* in_sizes, int n_in,
                              void* d_out, int out_size, void* d_ws, size_t ws_size,
                              hipStream_t stream) {
    (void)in_sizes; (void)n_in; (void)ws_size;

    const float* token_ctx = (const float*)d_in[0];
    const float* emb       = (const float*)d_in[1];
    const float* eWih      = (const float*)d_in[2];
    const float* eWhh      = (const float*)d_in[3];
    const float* ebih      = (const float*)d_in[4];
    const float* ebhh      = (const float*)d_in[5];
    const float* dWih      = (const float*)d_in[6];
    const float* dWhh      = (const float*)d_in[7];
    const float* dbih      = (const float*)d_in[8];
    const float* dbhh      = (const float*)d_in[9];
    const float* Wout      = (const float*)d_in[10];
    const float* bout      = (const float*)d_in[11];
    const int*   sent      = (const int*)d_in[12];
    const int*   ochars    = (const int*)d_in[13];
    float* out = (float*)d_out;

    // ---- ws layout (~40 MB) ----
    char* w = (char*)d_ws;
    float* hA = (float*)w;                      w += (size_t)TT * HH * 4;        // 1 MB
    __hip_bfloat16* Ab0 = (__hip_bfloat16*)w;   w += (size_t)TT * HH * 2;        // 0.5 MB
    __hip_bfloat16* Ab1 = (__hip_bfloat16*)w;   w += (size_t)TT * HH * 2;        // 0.5 MB
    __hip_bfloat16* hsb = (__hip_bfloat16*)w;   w += (size_t)FF * TT * HH * 2;   // 16.8 MB
    __hip_bfloat16* Woutb = (__hip_bfloat16*)w; w += (size_t)VV * HH * 2;        // 20.5 MB
    int* c_in = (int*)w;                        w += (size_t)TT * FF * 4;
    unsigned char* done = (unsigned char*)w;    w += (size_t)TT * FF;
    w = (char*)(((size_t)w + 255) & ~(size_t)255);
    int* ctr = (int*)w;                         w += (size_t)CTR_INTS * 4;

    // ---- d_out tail scratch (dead until scores_pipe) ----
    char* tail = (char*)d_out + (size_t)out_size * 4;
    tail -= (size_t)NG * HH * 2;          __hip_bfloat16* Bg_e = (__hip_bfloat16*)tail;   // 6.3 MB
    tail -= (size_t)NG * HH * 2;          __hip_bfloat16* Bg_d = (__hip_bfloat16*)tail;   // 6.3 MB
    tail -= (size_t)CCH * TT * NG * 2;    __hip_bfloat16* gi_enc = (__hip_bfloat16*)tail; // 12.6 MB
    tail -= (size_t)FF * TT * NG * 2;     __hip_bfloat16* gi_dec = (__hip_bfloat16*)tail; // 50.3 MB
    tail -= (size_t)VV * EE * 2;          __hip_bfloat16* emb_bf = (__hip_bfloat16*)tail; // 5.1 MB
    tail -= (size_t)NG * EE * 2;          __hip_bfloat16* Wihb_e = (__hip_bfloat16*)tail;
    tail -= (size_t)NG * EE * 2;          __hip_bfloat16* Wihb_d = (__hip_bfloat16*)tail;

    // allow >64KB dynamic LDS for the chain kernel (idempotent; r9-proven)
    hipFuncSetAttribute((const void*)chain_kernel,
                        hipFuncAttributeMaxDynamicSharedMemorySize, LDS_TOTAL);

    // ---- prep & conversions ----
    prep_kernel<<<1, 256, 0, stream>>>(ochars, c_in, done, ctr);
    h0_kernel<<<TT, 256, 0, stream>>>(token_ctx, sent, hA, Ab0);
    f2b_kernel<<<(VV * EE) / 4 / 256, 256, 0, stream>>>(emb, emb_bf);
    f2b_kernel<<<(NG * EE) / 4 / 256, 256, 0, stream>>>(eWih, Wihb_e);
    f2b_kernel<<<(NG * EE) / 4 / 256, 256, 0, stream>>>(dWih, Wihb_d);
    f2b_kernel<<<(VV * HH) / 4 / 256, 256, 0, stream>>>(Wout, Woutb);
    build_Bg2<<<NG, 256, 0, stream>>>(eWhh, Bg_e);
    build_Bg2<<<NG, 256, 0, stream>>>(dWhh, Bg_d);

    // ---- x-side tables: gi = emb_bf[ids] @ Wih^T (bf16, gate order g*1024+j) ----
    gemm_pipe<1><<<dim3(24, 16), 256, 0, stream>>>(emb_bf, EE, Wihb_e, EE, gi_enc, sent, 8);
    gemm_pipe<2><<<dim3(24, 64), 256, 0, stream>>>(emb_bf, EE, Wihb_d, EE, gi_dec, c_in, 8);

    // ---- persistent recurrent chain ----
    chain_kernel<<<CHAIN_BLKS, 256, LDS_TOTAL, stream>>>(Ab0, Ab1, Bg_e, Bg_d,
                                                         gi_enc, gi_dec,
                                                         ebih, ebhh, dbih, dbhh,
                                                         hA, hsb, done, ctr);

    // ---- scores ----
    scores_pipe<<<5056, 256, 0, stream>>>(hsb, Woutb, bout, ochars, out);
}